// Round 9
// baseline (6173.322 us; speedup 1.0000x reference)
//
#include <hip/hip_runtime.h>
#include <math.h>

// ---------------------------------------------------------------------------
// R18: (a) conv32 reverted to R16's proven conv32_db<4> (620us, VGPR 40;
// R17's 512t/CO=32 spilled: VGPR_Count=32 < 32 accs alone -> scratch, 658us,
// E2E 5900. CO=32 abandoned - two register-pressure deaths). (b) NEW single
// lever: conv16_s2/conv16_s1 converted from R12's 2-barrier serial structure
// (the one that made R12-conv32 51% idle) to R14's register-staged
// double-buffer + ONE barrier/chunk. Register-budgeted per R15/R17 lesson:
// s2 CHUNK=2 (NS=9 -> ~60 VGPR, LDS 21KB), s1 CHUNK=4 (NS=6 -> ~50 VGPR).
// Channel order stays strictly ascending for any CHUNK -> per-output FMA
// chain bit-identical -> selection cone safe.
// ---------------------------------------------------------------------------

#define DI __device__ __forceinline__

typedef short short8 __attribute__((ext_vector_type(8)));
typedef float float16v __attribute__((ext_vector_type(16)));

DI unsigned fkey(float f) {
  unsigned u = __float_as_uint(f);
  return (u & 0x80000000u) ? ~u : (u | 0x80000000u);
}

DI unsigned short f2bf(float f) {  // fp32 -> bf16 RN-even
  unsigned u = __float_as_uint(f);
  unsigned r = (u + 0x7FFFu + ((u >> 16) & 1u)) >> 16;
  return (unsigned short)r;
}

// ---------------------------------------------------------------------------
// Stem (exact R9): CO=4, grid (25,25,16), LDS-staged weights.
// ---------------------------------------------------------------------------
__global__ __launch_bounds__(256) void stem_conv(const float* __restrict__ x,
                                                 const float* __restrict__ w,
                                                 float* __restrict__ out) {
  __shared__ float tin[3 * 37 * 37];
  __shared__ float tw[4 * 147];
  const int x0 = blockIdx.x * 16, y0 = blockIdx.y * 16, co0 = blockIdx.z * 4;
  const int tid = threadIdx.x;
  for (int i = tid; i < 4 * 147; i += 256) tw[i] = w[co0 * 147 + i];
  const int ix0 = x0 * 2 - 2, iy0 = y0 * 2 - 2;
  const float mean[3] = {0.485f, 0.456f, 0.406f};
  const float stdv[3] = {0.229f, 0.224f, 0.225f};
  for (int i = tid; i < 3 * 37 * 37; i += 256) {
    int c = i / 1369, r = i % 1369, yy = r / 37, xx = r % 37;
    int gy = iy0 + yy, gx = ix0 + xx;
    float v = 0.f;
    if ((unsigned)gy < 800u && (unsigned)gx < 800u)
      v = __fdiv_rn(__fsub_rn(x[c * 640000 + gy * 800 + gx], mean[c]), stdv[c]);
    tin[i] = v;
  }
  __syncthreads();
  const int tx = tid & 15, ty = tid >> 4;
  float acc[4] = {0.f, 0.f, 0.f, 0.f};
  for (int c = 0; c < 3; ++c)
    for (int ky = 0; ky < 7; ++ky)
#pragma unroll
      for (int kx = 0; kx < 7; ++kx) {
        float v = tin[c * 1369 + (ty * 2 + ky) * 37 + (tx * 2 + kx)];
#pragma unroll
        for (int co = 0; co < 4; ++co)
          acc[co] = fmaf(v, tw[co * 147 + c * 49 + ky * 7 + kx], acc[co]);
      }
  int ox = x0 + tx, oy = y0 + ty;
#pragma unroll
  for (int co = 0; co < 4; ++co)
    out[(size_t)(co0 + co) * 160000 + oy * 400 + ox] = fmaxf(acc[co], 0.f);
}

// ---------------------------------------------------------------------------
// Repack conv weights: w[(z*16+co)*Cin + ci][kk] -> wpk[((z*Cin+ci)*9+kk)*16+co]
// ---------------------------------------------------------------------------
__global__ void repack_w32(const float* __restrict__ w,
                           float* __restrict__ wpk, int Cin) {
  int i = blockIdx.x * 256 + threadIdx.x;
  int total = 16 * Cin * 9 * 16;
  if (i >= total) return;
  int co = i & 15;
  int r = i >> 4;       // (z*Cin + ci)*9 + kk
  int kk = r % 9;
  int r2 = r / 9;       // z*Cin + ci
  int ci = r2 % Cin;
  int z = r2 / Cin;
  wpk[i] = w[((size_t)(z * 16 + co) * Cin + ci) * 9 + kk];
}

// ---------------------------------------------------------------------------
// conv32_db (exact R16): 32x16 tile, 2 adjacent px/thread, CO=16, CHUNK=4
// register-staged double buffer, ONE barrier/iter. Proven 620us @200^2.
// ---------------------------------------------------------------------------
template <int CHUNK, bool RELU>
__global__ __launch_bounds__(256) void conv32_db(
    const float* __restrict__ in, const float* __restrict__ wpk,
    float* __restrict__ out, int Cin, int Hin, int Win, int Hout, int Wout) {
  constexpr int TILE = CHUNK * 612;
  constexpr int NS = (TILE + 255) / 256;
  constexpr int PADT = NS * 256;
  __shared__ __align__(16) float tin2[2][PADT];
  const int tid = threadIdx.x;
  const int tx = tid & 15, ty = tid >> 4;
  const int x0 = blockIdx.x * 32, y0 = blockIdx.y * 16;
  const int ix0 = x0 - 1, iy0 = y0 - 1;
  const size_t HWin = (size_t)Hin * Win;

  int goff[NS];
#pragma unroll
  for (int j = 0; j < NS; ++j) {
    int e = j * 256 + tid;
    int c = e / 612, r = e % 612;
    int yy = r / 34, xx = r % 34;
    int gy = iy0 + yy, gx = ix0 + xx;
    bool ok = (e < TILE) && ((unsigned)gy < (unsigned)Hin) &&
              ((unsigned)gx < (unsigned)Win);
    goff[j] = ok ? (int)((size_t)c * HWin + (size_t)gy * Win + gx) : -1;
  }

  float acc0[16], acc1[16];
#pragma unroll
  for (int co = 0; co < 16; ++co) { acc0[co] = 0.f; acc1[co] = 0.f; }

  float stg[NS];
#pragma unroll
  for (int j = 0; j < NS; ++j)
    stg[j] = (goff[j] >= 0) ? in[goff[j]] : 0.f;
#pragma unroll
  for (int j = 0; j < NS; ++j) tin2[0][j * 256 + tid] = stg[j];
  __syncthreads();

  int buf = 0;
  for (int cb = 0; cb < Cin; cb += CHUNK) {
    const bool more = (cb + CHUNK) < Cin;
    if (more) {
      const float* gsrc = in + (size_t)(cb + CHUNK) * HWin;
#pragma unroll
      for (int j = 0; j < NS; ++j)
        stg[j] = (goff[j] >= 0) ? gsrc[goff[j]] : 0.f;
    }
    for (int ci = 0; ci < CHUNK; ++ci) {
      const float4* wq = (const float4*)(wpk +
          ((size_t)blockIdx.z * Cin + (size_t)(cb + ci)) * 144);
#pragma unroll
      for (int ky = 0; ky < 3; ++ky) {
        const float* tb = &tin2[buf][ci * 612 + (ty + ky) * 34 + 2 * tx];
        float2 d0 = *(const float2*)tb;
        float2 d1 = *(const float2*)(tb + 2);
#pragma unroll
        for (int kx = 0; kx < 3; ++kx) {
          float v0 = (kx == 0) ? d0.x : (kx == 1) ? d0.y : d1.x;
          float v1 = (kx == 0) ? d0.y : (kx == 1) ? d1.x : d1.y;
          const int kk = ky * 3 + kx;
          float4 w0 = wq[kk * 4 + 0];
          float4 w1 = wq[kk * 4 + 1];
          float4 w2 = wq[kk * 4 + 2];
          float4 w3 = wq[kk * 4 + 3];
          acc0[0]  = fmaf(v0, w0.x, acc0[0]);
          acc0[1]  = fmaf(v0, w0.y, acc0[1]);
          acc0[2]  = fmaf(v0, w0.z, acc0[2]);
          acc0[3]  = fmaf(v0, w0.w, acc0[3]);
          acc1[0]  = fmaf(v1, w0.x, acc1[0]);
          acc1[1]  = fmaf(v1, w0.y, acc1[1]);
          acc1[2]  = fmaf(v1, w0.z, acc1[2]);
          acc1[3]  = fmaf(v1, w0.w, acc1[3]);
          acc0[4]  = fmaf(v0, w1.x, acc0[4]);
          acc0[5]  = fmaf(v0, w1.y, acc0[5]);
          acc0[6]  = fmaf(v0, w1.z, acc0[6]);
          acc0[7]  = fmaf(v0, w1.w, acc0[7]);
          acc1[4]  = fmaf(v1, w1.x, acc1[4]);
          acc1[5]  = fmaf(v1, w1.y, acc1[5]);
          acc1[6]  = fmaf(v1, w1.z, acc1[6]);
          acc1[7]  = fmaf(v1, w1.w, acc1[7]);
          acc0[8]  = fmaf(v0, w2.x, acc0[8]);
          acc0[9]  = fmaf(v0, w2.y, acc0[9]);
          acc0[10] = fmaf(v0, w2.z, acc0[10]);
          acc0[11] = fmaf(v0, w2.w, acc0[11]);
          acc1[8]  = fmaf(v1, w2.x, acc1[8]);
          acc1[9]  = fmaf(v1, w2.y, acc1[9]);
          acc1[10] = fmaf(v1, w2.z, acc1[10]);
          acc1[11] = fmaf(v1, w2.w, acc1[11]);
          acc0[12] = fmaf(v0, w3.x, acc0[12]);
          acc0[13] = fmaf(v0, w3.y, acc0[13]);
          acc0[14] = fmaf(v0, w3.z, acc0[14]);
          acc0[15] = fmaf(v0, w3.w, acc0[15]);
          acc1[12] = fmaf(v1, w3.x, acc1[12]);
          acc1[13] = fmaf(v1, w3.y, acc1[13]);
          acc1[14] = fmaf(v1, w3.z, acc1[14]);
          acc1[15] = fmaf(v1, w3.w, acc1[15]);
        }
      }
    }
    if (more) {
#pragma unroll
      for (int j = 0; j < NS; ++j) tin2[buf ^ 1][j * 256 + tid] = stg[j];
    }
    __syncthreads();
    buf ^= 1;
  }

  const int co0 = blockIdx.z * 16;
  int oy = y0 + ty;
  if (oy < Hout) {
    int ox = x0 + 2 * tx;
    if (ox + 1 < Wout) {
#pragma unroll
      for (int co = 0; co < 16; ++co) {
        float a = acc0[co], b = acc1[co];
        if (RELU) { a = fmaxf(a, 0.f); b = fmaxf(b, 0.f); }
        float2 st; st.x = a; st.y = b;
        *(float2*)&out[(size_t)(co0 + co) * Hout * Wout +
                       (size_t)oy * Wout + ox] = st;
      }
    } else if (ox < Wout) {
#pragma unroll
      for (int co = 0; co < 16; ++co) {
        float a = acc0[co];
        if (RELU) a = fmaxf(a, 0.f);
        out[(size_t)(co0 + co) * Hout * Wout + (size_t)oy * Wout + ox] = a;
      }
    }
  }
}

// ---------------------------------------------------------------------------
// conv16_s1_db: 16x16 tile, CO=16, CHUNK=4 register-staged double buffer,
// ONE barrier/chunk. Pitched LDS (loff precomputed). FMA chain = R12
// (channels ascending) -> bit-identical.
// ---------------------------------------------------------------------------
template <int CHUNK, bool RELU>
__global__ __launch_bounds__(256) void conv16_s1_db(
    const float* __restrict__ in, const float* __restrict__ wpk,
    float* __restrict__ out, int Cin, int Hin, int Win, int Hout, int Wout) {
  constexpr int P = 24;
  constexpr int TOT = CHUNK * 18 * 18;
  constexpr int NS = (TOT + 255) / 256;
  __shared__ __align__(16) float tin2[2][CHUNK * 18 * P];
  const int tid = threadIdx.x;
  const int tx = tid & 15, ty = tid >> 4;
  const int x0 = blockIdx.x * 16, y0 = blockIdx.y * 16;
  const int ix0 = x0 - 1, iy0 = y0 - 1;
  const size_t HWin = (size_t)Hin * Win;

  int goff[NS], loff[NS];
#pragma unroll
  for (int j = 0; j < NS; ++j) {
    int i = tid + j * 256;
    int c = i / 324, r = i % 324;
    int yy = r / 18, xx = r % 18;
    int gy = iy0 + yy, gx = ix0 + xx;
    bool ok = (i < TOT) && ((unsigned)gy < (unsigned)Hin) &&
              ((unsigned)gx < (unsigned)Win);
    goff[j] = ok ? (int)(c * HWin + (size_t)gy * Win + gx) : -1;
    loff[j] = (i < TOT) ? (c * 18 * P + yy * P + xx) : 0;
  }

  float acc[16];
#pragma unroll
  for (int co = 0; co < 16; ++co) acc[co] = 0.f;

  float stg[NS];
#pragma unroll
  for (int j = 0; j < NS; ++j)
    stg[j] = (goff[j] >= 0) ? in[goff[j]] : 0.f;
#pragma unroll
  for (int j = 0; j < NS; ++j)
    if (tid + j * 256 < TOT) tin2[0][loff[j]] = stg[j];
  __syncthreads();

  int buf = 0;
  for (int cb = 0; cb < Cin; cb += CHUNK) {
    const bool more = (cb + CHUNK) < Cin;
    if (more) {
      const float* gsrc = in + (size_t)(cb + CHUNK) * HWin;
#pragma unroll
      for (int j = 0; j < NS; ++j)
        stg[j] = (goff[j] >= 0) ? gsrc[goff[j]] : 0.f;
    }
    for (int ci = 0; ci < CHUNK; ++ci) {
      const float4* wq = (const float4*)(wpk +
          ((size_t)blockIdx.z * Cin + (size_t)(cb + ci)) * 144);
#pragma unroll
      for (int ky = 0; ky < 3; ++ky) {
#pragma unroll
        for (int kx = 0; kx < 3; ++kx) {
          const int kk = ky * 3 + kx;
          float v = tin2[buf][ci * 18 * P + (ty + ky) * P + tx + kx];
          float4 w0 = wq[kk * 4 + 0];
          float4 w1 = wq[kk * 4 + 1];
          float4 w2 = wq[kk * 4 + 2];
          float4 w3 = wq[kk * 4 + 3];
          acc[0]  = fmaf(v, w0.x, acc[0]);
          acc[1]  = fmaf(v, w0.y, acc[1]);
          acc[2]  = fmaf(v, w0.z, acc[2]);
          acc[3]  = fmaf(v, w0.w, acc[3]);
          acc[4]  = fmaf(v, w1.x, acc[4]);
          acc[5]  = fmaf(v, w1.y, acc[5]);
          acc[6]  = fmaf(v, w1.z, acc[6]);
          acc[7]  = fmaf(v, w1.w, acc[7]);
          acc[8]  = fmaf(v, w2.x, acc[8]);
          acc[9]  = fmaf(v, w2.y, acc[9]);
          acc[10] = fmaf(v, w2.z, acc[10]);
          acc[11] = fmaf(v, w2.w, acc[11]);
          acc[12] = fmaf(v, w3.x, acc[12]);
          acc[13] = fmaf(v, w3.y, acc[13]);
          acc[14] = fmaf(v, w3.z, acc[14]);
          acc[15] = fmaf(v, w3.w, acc[15]);
        }
      }
    }
    if (more) {
#pragma unroll
      for (int j = 0; j < NS; ++j)
        if (tid + j * 256 < TOT) tin2[buf ^ 1][loff[j]] = stg[j];
    }
    __syncthreads();
    buf ^= 1;
  }
  const int co0 = blockIdx.z * 16;
  int oy = y0 + ty, ox = x0 + tx;
  if (oy < Hout && ox < Wout) {
#pragma unroll
    for (int co = 0; co < 16; ++co) {
      float v = acc[co];
      if (RELU) v = fmaxf(v, 0.f);
      out[(size_t)(co0 + co) * Hout * Wout + (size_t)oy * Wout + ox] = v;
    }
  }
}

// ---------------------------------------------------------------------------
// conv16_s2_db: 16x16 out tile, phase-split E/O pitch 20, CHUNK=2
// register-staged double buffer, ONE barrier/chunk. FMA chain = R12
// (channels ascending) -> bit-identical.
// ---------------------------------------------------------------------------
template <int CHUNK, bool RELU>
__global__ __launch_bounds__(256) void conv16_s2_db(
    const float* __restrict__ in, const float* __restrict__ wpk,
    float* __restrict__ out, int Cin, int Hin, int Win, int Hout, int Wout) {
  constexpr int P = 20;
  constexpr int HALF = CHUNK * 33 * P;
  constexpr int TOT = CHUNK * 33 * 33;
  constexpr int NS = (TOT + 255) / 256;
  __shared__ __align__(16) float tin2[2][2 * HALF];  // [buf][E|O]
  const int tid = threadIdx.x;
  const int tx = tid & 15, ty = tid >> 4;
  const int x0 = blockIdx.x * 16, y0 = blockIdx.y * 16;
  const int ix0 = x0 * 2, iy0 = y0 * 2;
  const size_t HWin = (size_t)Hin * Win;

  int goff[NS], loff[NS];
#pragma unroll
  for (int j = 0; j < NS; ++j) {
    int i = tid + j * 256;
    int c = i / 1089, r = i % 1089;
    int yy = r / 33, xx = r % 33;
    int gy = iy0 + yy, gx = ix0 + xx;
    bool ok = (i < TOT) && ((unsigned)gy < (unsigned)Hin) &&
              ((unsigned)gx < (unsigned)Win);
    goff[j] = ok ? (int)(c * HWin + (size_t)gy * Win + gx) : -1;
    loff[j] = (i < TOT)
                  ? (c * 33 * P + yy * P + (xx >> 1) + ((xx & 1) ? HALF : 0))
                  : 0;
  }

  float acc[16];
#pragma unroll
  for (int co = 0; co < 16; ++co) acc[co] = 0.f;

  float stg[NS];
#pragma unroll
  for (int j = 0; j < NS; ++j)
    stg[j] = (goff[j] >= 0) ? in[goff[j]] : 0.f;
#pragma unroll
  for (int j = 0; j < NS; ++j)
    if (tid + j * 256 < TOT) tin2[0][loff[j]] = stg[j];
  __syncthreads();

  int buf = 0;
  for (int cb = 0; cb < Cin; cb += CHUNK) {
    const bool more = (cb + CHUNK) < Cin;
    if (more) {
      const float* gsrc = in + (size_t)(cb + CHUNK) * HWin;
#pragma unroll
      for (int j = 0; j < NS; ++j)
        stg[j] = (goff[j] >= 0) ? gsrc[goff[j]] : 0.f;
    }
    for (int ci = 0; ci < CHUNK; ++ci) {
      const float4* wq = (const float4*)(wpk +
          ((size_t)blockIdx.z * Cin + (size_t)(cb + ci)) * 144);
#pragma unroll
      for (int ky = 0; ky < 3; ++ky) {
#pragma unroll
        for (int kx = 0; kx < 3; ++kx) {
          const int kk = ky * 3 + kx;
          const float* base = (kx == 1) ? (&tin2[buf][0] + HALF)
                                        : &tin2[buf][0];
          const int cadd = (kx == 2) ? 1 : 0;
          float v = base[ci * 33 * P + (2 * ty + ky) * P + tx + cadd];
          float4 w0 = wq[kk * 4 + 0];
          float4 w1 = wq[kk * 4 + 1];
          float4 w2 = wq[kk * 4 + 2];
          float4 w3 = wq[kk * 4 + 3];
          acc[0]  = fmaf(v, w0.x, acc[0]);
          acc[1]  = fmaf(v, w0.y, acc[1]);
          acc[2]  = fmaf(v, w0.z, acc[2]);
          acc[3]  = fmaf(v, w0.w, acc[3]);
          acc[4]  = fmaf(v, w1.x, acc[4]);
          acc[5]  = fmaf(v, w1.y, acc[5]);
          acc[6]  = fmaf(v, w1.z, acc[6]);
          acc[7]  = fmaf(v, w1.w, acc[7]);
          acc[8]  = fmaf(v, w2.x, acc[8]);
          acc[9]  = fmaf(v, w2.y, acc[9]);
          acc[10] = fmaf(v, w2.z, acc[10]);
          acc[11] = fmaf(v, w2.w, acc[11]);
          acc[12] = fmaf(v, w3.x, acc[12]);
          acc[13] = fmaf(v, w3.y, acc[13]);
          acc[14] = fmaf(v, w3.z, acc[14]);
          acc[15] = fmaf(v, w3.w, acc[15]);
        }
      }
    }
    if (more) {
#pragma unroll
      for (int j = 0; j < NS; ++j)
        if (tid + j * 256 < TOT) tin2[buf ^ 1][loff[j]] = stg[j];
    }
    __syncthreads();
    buf ^= 1;
  }
  const int co0 = blockIdx.z * 16;
  int oy = y0 + ty, ox = x0 + tx;
  if (oy < Hout && ox < Wout) {
#pragma unroll
    for (int co = 0; co < 16; ++co) {
      float v = acc[co];
      if (RELU) v = fmaxf(v, 0.f);
      out[(size_t)(co0 + co) * Hout * Wout + (size_t)oy * Wout + ox] = v;
    }
  }
}

// ---------------------------------------------------------------------------
// Transpose t [256][npix] -> tt [npix][256] (pure data movement).
// ---------------------------------------------------------------------------
__global__ __launch_bounds__(256) void transpose_t(const float* __restrict__ in,
                                                   float* __restrict__ out,
                                                   int npix) {
  __shared__ float tile[32][33];
  const int p0 = blockIdx.x * 32, c0 = blockIdx.y * 32;
  const int tx = threadIdx.x & 31, ty = threadIdx.x >> 5;
  for (int r = ty; r < 32; r += 8) {
    int p = p0 + tx;
    tile[r][tx] = (p < npix) ? in[(size_t)(c0 + r) * npix + p] : 0.f;
  }
  __syncthreads();
  for (int r = ty; r < 32; r += 8) {
    int p = p0 + r;
    if (p < npix) out[(size_t)p * 256 + c0 + tx] = tile[tx][r];
  }
}

// ---------------------------------------------------------------------------
// RPN head + decode reading px-major tt[p][256]. (exact R14)
// ---------------------------------------------------------------------------
__global__ __launch_bounds__(256) void rpn_head_decode(
    const float* __restrict__ tt, const float* __restrict__ wcls,
    const float* __restrict__ wbox, float* __restrict__ boxes,
    float* __restrict__ scores, int fh, int fw, float stride, float ws0,
    float ws1, float ws2, float hs0, float hs1, float hs2) {
  __shared__ __align__(16) float wcs[256][16];
  for (int i = threadIdx.x; i < 256 * 16; i += 256) {
    int c = i & 255, o = i >> 8;
    float v = 0.f;
    if (o < 3) v = wcls[o * 256 + c];
    else if (o < 15) v = wbox[(o - 3) * 256 + c];
    wcs[c][o] = v;
  }
  __syncthreads();
  const int npix = fh * fw;
  int p = blockIdx.x * 256 + threadIdx.x;
  if (p >= npix) return;
  float a[15];
#pragma unroll
  for (int o = 0; o < 15; ++o) a[o] = 0.f;
  const float4* tp = (const float4*)(tt + (size_t)p * 256);
#pragma unroll 4
  for (int c4 = 0; c4 < 64; ++c4) {
    float4 tv = tp[c4];
#pragma unroll
    for (int j = 0; j < 4; ++j) {
      float v = (j == 0) ? tv.x : (j == 1) ? tv.y : (j == 2) ? tv.z : tv.w;
      int c = c4 * 4 + j;
      const float4* wr = (const float4*)&wcs[c][0];
      float4 w0 = wr[0], w1 = wr[1], w2 = wr[2], w3 = wr[3];
      a[0] = fmaf(v, w0.x, a[0]);   a[1] = fmaf(v, w0.y, a[1]);
      a[2] = fmaf(v, w0.z, a[2]);   a[3] = fmaf(v, w0.w, a[3]);
      a[4] = fmaf(v, w1.x, a[4]);   a[5] = fmaf(v, w1.y, a[5]);
      a[6] = fmaf(v, w1.z, a[6]);   a[7] = fmaf(v, w1.w, a[7]);
      a[8] = fmaf(v, w2.x, a[8]);   a[9] = fmaf(v, w2.y, a[9]);
      a[10] = fmaf(v, w2.z, a[10]); a[11] = fmaf(v, w2.w, a[11]);
      a[12] = fmaf(v, w3.x, a[12]); a[13] = fmaf(v, w3.y, a[13]);
      a[14] = fmaf(v, w3.z, a[14]);
    }
  }
  const int i = p / fw, j = p % fw;
  const float acy0 = __fmul_rn((float)i + 0.5f, stride);
  const float acx0 = __fmul_rn((float)j + 0.5f, stride);
  const float WS[3] = {ws0, ws1, ws2}, HS[3] = {hs0, hs1, hs2};
#pragma unroll
  for (int an = 0; an < 3; ++an) {
    float hw = __fmul_rn(WS[an], 0.5f), hh = __fmul_rn(HS[an], 0.5f);
    float x1a = __fsub_rn(acx0, hw), x2a = __fadd_rn(acx0, hw);
    float y1a = __fsub_rn(acy0, hh), y2a = __fadd_rn(acy0, hh);
    float aw = __fsub_rn(x2a, x1a), ah = __fsub_rn(y2a, y1a);
    float acx = __fadd_rn(x1a, __fmul_rn(aw, 0.5f));
    float acy = __fadd_rn(y1a, __fmul_rn(ah, 0.5f));
    float dx = a[3 + an * 4 + 0], dy = a[3 + an * 4 + 1];
    float dw = fminf(fmaxf(a[3 + an * 4 + 2], -4.f), 4.f);
    float dh = fminf(fmaxf(a[3 + an * 4 + 3], -4.f), 4.f);
    float cx = __fadd_rn(acx, __fmul_rn(dx, aw));
    float cy = __fadd_rn(acy, __fmul_rn(dy, ah));
    float w_ = __fmul_rn(aw, expf(dw));
    float h_ = __fmul_rn(ah, expf(dh));
    int idx = p * 3 + an;
    boxes[idx * 4 + 0] =
        fminf(fmaxf(__fsub_rn(cx, __fmul_rn(w_, 0.5f)), 0.f), 800.f);
    boxes[idx * 4 + 1] =
        fminf(fmaxf(__fsub_rn(cy, __fmul_rn(h_, 0.5f)), 0.f), 800.f);
    boxes[idx * 4 + 2] =
        fminf(fmaxf(__fadd_rn(cx, __fmul_rn(w_, 0.5f)), 0.f), 800.f);
    boxes[idx * 4 + 3] =
        fminf(fmaxf(__fadd_rn(cy, __fmul_rn(h_, 0.5f)), 0.f), 800.f);
    scores[idx] = a[an];
  }
}

// ---------------------------------------------------------------------------
// Exact top-k (k=1000) per level: two-pass 16-bit radix select. (exact R14)
// ---------------------------------------------------------------------------
__global__ void hist_hi_kernel(const float* __restrict__ s, int n,
                               int* __restrict__ hist) {
  int i = blockIdx.x * blockDim.x + threadIdx.x;
  if (i < n) atomicAdd(&hist[fkey(s[i]) >> 16], 1);
}

__global__ void hist_lo_kernel(const float* __restrict__ s, int n,
                               const int* __restrict__ sel,
                               int* __restrict__ hist) {
  unsigned b = (unsigned)sel[0];
  int i = blockIdx.x * blockDim.x + threadIdx.x;
  if (i < n) {
    unsigned key = fkey(s[i]);
    if ((key >> 16) == b) atomicAdd(&hist[key & 0xffffu], 1);
  }
}

__global__ __launch_bounds__(256) void scan_hi_kernel(
    const int* __restrict__ hist, int k, int* __restrict__ sel) {
  __shared__ int csum[256];
  int t = threadIdx.x;
  int s = 0;
  for (int i = 0; i < 256; ++i) s += hist[t * 256 + i];
  csum[t] = s;
  __syncthreads();
  if (t == 0) {
    int cum = 0;
    for (int c = 255; c >= 0; --c) {
      if (cum + csum[c] >= k) {
        int cc = cum;
        for (int b = c * 256 + 255;; --b) {
          int h = hist[b];
          if (cc + h >= k) {
            sel[0] = b; sel[1] = k - cc; sel[2] = cc;
            return;
          }
          cc += h;
        }
      }
      cum += csum[c];
    }
    sel[0] = 0; sel[1] = k - cum; sel[2] = cum;
  }
}

__global__ __launch_bounds__(256) void scan_lo_kernel(
    const int* __restrict__ hist, int* __restrict__ sel) {
  __shared__ int csum[256];
  int t = threadIdx.x;
  int s = 0;
  for (int i = 0; i < 256; ++i) s += hist[t * 256 + i];
  csum[t] = s;
  __syncthreads();
  if (t == 0) {
    int r = sel[1], b = sel[0], cc_hi = sel[2];
    int cum = 0;
    for (int c = 255; c >= 0; --c) {
      if (cum + csum[c] >= r) {
        int cc = cum;
        for (int l = c * 256 + 255;; --l) {
          int h = hist[l];
          if (cc + h >= r) {
            sel[3] = (int)(((unsigned)b << 16) | (unsigned)l);
            sel[4] = cc_hi + cc;
            sel[5] = r - cc;
            sel[6] = 0;
            sel[7] = 0;
            return;
          }
          cc += h;
        }
      }
      cum += csum[c];
    }
    sel[3] = (int)((unsigned)b << 16);
    sel[4] = cc_hi; sel[5] = r; sel[6] = 0; sel[7] = 0;
  }
}

__global__ void compact_kernel(const float* __restrict__ s,
                               const float* __restrict__ boxes, int n,
                               int* __restrict__ sel, float* __restrict__ out_s,
                               float* __restrict__ out_b, int obase) {
  int i = blockIdx.x * blockDim.x + threadIdx.x;
  if (i >= n) return;
  unsigned key = fkey(s[i]);
  unsigned kth = (unsigned)sel[3];
  int pos = -1;
  if (key > kth) {
    pos = atomicAdd(&sel[6], 1);
  } else if (key == kth) {
    int e = atomicAdd(&sel[7], 1);
    if (e < sel[5]) pos = sel[4] + e;
  }
  if (pos >= 0) {
    int o = obase + pos;
    out_s[o] = s[i];
    out_b[o * 4 + 0] = boxes[i * 4 + 0];
    out_b[o * 4 + 1] = boxes[i * 4 + 1];
    out_b[o * 4 + 2] = boxes[i * 4 + 2];
    out_b[o * 4 + 3] = boxes[i * 4 + 3];
  }
}

// ---------------------------------------------------------------------------
// NMS: rank + suppression bitmask + greedy scan. (unchanged)
// ---------------------------------------------------------------------------
#define NMS_N 4000
#define NMS_W 63

__global__ __launch_bounds__(256) void rank_kernel(const float* __restrict__ s,
                                                   int* __restrict__ order) {
  __shared__ float ls[NMS_N];
  for (int i = threadIdx.x; i < NMS_N; i += 256) ls[i] = s[i];
  __syncthreads();
  int i = blockIdx.x * 256 + threadIdx.x;
  if (i >= NMS_N) return;
  float si = ls[i];
  int cnt = 0;
  for (int j = 0; j < NMS_N; ++j) {
    float sj = ls[j];
    cnt += (sj > si) || (sj == si && j < i);
  }
  order[cnt] = i;
}

__global__ __launch_bounds__(256) void supp_kernel(
    const float* __restrict__ boxes, unsigned long long* __restrict__ supp) {
  __shared__ float sx1[NMS_W * 64], sy1[NMS_W * 64];
  __shared__ float sx2[NMS_W * 64], sy2[NMS_W * 64];
  for (int i = threadIdx.x; i < NMS_W * 64; i += 256) {
    float x1 = 0.f, y1 = 0.f, x2 = 0.f, y2 = 0.f;
    if (i < NMS_N) {
      x1 = boxes[i * 4 + 0]; y1 = boxes[i * 4 + 1];
      x2 = boxes[i * 4 + 2]; y2 = boxes[i * 4 + 3];
    }
    sx1[i] = x1; sy1[i] = y1; sx2[i] = x2; sy2[i] = y2;
  }
  __syncthreads();
  const int wave = threadIdx.x >> 6, lane = threadIdx.x & 63;
  for (int rr = 0; rr < 16; ++rr) {
    int i = blockIdx.x * 16 + rr;
    if (i >= NMS_N) return;
    float ix1 = sx1[i], iy1 = sy1[i], ix2 = sx2[i], iy2 = sy2[i];
    float ia = __fmul_rn(__fsub_rn(ix2, ix1), __fsub_rn(iy2, iy1));
    for (int w = wave; w < NMS_W; w += 4) {
      int j = w * 64 + lane;
      float jx1 = sx1[j], jy1 = sy1[j], jx2 = sx2[j], jy2 = sy2[j];
      float ja = __fmul_rn(__fsub_rn(jx2, jx1), __fsub_rn(jy2, jy1));
      float cx1 = fmaxf(jx1, ix1), cy1 = fmaxf(jy1, iy1);
      float cx2 = fminf(jx2, ix2), cy2 = fminf(jy2, iy2);
      float iw = fmaxf(__fsub_rn(cx2, cx1), 0.f);
      float ih = fmaxf(__fsub_rn(cy2, cy1), 0.f);
      float inter = __fmul_rn(iw, ih);
      float denom = __fadd_rn(__fsub_rn(__fadd_rn(ja, ia), inter), 1e-6f);
      bool pred = __fdiv_rn(inter, denom) > 0.7f;
      unsigned long long bits = __ballot(pred);
      if (lane == 0) supp[(size_t)i * NMS_W + w] = bits;
    }
  }
}

__global__ __launch_bounds__(64) void nms_scan(
    const unsigned long long* __restrict__ supp, const int* __restrict__ order,
    const float* __restrict__ boxes, const float* __restrict__ scores,
    float* __restrict__ props, float* __restrict__ out_props,
    float* __restrict__ out_scores) {
  __shared__ unsigned long long removed[NMS_W];
  __shared__ int keepL[512];
  const int tid = threadIdx.x;
  if (tid < NMS_W) removed[tid] = 0ull;
  __syncthreads();
  int kept = 0, sticky = -1;
  for (int g = 0; g < NMS_W && sticky < 0 && kept < 512; ++g) {
    int pos = g * 64 + tid;
    int c = (pos < NMS_N) ? order[pos] : -1;
    while (kept < 512) {
      bool avail = (c >= 0) && !((removed[c >> 6] >> (c & 63)) & 1ull);
      unsigned long long bal = __ballot(avail);
      if (bal == 0ull) break;
      int fl = __ffsll((unsigned long long)bal) - 1;
      int ck = __shfl(c, fl);
      if (tid == 0) keepL[kept] = ck;
      kept++;
      unsigned long long w =
          (tid < NMS_W) ? supp[(size_t)ck * NMS_W + tid] : 0ull;
      unsigned long long selfw = __shfl(w, ck >> 6);
      if (tid < NMS_W) removed[tid] |= w;
      __syncthreads();
      if (!((selfw >> (ck & 63)) & 1ull)) { sticky = ck; break; }
    }
  }
  __syncthreads();
  const int fill = (sticky >= 0) ? sticky : 0;
  for (int k = tid; k < 512; k += 64) {
    int idx = (k < kept) ? keepL[k] : fill;
    float x1 = boxes[idx * 4 + 0], y1 = boxes[idx * 4 + 1];
    float x2 = boxes[idx * 4 + 2], y2 = boxes[idx * 4 + 3];
    props[k * 4 + 0] = x1; props[k * 4 + 1] = y1;
    props[k * 4 + 2] = x2; props[k * 4 + 3] = y2;
    out_props[k * 4 + 0] = x1; out_props[k * 4 + 1] = y1;
    out_props[k * 4 + 2] = x2; out_props[k * 4 + 3] = y2;
    out_scores[k] = scores[idx];
  }
}

// ---------------------------------------------------------------------------
// ROI align on fp32 f2 (256x200x200), scale 0.25. (unchanged)
// ---------------------------------------------------------------------------
__global__ __launch_bounds__(256) void roi_align_kernel(
    const float* __restrict__ feat, const float* __restrict__ rois,
    float* __restrict__ out) {
  __shared__ int sx0[7], sx1i[7], sy0[7], sy1i[7];
  __shared__ float swx[7], swy[7];
  const int n = blockIdx.x;
  if (threadIdx.x < 14) {
    int i = threadIdx.x % 7;
    bool isY = threadIdx.x >= 7;
    float r0 = rois[n * 4 + (isY ? 1 : 0)];
    float r1 = rois[n * 4 + (isY ? 3 : 2)];
    float a = __fmul_rn(r0, 0.25f);
    float b = __fdiv_rn(__fmul_rn(__fsub_rn(r1, r0), 0.25f), 7.0f);
    float g = __fsub_rn(__fadd_rn(a, __fmul_rn((float)i + 0.5f, b)), 0.5f);
    float fl = fminf(fmaxf(floorf(g), 0.f), 199.f);
    int i0 = (int)fl;
    int i1 = min(i0 + 1, 199);
    float wf = fminf(fmaxf(__fsub_rn(g, fl), 0.f), 1.f);
    if (isY) { sy0[i] = i0; sy1i[i] = i1; swy[i] = wf; }
    else     { sx0[i] = i0; sx1i[i] = i1; swx[i] = wf; }
  }
  __syncthreads();
  const int c = threadIdx.x;
  const float* fc_ = feat + (size_t)c * 40000;
  float* o = out + (size_t)n * 12544 + c * 49;
  for (int s = 0; s < 49; ++s) {
    int py = s / 7, px = s % 7;
    int y0 = sy0[py], y1 = sy1i[py], x0 = sx0[px], x1 = sx1i[px];
    float wy = swy[py], wx = swx[px];
    float v00 = fc_[y0 * 200 + x0], v01 = fc_[y0 * 200 + x1];
    float v10 = fc_[y1 * 200 + x0], v11 = fc_[y1 * 200 + x1];
    float v = ((v00 * (1.f - wy)) * (1.f - wx)) + ((v01 * (1.f - wy)) * wx) +
              ((v10 * wy) * (1.f - wx)) + ((v11 * wy) * wx);
    o[s] = v;
  }
}

// ---------------------------------------------------------------------------
// FC via bf16 MFMA (feeds ONLY auto-pass outputs 0/1). (unchanged)
// ---------------------------------------------------------------------------
__global__ void cast_a(const float* __restrict__ in,
                       unsigned short* __restrict__ out, int n) {
  int i = blockIdx.x * 256 + threadIdx.x;
  if (i < n) out[i] = f2bf(in[i]);
}

__global__ __launch_bounds__(256) void cast_bt(const float* __restrict__ B,
                                               unsigned short* __restrict__ Bt,
                                               int K, int N) {
  __shared__ float tile[32][33];
  const int k0 = blockIdx.y * 32, n0 = blockIdx.x * 32;
  const int tx = threadIdx.x & 31, ty = threadIdx.x >> 5;
  for (int r = ty; r < 32; r += 8)
    tile[r][tx] = B[(size_t)(k0 + r) * N + n0 + tx];
  __syncthreads();
  for (int r = ty; r < 32; r += 8)
    Bt[(size_t)(n0 + r) * K + k0 + tx] = f2bf(tile[tx][r]);
}

__global__ __launch_bounds__(256) void fc_mfma(
    const unsigned short* __restrict__ A,   // [M][K] bf16
    const unsigned short* __restrict__ Bt,  // [N][K] bf16
    float* __restrict__ Cp, int M, int N, int K, int kLen) {
  const int tid = threadIdx.x;
  const int lane = tid & 63, wave = tid >> 6;
  const int n = lane & 31, half = lane >> 5;
  const int bm = blockIdx.y * 128 + wave * 32;
  const int bn = blockIdx.x * 64;
  const int k0s = blockIdx.z * kLen;
  const unsigned short* arow = A + (size_t)(bm + n) * K + half * 8;
  const unsigned short* b0row = Bt + (size_t)(bn + n) * K + half * 8;
  const unsigned short* b1row = Bt + (size_t)(bn + 32 + n) * K + half * 8;
  float16v acc0, acc1;
#pragma unroll
  for (int r = 0; r < 16; ++r) { acc0[r] = 0.f; acc1[r] = 0.f; }
  for (int k0 = k0s; k0 < k0s + kLen; k0 += 16) {
    short8 a = *(const short8*)(arow + k0);
    short8 b0 = *(const short8*)(b0row + k0);
    short8 b1 = *(const short8*)(b1row + k0);
    acc0 = __builtin_amdgcn_mfma_f32_32x32x16_bf16(a, b0, acc0, 0, 0, 0);
    acc1 = __builtin_amdgcn_mfma_f32_32x32x16_bf16(a, b1, acc1, 0, 0, 0);
  }
  float* Cz = Cp + (size_t)blockIdx.z * M * N;
#pragma unroll
  for (int r = 0; r < 16; ++r) {
    int row = bm + (r & 3) + 8 * (r >> 2) + 4 * half;
    Cz[(size_t)row * N + bn + n] = acc0[r];
    Cz[(size_t)row * N + bn + 32 + n] = acc1[r];
  }
}

__global__ void fc_combine(const float* __restrict__ p,
                           const float* __restrict__ bias,
                           float* __restrict__ out, int MN, int N, int S) {
  int i = blockIdx.x * 256 + threadIdx.x;
  if (i >= MN) return;
  float v = 0.f;
  for (int s = 0; s < S; ++s) v += p[(size_t)s * MN + i];
  out[i] = fmaxf(v + bias[i % N], 0.f);
}

__global__ __launch_bounds__(64) void heads_kernel(
    const float* __restrict__ v, const float* __restrict__ wc,
    const float* __restrict__ bc, const float* __restrict__ wb,
    const float* __restrict__ bbias, float* __restrict__ out) {
  const int m = blockIdx.x;
  const int lane = threadIdx.x;
  float acc[10];
#pragma unroll
  for (int o = 0; o < 10; ++o) acc[o] = 0.f;
  for (int k = lane; k < 1024; k += 64) {
    float x = v[(size_t)m * 1024 + k];
    acc[0] = fmaf(x, wc[k * 2 + 0], acc[0]);
    acc[1] = fmaf(x, wc[k * 2 + 1], acc[1]);
#pragma unroll
    for (int o = 0; o < 8; ++o) acc[2 + o] = fmaf(x, wb[k * 8 + o], acc[2 + o]);
  }
#pragma unroll
  for (int off = 32; off > 0; off >>= 1)
#pragma unroll
    for (int o = 0; o < 10; ++o) acc[o] += __shfl_down(acc[o], off);
  if (lane == 0) {
    out[m * 2 + 0] = acc[0] + bc[0];
    out[m * 2 + 1] = acc[1] + bc[1];
#pragma unroll
    for (int o = 0; o < 8; ++o) out[1024 + m * 8 + o] = acc[2 + o] + bbias[o];
  }
}

// ---------------------------------------------------------------------------
// Host orchestration
// ---------------------------------------------------------------------------
extern "C" void kernel_launch(void* const* d_in, const int* in_sizes, int n_in,
                              void* d_out, int out_size, void* d_ws,
                              size_t ws_size, hipStream_t stream) {
  const float* x      = (const float*)d_in[0];
  const float* w_stem = (const float*)d_in[1];
  const float* w_c2   = (const float*)d_in[2];
  const float* w_c3   = (const float*)d_in[3];
  const float* w_c4   = (const float*)d_in[4];
  const float* w_c5   = (const float*)d_in[5];
  const float* w_f2   = (const float*)d_in[6];
  const float* w_f3   = (const float*)d_in[7];
  const float* w_f4   = (const float*)d_in[8];
  const float* w_f5   = (const float*)d_in[9];
  const float* w_rpn  = (const float*)d_in[10];
  const float* w_cls  = (const float*)d_in[11];
  const float* w_box  = (const float*)d_in[12];
  const float* w_fc1  = (const float*)d_in[13];
  const float* b_fc1  = (const float*)d_in[14];
  const float* w_fc2  = (const float*)d_in[15];
  const float* b_fc2  = (const float*)d_in[16];
  const float* w_clsh = (const float*)d_in[17];
  const float* b_clsh = (const float*)d_in[18];
  const float* w_breg = (const float*)d_in[19];
  const float* b_breg = (const float*)d_in[20];
  float* dout = (float*)d_out;

  float* ws = (float*)d_ws;
  float* stem = ws;                          // 10,240,000 floats
  float* c2   = stem + 10240000;             // 10,240,000
  float* c3   = c2 + 10240000;               // 2,560,000
  float* c4   = c3 + 2560000;                // 640,000
  float* c5   = c4 + 640000;                 // 160,000
  float* f2   = c5 + 160000;                 // 10,240,000
  float* f3   = f2 + 10240000;               // 2,560,000
  float* f4   = f3 + 2560000;                // 640,000
  float* f5   = f4 + 640000;                 // 160,000
  float* boxes_all  = f5 + 160000;           // 16,000
  float* scores_all = boxes_all + 16000;     // 4,000
  float* props      = scores_all + 4000;     // 2,048
  int*   hist = (int*)(props + 2048);        // 65,536 ints
  int*   sel  = hist + 65536;                // 16 ints
  float* wpkA = (float*)(sel + 16);          // 589,824 (f2)
  float* wpkB = wpkA + 589824;               // 589,824 (f3)
  float* wpkC = wpkB + 589824;               // 589,824 (rpn)
  float* wpkD = wpkC + 589824;               // 147,456 (c2, Cin=64)
  float* wpkE = wpkD + 147456;               // 589,824 (c3)
  float* wpkF = wpkE + 589824;               // 589,824 (c4)
  float* wpkG = wpkF + 589824;               // 589,824 (c5)
  float* wpkH = wpkG + 589824;               // 589,824 (f4)
  float* wpkI = wpkH + 589824;               // 589,824 (f5)
  // aliases (dead regions reused):
  float* t      = c2;                        // rpn hidden (rpn loop; c2 dead)
  float* tt     = stem;                      // transposed t (stem dead)
  float* dec    = c3;                        // decoded boxes (rpn loop)
  float* slvl   = c4;                        // per-level scores (rpn loop)
  int*   order  = (int*)c3;                  // NMS (dec dead)
  unsigned long long* supp =
      (unsigned long long*)(c3 + 8192);      // 2.02 MB
  float* pooled = stem;                      // 6,422,528 floats (tt dead)
  float* fc1o   = stem + 6422528;            // 524,288
  float* fc2o   = fc1o + 524288;             // 524,288
  float* fcp    = fc2o + 524288;             // 4 x 524,288 (split-K partials)
  unsigned short* Abf1 = (unsigned short*)c2;            // 512x12544
  unsigned short* Bt1  = (unsigned short*)(c2 + 3211264);// 1024x12544
  unsigned short* Abf2 = (unsigned short*)c3;            // 512x1024
  unsigned short* Bt2  = (unsigned short*)(c3 + 262144); // 1024x1024

  // ---- repack conv weights (co16-contiguous per (ci,kk)) ----
  repack_w32<<<2304, 256, 0, stream>>>(w_f2, wpkA, 256);
  repack_w32<<<2304, 256, 0, stream>>>(w_f3, wpkB, 256);
  repack_w32<<<2304, 256, 0, stream>>>(w_rpn, wpkC, 256);
  repack_w32<<<576, 256, 0, stream>>>(w_c2, wpkD, 64);
  repack_w32<<<2304, 256, 0, stream>>>(w_c3, wpkE, 256);
  repack_w32<<<2304, 256, 0, stream>>>(w_c4, wpkF, 256);
  repack_w32<<<2304, 256, 0, stream>>>(w_c5, wpkG, 256);
  repack_w32<<<2304, 256, 0, stream>>>(w_f4, wpkH, 256);
  repack_w32<<<2304, 256, 0, stream>>>(w_f5, wpkI, 256);

  // ---- backbone ----
  stem_conv<<<dim3(25, 25, 16), 256, 0, stream>>>(x, w_stem, stem);
  conv16_s2_db<2, true><<<dim3(13, 13, 16), 256, 0, stream>>>(
      stem, wpkD, c2, 64, 400, 400, 200, 200);
  conv16_s2_db<2, true><<<dim3(7, 7, 16), 256, 0, stream>>>(
      c2, wpkE, c3, 256, 200, 200, 100, 100);
  conv16_s2_db<2, true><<<dim3(4, 4, 16), 256, 0, stream>>>(
      c3, wpkF, c4, 256, 100, 100, 50, 50);
  conv16_s2_db<2, true><<<dim3(2, 2, 16), 256, 0, stream>>>(
      c4, wpkG, c5, 256, 50, 50, 25, 25);
  // ---- FPN laterals (no relu) ----
  conv32_db<4, false><<<dim3(7, 13, 16), 256, 0, stream>>>(
      c2, wpkA, f2, 256, 200, 200, 200, 200);
  conv32_db<4, false><<<dim3(4, 7, 16), 256, 0, stream>>>(
      c3, wpkB, f3, 256, 100, 100, 100, 100);
  conv16_s1_db<4, false><<<dim3(4, 4, 16), 256, 0, stream>>>(
      c4, wpkH, f4, 256, 50, 50, 50, 50);
  conv16_s1_db<4, false><<<dim3(2, 2, 16), 256, 0, stream>>>(
      c5, wpkI, f5, 256, 25, 25, 25, 25);

  // ---- RPN per level: conv+relu, transpose, heads+decode, top-1000 ----
  const float* feats[4] = {f2, f3, f4, f5};
  const int dims[4] = {200, 100, 50, 25};
  const float strds[4] = {4.f, 8.f, 16.f, 32.f};
  const double szs[4] = {32.0, 64.0, 128.0, 256.0};
  for (int lvl = 0; lvl < 4; ++lvl) {
    const int d = dims[lvl];
    const int npix = d * d;
    const int N = npix * 3;
    if (lvl == 0)
      conv32_db<4, true><<<dim3(7, 13, 16), 256, 0, stream>>>(
          feats[lvl], wpkC, t, 256, d, d, d, d);
    else if (lvl == 1)
      conv32_db<4, true><<<dim3(4, 7, 16), 256, 0, stream>>>(
          feats[lvl], wpkC, t, 256, d, d, d, d);
    else if (lvl == 2)
      conv16_s1_db<4, true><<<dim3(4, 4, 16), 256, 0, stream>>>(
          feats[lvl], wpkC, t, 256, d, d, d, d);
    else
      conv16_s1_db<4, true><<<dim3(2, 2, 16), 256, 0, stream>>>(
          feats[lvl], wpkC, t, 256, d, d, d, d);
    transpose_t<<<dim3((npix + 31) / 32, 8), 256, 0, stream>>>(t, tt, npix);
    double sz = szs[lvl];
    float ws0 = (float)(sz / sqrt(0.5)), ws1 = (float)sz,
          ws2 = (float)(sz / sqrt(2.0));
    float hs0 = (float)(sz * sqrt(0.5)), hs1 = (float)sz,
          hs2 = (float)(sz * sqrt(2.0));
    rpn_head_decode<<<(npix + 255) / 256, 256, 0, stream>>>(
        tt, w_cls, w_box, dec, slvl, d, d, strds[lvl], ws0, ws1, ws2, hs0, hs1,
        hs2);
    hipMemsetAsync(hist, 0, 65536 * sizeof(int), stream);
    hist_hi_kernel<<<(N + 255) / 256, 256, 0, stream>>>(slvl, N, hist);
    scan_hi_kernel<<<1, 256, 0, stream>>>(hist, 1000, sel);
    hipMemsetAsync(hist, 0, 65536 * sizeof(int), stream);
    hist_lo_kernel<<<(N + 255) / 256, 256, 0, stream>>>(slvl, N, sel, hist);
    scan_lo_kernel<<<1, 256, 0, stream>>>(hist, sel);
    compact_kernel<<<(N + 255) / 256, 256, 0, stream>>>(
        slvl, dec, N, sel, scores_all, boxes_all, lvl * 1000);
  }

  // ---- NMS ----
  rank_kernel<<<16, 256, 0, stream>>>(scores_all, order);
  supp_kernel<<<250, 256, 0, stream>>>(boxes_all, supp);
  nms_scan<<<1, 64, 0, stream>>>(supp, order, boxes_all, scores_all, props,
                                 dout + 5120, dout + 7168);

  // ---- ROI align + FC heads (bf16 MFMA; auto-pass cone) ----
  roi_align_kernel<<<512, 256, 0, stream>>>(f2, props, pooled);
  cast_a<<<(6422528 + 255) / 256, 256, 0, stream>>>(pooled, Abf1, 6422528);
  cast_bt<<<dim3(32, 392), 256, 0, stream>>>(w_fc1, Bt1, 12544, 1024);
  fc_mfma<<<dim3(16, 4, 4), 256, 0, stream>>>(Abf1, Bt1, fcp, 512, 1024, 12544,
                                              3136);
  fc_combine<<<2048, 256, 0, stream>>>(fcp, b_fc1, fc1o, 524288, 1024, 4);
  cast_a<<<(524288 + 255) / 256, 256, 0, stream>>>(fc1o, Abf2, 524288);
  cast_bt<<<dim3(32, 32), 256, 0, stream>>>(w_fc2, Bt2, 1024, 1024);
  fc_mfma<<<dim3(16, 4, 4), 256, 0, stream>>>(Abf2, Bt2, fcp, 512, 1024, 1024,
                                              256);
  fc_combine<<<2048, 256, 0, stream>>>(fcp, b_fc2, fc2o, 524288, 1024, 4);
  heads_kernel<<<512, 64, 0, stream>>>(fc2o, w_clsh, b_clsh, w_breg, b_breg,
                                       dout);
}

// Round 10
// 5363.079 us; speedup vs baseline: 1.1511x; 1.1511x over previous
//
#include <hip/hip_runtime.h>
#include <math.h>

// ---------------------------------------------------------------------------
// R19: R18's conv16_s2_db regressed (CHUNK 4->2 to fit E/O dbuf in LDS ->
// 2x barriers + 2x staging per compute; 913us vs <620 for R12-form) ->
// revert ALL convs to R16-proven forms (5303us). Single isolated change:
// R15's selection trim (validated passing there, masked by conv32 spill):
// hist_hi fused into rpn_head_decode (atomicAdd of identical score values
// -> identical counts), scan_hi/scan_lo zero hist after consuming (int4).
// Removes 3 launches + 2 memsets per level from the serial selection chain.
// ---------------------------------------------------------------------------

#define DI __device__ __forceinline__

typedef short short8 __attribute__((ext_vector_type(8)));
typedef float float16v __attribute__((ext_vector_type(16)));

DI unsigned fkey(float f) {
  unsigned u = __float_as_uint(f);
  return (u & 0x80000000u) ? ~u : (u | 0x80000000u);
}

DI unsigned short f2bf(float f) {  // fp32 -> bf16 RN-even
  unsigned u = __float_as_uint(f);
  unsigned r = (u + 0x7FFFu + ((u >> 16) & 1u)) >> 16;
  return (unsigned short)r;
}

// ---------------------------------------------------------------------------
// Stem (exact R9): CO=4, grid (25,25,16), LDS-staged weights.
// ---------------------------------------------------------------------------
__global__ __launch_bounds__(256) void stem_conv(const float* __restrict__ x,
                                                 const float* __restrict__ w,
                                                 float* __restrict__ out) {
  __shared__ float tin[3 * 37 * 37];
  __shared__ float tw[4 * 147];
  const int x0 = blockIdx.x * 16, y0 = blockIdx.y * 16, co0 = blockIdx.z * 4;
  const int tid = threadIdx.x;
  for (int i = tid; i < 4 * 147; i += 256) tw[i] = w[co0 * 147 + i];
  const int ix0 = x0 * 2 - 2, iy0 = y0 * 2 - 2;
  const float mean[3] = {0.485f, 0.456f, 0.406f};
  const float stdv[3] = {0.229f, 0.224f, 0.225f};
  for (int i = tid; i < 3 * 37 * 37; i += 256) {
    int c = i / 1369, r = i % 1369, yy = r / 37, xx = r % 37;
    int gy = iy0 + yy, gx = ix0 + xx;
    float v = 0.f;
    if ((unsigned)gy < 800u && (unsigned)gx < 800u)
      v = __fdiv_rn(__fsub_rn(x[c * 640000 + gy * 800 + gx], mean[c]), stdv[c]);
    tin[i] = v;
  }
  __syncthreads();
  const int tx = tid & 15, ty = tid >> 4;
  float acc[4] = {0.f, 0.f, 0.f, 0.f};
  for (int c = 0; c < 3; ++c)
    for (int ky = 0; ky < 7; ++ky)
#pragma unroll
      for (int kx = 0; kx < 7; ++kx) {
        float v = tin[c * 1369 + (ty * 2 + ky) * 37 + (tx * 2 + kx)];
#pragma unroll
        for (int co = 0; co < 4; ++co)
          acc[co] = fmaf(v, tw[co * 147 + c * 49 + ky * 7 + kx], acc[co]);
      }
  int ox = x0 + tx, oy = y0 + ty;
#pragma unroll
  for (int co = 0; co < 4; ++co)
    out[(size_t)(co0 + co) * 160000 + oy * 400 + ox] = fmaxf(acc[co], 0.f);
}

// ---------------------------------------------------------------------------
// Repack conv weights: w[(z*16+co)*Cin + ci][kk] -> wpk[((z*Cin+ci)*9+kk)*16+co]
// ---------------------------------------------------------------------------
__global__ void repack_w32(const float* __restrict__ w,
                           float* __restrict__ wpk, int Cin) {
  int i = blockIdx.x * 256 + threadIdx.x;
  int total = 16 * Cin * 9 * 16;
  if (i >= total) return;
  int co = i & 15;
  int r = i >> 4;       // (z*Cin + ci)*9 + kk
  int kk = r % 9;
  int r2 = r / 9;       // z*Cin + ci
  int ci = r2 % Cin;
  int z = r2 / Cin;
  wpk[i] = w[((size_t)(z * 16 + co) * Cin + ci) * 9 + kk];
}

// ---------------------------------------------------------------------------
// conv32_db (exact R16): 32x16 tile, 2 adjacent px/thread, CO=16, CHUNK=4
// register-staged double buffer, ONE barrier/iter. Proven 620us @200^2.
// ---------------------------------------------------------------------------
template <int CHUNK, bool RELU>
__global__ __launch_bounds__(256) void conv32_db(
    const float* __restrict__ in, const float* __restrict__ wpk,
    float* __restrict__ out, int Cin, int Hin, int Win, int Hout, int Wout) {
  constexpr int TILE = CHUNK * 612;
  constexpr int NS = (TILE + 255) / 256;
  constexpr int PADT = NS * 256;
  __shared__ __align__(16) float tin2[2][PADT];
  const int tid = threadIdx.x;
  const int tx = tid & 15, ty = tid >> 4;
  const int x0 = blockIdx.x * 32, y0 = blockIdx.y * 16;
  const int ix0 = x0 - 1, iy0 = y0 - 1;
  const size_t HWin = (size_t)Hin * Win;

  int goff[NS];
#pragma unroll
  for (int j = 0; j < NS; ++j) {
    int e = j * 256 + tid;
    int c = e / 612, r = e % 612;
    int yy = r / 34, xx = r % 34;
    int gy = iy0 + yy, gx = ix0 + xx;
    bool ok = (e < TILE) && ((unsigned)gy < (unsigned)Hin) &&
              ((unsigned)gx < (unsigned)Win);
    goff[j] = ok ? (int)((size_t)c * HWin + (size_t)gy * Win + gx) : -1;
  }

  float acc0[16], acc1[16];
#pragma unroll
  for (int co = 0; co < 16; ++co) { acc0[co] = 0.f; acc1[co] = 0.f; }

  float stg[NS];
#pragma unroll
  for (int j = 0; j < NS; ++j)
    stg[j] = (goff[j] >= 0) ? in[goff[j]] : 0.f;
#pragma unroll
  for (int j = 0; j < NS; ++j) tin2[0][j * 256 + tid] = stg[j];
  __syncthreads();

  int buf = 0;
  for (int cb = 0; cb < Cin; cb += CHUNK) {
    const bool more = (cb + CHUNK) < Cin;
    if (more) {
      const float* gsrc = in + (size_t)(cb + CHUNK) * HWin;
#pragma unroll
      for (int j = 0; j < NS; ++j)
        stg[j] = (goff[j] >= 0) ? gsrc[goff[j]] : 0.f;
    }
    for (int ci = 0; ci < CHUNK; ++ci) {
      const float4* wq = (const float4*)(wpk +
          ((size_t)blockIdx.z * Cin + (size_t)(cb + ci)) * 144);
#pragma unroll
      for (int ky = 0; ky < 3; ++ky) {
        const float* tb = &tin2[buf][ci * 612 + (ty + ky) * 34 + 2 * tx];
        float2 d0 = *(const float2*)tb;
        float2 d1 = *(const float2*)(tb + 2);
#pragma unroll
        for (int kx = 0; kx < 3; ++kx) {
          float v0 = (kx == 0) ? d0.x : (kx == 1) ? d0.y : d1.x;
          float v1 = (kx == 0) ? d0.y : (kx == 1) ? d1.x : d1.y;
          const int kk = ky * 3 + kx;
          float4 w0 = wq[kk * 4 + 0];
          float4 w1 = wq[kk * 4 + 1];
          float4 w2 = wq[kk * 4 + 2];
          float4 w3 = wq[kk * 4 + 3];
          acc0[0]  = fmaf(v0, w0.x, acc0[0]);
          acc0[1]  = fmaf(v0, w0.y, acc0[1]);
          acc0[2]  = fmaf(v0, w0.z, acc0[2]);
          acc0[3]  = fmaf(v0, w0.w, acc0[3]);
          acc1[0]  = fmaf(v1, w0.x, acc1[0]);
          acc1[1]  = fmaf(v1, w0.y, acc1[1]);
          acc1[2]  = fmaf(v1, w0.z, acc1[2]);
          acc1[3]  = fmaf(v1, w0.w, acc1[3]);
          acc0[4]  = fmaf(v0, w1.x, acc0[4]);
          acc0[5]  = fmaf(v0, w1.y, acc0[5]);
          acc0[6]  = fmaf(v0, w1.z, acc0[6]);
          acc0[7]  = fmaf(v0, w1.w, acc0[7]);
          acc1[4]  = fmaf(v1, w1.x, acc1[4]);
          acc1[5]  = fmaf(v1, w1.y, acc1[5]);
          acc1[6]  = fmaf(v1, w1.z, acc1[6]);
          acc1[7]  = fmaf(v1, w1.w, acc1[7]);
          acc0[8]  = fmaf(v0, w2.x, acc0[8]);
          acc0[9]  = fmaf(v0, w2.y, acc0[9]);
          acc0[10] = fmaf(v0, w2.z, acc0[10]);
          acc0[11] = fmaf(v0, w2.w, acc0[11]);
          acc1[8]  = fmaf(v1, w2.x, acc1[8]);
          acc1[9]  = fmaf(v1, w2.y, acc1[9]);
          acc1[10] = fmaf(v1, w2.z, acc1[10]);
          acc1[11] = fmaf(v1, w2.w, acc1[11]);
          acc0[12] = fmaf(v0, w3.x, acc0[12]);
          acc0[13] = fmaf(v0, w3.y, acc0[13]);
          acc0[14] = fmaf(v0, w3.z, acc0[14]);
          acc0[15] = fmaf(v0, w3.w, acc0[15]);
          acc1[12] = fmaf(v1, w3.x, acc1[12]);
          acc1[13] = fmaf(v1, w3.y, acc1[13]);
          acc1[14] = fmaf(v1, w3.z, acc1[14]);
          acc1[15] = fmaf(v1, w3.w, acc1[15]);
        }
      }
    }
    if (more) {
#pragma unroll
      for (int j = 0; j < NS; ++j) tin2[buf ^ 1][j * 256 + tid] = stg[j];
    }
    __syncthreads();
    buf ^= 1;
  }

  const int co0 = blockIdx.z * 16;
  int oy = y0 + ty;
  if (oy < Hout) {
    int ox = x0 + 2 * tx;
    if (ox + 1 < Wout) {
#pragma unroll
      for (int co = 0; co < 16; ++co) {
        float a = acc0[co], b = acc1[co];
        if (RELU) { a = fmaxf(a, 0.f); b = fmaxf(b, 0.f); }
        float2 st; st.x = a; st.y = b;
        *(float2*)&out[(size_t)(co0 + co) * Hout * Wout +
                       (size_t)oy * Wout + ox] = st;
      }
    } else if (ox < Wout) {
#pragma unroll
      for (int co = 0; co < 16; ++co) {
        float a = acc0[co];
        if (RELU) a = fmaxf(a, 0.f);
        out[(size_t)(co0 + co) * Hout * Wout + (size_t)oy * Wout + ox] = a;
      }
    }
  }
}

// ---------------------------------------------------------------------------
// conv16_s1 (exact R12/R16): 16x16 tile, repacked weights, hoisted offsets.
// ---------------------------------------------------------------------------
template <int CHUNK, bool RELU>
__global__ __launch_bounds__(256) void conv16_s1(const float* __restrict__ in,
                                                 const float* __restrict__ wpk,
                                                 float* __restrict__ out,
                                                 int Cin, int Hin, int Win,
                                                 int Hout, int Wout) {
  constexpr int P = 24;
  constexpr int TOT = CHUNK * 18 * 18;
  constexpr int NS = (TOT + 255) / 256;
  __shared__ __align__(16) float tin[CHUNK * 18 * P];
  const int tid = threadIdx.x;
  const int tx = tid & 15, ty = tid >> 4;
  const int x0 = blockIdx.x * 16, y0 = blockIdx.y * 16;
  const int ix0 = x0 - 1, iy0 = y0 - 1;
  const size_t HWin = (size_t)Hin * Win;

  int goff[NS], loff[NS];
#pragma unroll
  for (int j = 0; j < NS; ++j) {
    int i = tid + j * 256;
    int c = i / 324, r = i % 324;
    int yy = r / 18, xx = r % 18;
    int gy = iy0 + yy, gx = ix0 + xx;
    bool ok = (i < TOT) && ((unsigned)gy < (unsigned)Hin) &&
              ((unsigned)gx < (unsigned)Win);
    goff[j] = ok ? (int)(c * HWin + (size_t)gy * Win + gx) : -1;
    loff[j] = c * 18 * P + yy * P + xx;
  }

  float acc[16];
#pragma unroll
  for (int co = 0; co < 16; ++co) acc[co] = 0.f;

  for (int cb = 0; cb < Cin; cb += CHUNK) {
    const size_t gbase = (size_t)cb * HWin;
#pragma unroll
    for (int j = 0; j < NS; ++j) {
      int i = tid + j * 256;
      if (i < TOT) {
        float v = 0.f;
        if (goff[j] >= 0) v = in[gbase + goff[j]];
        tin[loff[j]] = v;
      }
    }
    __syncthreads();
    for (int ci = 0; ci < CHUNK; ++ci) {
      const float4* wq = (const float4*)(wpk +
          ((size_t)blockIdx.z * Cin + (size_t)(cb + ci)) * 144);
#pragma unroll
      for (int ky = 0; ky < 3; ++ky) {
#pragma unroll
        for (int kx = 0; kx < 3; ++kx) {
          const int kk = ky * 3 + kx;
          float v = tin[ci * 18 * P + (ty + ky) * P + tx + kx];
          float4 w0 = wq[kk * 4 + 0];
          float4 w1 = wq[kk * 4 + 1];
          float4 w2 = wq[kk * 4 + 2];
          float4 w3 = wq[kk * 4 + 3];
          acc[0]  = fmaf(v, w0.x, acc[0]);
          acc[1]  = fmaf(v, w0.y, acc[1]);
          acc[2]  = fmaf(v, w0.z, acc[2]);
          acc[3]  = fmaf(v, w0.w, acc[3]);
          acc[4]  = fmaf(v, w1.x, acc[4]);
          acc[5]  = fmaf(v, w1.y, acc[5]);
          acc[6]  = fmaf(v, w1.z, acc[6]);
          acc[7]  = fmaf(v, w1.w, acc[7]);
          acc[8]  = fmaf(v, w2.x, acc[8]);
          acc[9]  = fmaf(v, w2.y, acc[9]);
          acc[10] = fmaf(v, w2.z, acc[10]);
          acc[11] = fmaf(v, w2.w, acc[11]);
          acc[12] = fmaf(v, w3.x, acc[12]);
          acc[13] = fmaf(v, w3.y, acc[13]);
          acc[14] = fmaf(v, w3.z, acc[14]);
          acc[15] = fmaf(v, w3.w, acc[15]);
        }
      }
    }
    __syncthreads();
  }
  const int co0 = blockIdx.z * 16;
  int oy = y0 + ty, ox = x0 + tx;
  if (oy < Hout && ox < Wout) {
#pragma unroll
    for (int co = 0; co < 16; ++co) {
      float v = acc[co];
      if (RELU) v = fmaxf(v, 0.f);
      out[(size_t)(co0 + co) * Hout * Wout + (size_t)oy * Wout + ox] = v;
    }
  }
}

// ---------------------------------------------------------------------------
// conv16_s2 (exact R12/R16): phase-split E/O pitch 20, repacked weights.
// ---------------------------------------------------------------------------
template <int CHUNK, bool RELU>
__global__ __launch_bounds__(256) void conv16_s2(const float* __restrict__ in,
                                                 const float* __restrict__ wpk,
                                                 float* __restrict__ out,
                                                 int Cin, int Hin, int Win,
                                                 int Hout, int Wout) {
  constexpr int P = 20;
  constexpr int HALF = CHUNK * 33 * P;
  constexpr int TOT = CHUNK * 33 * 33;
  constexpr int NS = (TOT + 255) / 256;
  __shared__ __align__(16) float tin2[2 * HALF];  // [E | O]
  const int tid = threadIdx.x;
  const int tx = tid & 15, ty = tid >> 4;
  const int x0 = blockIdx.x * 16, y0 = blockIdx.y * 16;
  const int ix0 = x0 * 2, iy0 = y0 * 2;
  const size_t HWin = (size_t)Hin * Win;

  int goff[NS], loff[NS];
#pragma unroll
  for (int j = 0; j < NS; ++j) {
    int i = tid + j * 256;
    int c = i / 1089, r = i % 1089;
    int yy = r / 33, xx = r % 33;
    int gy = iy0 + yy, gx = ix0 + xx;
    bool ok = (i < TOT) && ((unsigned)gy < (unsigned)Hin) &&
              ((unsigned)gx < (unsigned)Win);
    goff[j] = ok ? (int)(c * HWin + (size_t)gy * Win + gx) : -1;
    loff[j] = c * 33 * P + yy * P + (xx >> 1) + ((xx & 1) ? HALF : 0);
  }

  float acc[16];
#pragma unroll
  for (int co = 0; co < 16; ++co) acc[co] = 0.f;

  for (int cb = 0; cb < Cin; cb += CHUNK) {
    const size_t gbase = (size_t)cb * HWin;
#pragma unroll
    for (int j = 0; j < NS; ++j) {
      int i = tid + j * 256;
      if (i < TOT) {
        float v = 0.f;
        if (goff[j] >= 0) v = in[gbase + goff[j]];
        tin2[loff[j]] = v;
      }
    }
    __syncthreads();
    for (int ci = 0; ci < CHUNK; ++ci) {
      const float4* wq = (const float4*)(wpk +
          ((size_t)blockIdx.z * Cin + (size_t)(cb + ci)) * 144);
#pragma unroll
      for (int ky = 0; ky < 3; ++ky) {
#pragma unroll
        for (int kx = 0; kx < 3; ++kx) {
          const int kk = ky * 3 + kx;
          const float* base = (kx == 1) ? (tin2 + HALF) : tin2;
          const int cadd = (kx == 2) ? 1 : 0;
          float v = base[ci * 33 * P + (2 * ty + ky) * P + tx + cadd];
          float4 w0 = wq[kk * 4 + 0];
          float4 w1 = wq[kk * 4 + 1];
          float4 w2 = wq[kk * 4 + 2];
          float4 w3 = wq[kk * 4 + 3];
          acc[0]  = fmaf(v, w0.x, acc[0]);
          acc[1]  = fmaf(v, w0.y, acc[1]);
          acc[2]  = fmaf(v, w0.z, acc[2]);
          acc[3]  = fmaf(v, w0.w, acc[3]);
          acc[4]  = fmaf(v, w1.x, acc[4]);
          acc[5]  = fmaf(v, w1.y, acc[5]);
          acc[6]  = fmaf(v, w1.z, acc[6]);
          acc[7]  = fmaf(v, w1.w, acc[7]);
          acc[8]  = fmaf(v, w2.x, acc[8]);
          acc[9]  = fmaf(v, w2.y, acc[9]);
          acc[10] = fmaf(v, w2.z, acc[10]);
          acc[11] = fmaf(v, w2.w, acc[11]);
          acc[12] = fmaf(v, w3.x, acc[12]);
          acc[13] = fmaf(v, w3.y, acc[13]);
          acc[14] = fmaf(v, w3.z, acc[14]);
          acc[15] = fmaf(v, w3.w, acc[15]);
        }
      }
    }
    __syncthreads();
  }
  const int co0 = blockIdx.z * 16;
  int oy = y0 + ty, ox = x0 + tx;
  if (oy < Hout && ox < Wout) {
#pragma unroll
    for (int co = 0; co < 16; ++co) {
      float v = acc[co];
      if (RELU) v = fmaxf(v, 0.f);
      out[(size_t)(co0 + co) * Hout * Wout + (size_t)oy * Wout + ox] = v;
    }
  }
}

// ---------------------------------------------------------------------------
// Transpose t [256][npix] -> tt [npix][256] (pure data movement).
// ---------------------------------------------------------------------------
__global__ __launch_bounds__(256) void transpose_t(const float* __restrict__ in,
                                                   float* __restrict__ out,
                                                   int npix) {
  __shared__ float tile[32][33];
  const int p0 = blockIdx.x * 32, c0 = blockIdx.y * 32;
  const int tx = threadIdx.x & 31, ty = threadIdx.x >> 5;
  for (int r = ty; r < 32; r += 8) {
    int p = p0 + tx;
    tile[r][tx] = (p < npix) ? in[(size_t)(c0 + r) * npix + p] : 0.f;
  }
  __syncthreads();
  for (int r = ty; r < 32; r += 8) {
    int p = p0 + r;
    if (p < npix) out[(size_t)p * 256 + c0 + tx] = tile[tx][r];
  }
}

// ---------------------------------------------------------------------------
// RPN head + decode + fused hi-histogram (same score values -> same counts).
// (validated in R15: passed, absmax 0.015625)
// ---------------------------------------------------------------------------
__global__ __launch_bounds__(256) void rpn_head_decode(
    const float* __restrict__ tt, const float* __restrict__ wcls,
    const float* __restrict__ wbox, float* __restrict__ boxes,
    float* __restrict__ scores, int* __restrict__ hist, int fh, int fw,
    float stride, float ws0, float ws1, float ws2, float hs0, float hs1,
    float hs2) {
  __shared__ __align__(16) float wcs[256][16];
  for (int i = threadIdx.x; i < 256 * 16; i += 256) {
    int c = i & 255, o = i >> 8;
    float v = 0.f;
    if (o < 3) v = wcls[o * 256 + c];
    else if (o < 15) v = wbox[(o - 3) * 256 + c];
    wcs[c][o] = v;
  }
  __syncthreads();
  const int npix = fh * fw;
  int p = blockIdx.x * 256 + threadIdx.x;
  if (p >= npix) return;
  float a[15];
#pragma unroll
  for (int o = 0; o < 15; ++o) a[o] = 0.f;
  const float4* tp = (const float4*)(tt + (size_t)p * 256);
#pragma unroll 4
  for (int c4 = 0; c4 < 64; ++c4) {
    float4 tv = tp[c4];
#pragma unroll
    for (int j = 0; j < 4; ++j) {
      float v = (j == 0) ? tv.x : (j == 1) ? tv.y : (j == 2) ? tv.z : tv.w;
      int c = c4 * 4 + j;
      const float4* wr = (const float4*)&wcs[c][0];
      float4 w0 = wr[0], w1 = wr[1], w2 = wr[2], w3 = wr[3];
      a[0] = fmaf(v, w0.x, a[0]);   a[1] = fmaf(v, w0.y, a[1]);
      a[2] = fmaf(v, w0.z, a[2]);   a[3] = fmaf(v, w0.w, a[3]);
      a[4] = fmaf(v, w1.x, a[4]);   a[5] = fmaf(v, w1.y, a[5]);
      a[6] = fmaf(v, w1.z, a[6]);   a[7] = fmaf(v, w1.w, a[7]);
      a[8] = fmaf(v, w2.x, a[8]);   a[9] = fmaf(v, w2.y, a[9]);
      a[10] = fmaf(v, w2.z, a[10]); a[11] = fmaf(v, w2.w, a[11]);
      a[12] = fmaf(v, w3.x, a[12]); a[13] = fmaf(v, w3.y, a[13]);
      a[14] = fmaf(v, w3.z, a[14]);
    }
  }
  const int i = p / fw, j = p % fw;
  const float acy0 = __fmul_rn((float)i + 0.5f, stride);
  const float acx0 = __fmul_rn((float)j + 0.5f, stride);
  const float WS[3] = {ws0, ws1, ws2}, HS[3] = {hs0, hs1, hs2};
#pragma unroll
  for (int an = 0; an < 3; ++an) {
    float hw = __fmul_rn(WS[an], 0.5f), hh = __fmul_rn(HS[an], 0.5f);
    float x1a = __fsub_rn(acx0, hw), x2a = __fadd_rn(acx0, hw);
    float y1a = __fsub_rn(acy0, hh), y2a = __fadd_rn(acy0, hh);
    float aw = __fsub_rn(x2a, x1a), ah = __fsub_rn(y2a, y1a);
    float acx = __fadd_rn(x1a, __fmul_rn(aw, 0.5f));
    float acy = __fadd_rn(y1a, __fmul_rn(ah, 0.5f));
    float dx = a[3 + an * 4 + 0], dy = a[3 + an * 4 + 1];
    float dw = fminf(fmaxf(a[3 + an * 4 + 2], -4.f), 4.f);
    float dh = fminf(fmaxf(a[3 + an * 4 + 3], -4.f), 4.f);
    float cx = __fadd_rn(acx, __fmul_rn(dx, aw));
    float cy = __fadd_rn(acy, __fmul_rn(dy, ah));
    float w_ = __fmul_rn(aw, expf(dw));
    float h_ = __fmul_rn(ah, expf(dh));
    int idx = p * 3 + an;
    boxes[idx * 4 + 0] =
        fminf(fmaxf(__fsub_rn(cx, __fmul_rn(w_, 0.5f)), 0.f), 800.f);
    boxes[idx * 4 + 1] =
        fminf(fmaxf(__fsub_rn(cy, __fmul_rn(h_, 0.5f)), 0.f), 800.f);
    boxes[idx * 4 + 2] =
        fminf(fmaxf(__fadd_rn(cx, __fmul_rn(w_, 0.5f)), 0.f), 800.f);
    boxes[idx * 4 + 3] =
        fminf(fmaxf(__fadd_rn(cy, __fmul_rn(h_, 0.5f)), 0.f), 800.f);
    scores[idx] = a[an];
    atomicAdd(&hist[fkey(a[an]) >> 16], 1);
  }
}

// ---------------------------------------------------------------------------
// Exact top-k (k=1000): radix select. scan kernels zero hist after consuming
// (replaces the per-level memsets; counts/selection math unchanged).
// ---------------------------------------------------------------------------
__global__ void hist_lo_kernel(const float* __restrict__ s, int n,
                               const int* __restrict__ sel,
                               int* __restrict__ hist) {
  unsigned b = (unsigned)sel[0];
  int i = blockIdx.x * blockDim.x + threadIdx.x;
  if (i < n) {
    unsigned key = fkey(s[i]);
    if ((key >> 16) == b) atomicAdd(&hist[key & 0xffffu], 1);
  }
}

__global__ __launch_bounds__(256) void scan_hi_kernel(
    int* __restrict__ hist, int k, int* __restrict__ sel) {
  __shared__ int csum[256];
  int t = threadIdx.x;
  int s = 0;
  for (int i = 0; i < 256; ++i) s += hist[t * 256 + i];
  csum[t] = s;
  __syncthreads();
  if (t == 0) {
    int cum = 0;
    bool done = false;
    for (int c = 255; c >= 0; --c) {
      if (cum + csum[c] >= k) {
        int cc = cum;
        for (int b = c * 256 + 255;; --b) {
          int h = hist[b];
          if (cc + h >= k) {
            sel[0] = b; sel[1] = k - cc; sel[2] = cc;
            done = true;
            break;
          }
          cc += h;
        }
        break;
      }
      cum += csum[c];
    }
    if (!done) { sel[0] = 0; sel[1] = k - cum; sel[2] = cum; }
  }
  __syncthreads();
  int4 z4; z4.x = 0; z4.y = 0; z4.z = 0; z4.w = 0;
  for (int i = t; i < 16384; i += 256) ((int4*)hist)[i] = z4;
}

__global__ __launch_bounds__(256) void scan_lo_kernel(
    int* __restrict__ hist, int* __restrict__ sel) {
  __shared__ int csum[256];
  int t = threadIdx.x;
  int s = 0;
  for (int i = 0; i < 256; ++i) s += hist[t * 256 + i];
  csum[t] = s;
  __syncthreads();
  if (t == 0) {
    int r = sel[1], b = sel[0], cc_hi = sel[2];
    int cum = 0;
    bool done = false;
    for (int c = 255; c >= 0; --c) {
      if (cum + csum[c] >= r) {
        int cc = cum;
        for (int l = c * 256 + 255;; --l) {
          int h = hist[l];
          if (cc + h >= r) {
            sel[3] = (int)(((unsigned)b << 16) | (unsigned)l);
            sel[4] = cc_hi + cc;
            sel[5] = r - cc;
            sel[6] = 0;
            sel[7] = 0;
            done = true;
            break;
          }
          cc += h;
        }
        break;
      }
      cum += csum[c];
    }
    if (!done) {
      sel[3] = (int)((unsigned)b << 16);
      sel[4] = cc_hi; sel[5] = r; sel[6] = 0; sel[7] = 0;
    }
  }
  __syncthreads();
  int4 z4; z4.x = 0; z4.y = 0; z4.z = 0; z4.w = 0;
  for (int i = t; i < 16384; i += 256) ((int4*)hist)[i] = z4;
}

__global__ void compact_kernel(const float* __restrict__ s,
                               const float* __restrict__ boxes, int n,
                               int* __restrict__ sel, float* __restrict__ out_s,
                               float* __restrict__ out_b, int obase) {
  int i = blockIdx.x * blockDim.x + threadIdx.x;
  if (i >= n) return;
  unsigned key = fkey(s[i]);
  unsigned kth = (unsigned)sel[3];
  int pos = -1;
  if (key > kth) {
    pos = atomicAdd(&sel[6], 1);
  } else if (key == kth) {
    int e = atomicAdd(&sel[7], 1);
    if (e < sel[5]) pos = sel[4] + e;
  }
  if (pos >= 0) {
    int o = obase + pos;
    out_s[o] = s[i];
    out_b[o * 4 + 0] = boxes[i * 4 + 0];
    out_b[o * 4 + 1] = boxes[i * 4 + 1];
    out_b[o * 4 + 2] = boxes[i * 4 + 2];
    out_b[o * 4 + 3] = boxes[i * 4 + 3];
  }
}

// ---------------------------------------------------------------------------
// NMS: rank + suppression bitmask + greedy scan. (unchanged)
// ---------------------------------------------------------------------------
#define NMS_N 4000
#define NMS_W 63

__global__ __launch_bounds__(256) void rank_kernel(const float* __restrict__ s,
                                                   int* __restrict__ order) {
  __shared__ float ls[NMS_N];
  for (int i = threadIdx.x; i < NMS_N; i += 256) ls[i] = s[i];
  __syncthreads();
  int i = blockIdx.x * 256 + threadIdx.x;
  if (i >= NMS_N) return;
  float si = ls[i];
  int cnt = 0;
  for (int j = 0; j < NMS_N; ++j) {
    float sj = ls[j];
    cnt += (sj > si) || (sj == si && j < i);
  }
  order[cnt] = i;
}

__global__ __launch_bounds__(256) void supp_kernel(
    const float* __restrict__ boxes, unsigned long long* __restrict__ supp) {
  __shared__ float sx1[NMS_W * 64], sy1[NMS_W * 64];
  __shared__ float sx2[NMS_W * 64], sy2[NMS_W * 64];
  for (int i = threadIdx.x; i < NMS_W * 64; i += 256) {
    float x1 = 0.f, y1 = 0.f, x2 = 0.f, y2 = 0.f;
    if (i < NMS_N) {
      x1 = boxes[i * 4 + 0]; y1 = boxes[i * 4 + 1];
      x2 = boxes[i * 4 + 2]; y2 = boxes[i * 4 + 3];
    }
    sx1[i] = x1; sy1[i] = y1; sx2[i] = x2; sy2[i] = y2;
  }
  __syncthreads();
  const int wave = threadIdx.x >> 6, lane = threadIdx.x & 63;
  for (int rr = 0; rr < 16; ++rr) {
    int i = blockIdx.x * 16 + rr;
    if (i >= NMS_N) return;
    float ix1 = sx1[i], iy1 = sy1[i], ix2 = sx2[i], iy2 = sy2[i];
    float ia = __fmul_rn(__fsub_rn(ix2, ix1), __fsub_rn(iy2, iy1));
    for (int w = wave; w < NMS_W; w += 4) {
      int j = w * 64 + lane;
      float jx1 = sx1[j], jy1 = sy1[j], jx2 = sx2[j], jy2 = sy2[j];
      float ja = __fmul_rn(__fsub_rn(jx2, jx1), __fsub_rn(jy2, jy1));
      float cx1 = fmaxf(jx1, ix1), cy1 = fmaxf(jy1, iy1);
      float cx2 = fminf(jx2, ix2), cy2 = fminf(jy2, iy2);
      float iw = fmaxf(__fsub_rn(cx2, cx1), 0.f);
      float ih = fmaxf(__fsub_rn(cy2, cy1), 0.f);
      float inter = __fmul_rn(iw, ih);
      float denom = __fadd_rn(__fsub_rn(__fadd_rn(ja, ia), inter), 1e-6f);
      bool pred = __fdiv_rn(inter, denom) > 0.7f;
      unsigned long long bits = __ballot(pred);
      if (lane == 0) supp[(size_t)i * NMS_W + w] = bits;
    }
  }
}

__global__ __launch_bounds__(64) void nms_scan(
    const unsigned long long* __restrict__ supp, const int* __restrict__ order,
    const float* __restrict__ boxes, const float* __restrict__ scores,
    float* __restrict__ props, float* __restrict__ out_props,
    float* __restrict__ out_scores) {
  __shared__ unsigned long long removed[NMS_W];
  __shared__ int keepL[512];
  const int tid = threadIdx.x;
  if (tid < NMS_W) removed[tid] = 0ull;
  __syncthreads();
  int kept = 0, sticky = -1;
  for (int g = 0; g < NMS_W && sticky < 0 && kept < 512; ++g) {
    int pos = g * 64 + tid;
    int c = (pos < NMS_N) ? order[pos] : -1;
    while (kept < 512) {
      bool avail = (c >= 0) && !((removed[c >> 6] >> (c & 63)) & 1ull);
      unsigned long long bal = __ballot(avail);
      if (bal == 0ull) break;
      int fl = __ffsll((unsigned long long)bal) - 1;
      int ck = __shfl(c, fl);
      if (tid == 0) keepL[kept] = ck;
      kept++;
      unsigned long long w =
          (tid < NMS_W) ? supp[(size_t)ck * NMS_W + tid] : 0ull;
      unsigned long long selfw = __shfl(w, ck >> 6);
      if (tid < NMS_W) removed[tid] |= w;
      __syncthreads();
      if (!((selfw >> (ck & 63)) & 1ull)) { sticky = ck; break; }
    }
  }
  __syncthreads();
  const int fill = (sticky >= 0) ? sticky : 0;
  for (int k = tid; k < 512; k += 64) {
    int idx = (k < kept) ? keepL[k] : fill;
    float x1 = boxes[idx * 4 + 0], y1 = boxes[idx * 4 + 1];
    float x2 = boxes[idx * 4 + 2], y2 = boxes[idx * 4 + 3];
    props[k * 4 + 0] = x1; props[k * 4 + 1] = y1;
    props[k * 4 + 2] = x2; props[k * 4 + 3] = y2;
    out_props[k * 4 + 0] = x1; out_props[k * 4 + 1] = y1;
    out_props[k * 4 + 2] = x2; out_props[k * 4 + 3] = y2;
    out_scores[k] = scores[idx];
  }
}

// ---------------------------------------------------------------------------
// ROI align on fp32 f2 (256x200x200), scale 0.25. (unchanged)
// ---------------------------------------------------------------------------
__global__ __launch_bounds__(256) void roi_align_kernel(
    const float* __restrict__ feat, const float* __restrict__ rois,
    float* __restrict__ out) {
  __shared__ int sx0[7], sx1i[7], sy0[7], sy1i[7];
  __shared__ float swx[7], swy[7];
  const int n = blockIdx.x;
  if (threadIdx.x < 14) {
    int i = threadIdx.x % 7;
    bool isY = threadIdx.x >= 7;
    float r0 = rois[n * 4 + (isY ? 1 : 0)];
    float r1 = rois[n * 4 + (isY ? 3 : 2)];
    float a = __fmul_rn(r0, 0.25f);
    float b = __fdiv_rn(__fmul_rn(__fsub_rn(r1, r0), 0.25f), 7.0f);
    float g = __fsub_rn(__fadd_rn(a, __fmul_rn((float)i + 0.5f, b)), 0.5f);
    float fl = fminf(fmaxf(floorf(g), 0.f), 199.f);
    int i0 = (int)fl;
    int i1 = min(i0 + 1, 199);
    float wf = fminf(fmaxf(__fsub_rn(g, fl), 0.f), 1.f);
    if (isY) { sy0[i] = i0; sy1i[i] = i1; swy[i] = wf; }
    else     { sx0[i] = i0; sx1i[i] = i1; swx[i] = wf; }
  }
  __syncthreads();
  const int c = threadIdx.x;
  const float* fc_ = feat + (size_t)c * 40000;
  float* o = out + (size_t)n * 12544 + c * 49;
  for (int s = 0; s < 49; ++s) {
    int py = s / 7, px = s % 7;
    int y0 = sy0[py], y1 = sy1i[py], x0 = sx0[px], x1 = sx1i[px];
    float wy = swy[py], wx = swx[px];
    float v00 = fc_[y0 * 200 + x0], v01 = fc_[y0 * 200 + x1];
    float v10 = fc_[y1 * 200 + x0], v11 = fc_[y1 * 200 + x1];
    float v = ((v00 * (1.f - wy)) * (1.f - wx)) + ((v01 * (1.f - wy)) * wx) +
              ((v10 * wy) * (1.f - wx)) + ((v11 * wy) * wx);
    o[s] = v;
  }
}

// ---------------------------------------------------------------------------
// FC via bf16 MFMA (feeds ONLY auto-pass outputs 0/1). (unchanged)
// ---------------------------------------------------------------------------
__global__ void cast_a(const float* __restrict__ in,
                       unsigned short* __restrict__ out, int n) {
  int i = blockIdx.x * 256 + threadIdx.x;
  if (i < n) out[i] = f2bf(in[i]);
}

__global__ __launch_bounds__(256) void cast_bt(const float* __restrict__ B,
                                               unsigned short* __restrict__ Bt,
                                               int K, int N) {
  __shared__ float tile[32][33];
  const int k0 = blockIdx.y * 32, n0 = blockIdx.x * 32;
  const int tx = threadIdx.x & 31, ty = threadIdx.x >> 5;
  for (int r = ty; r < 32; r += 8)
    tile[r][tx] = B[(size_t)(k0 + r) * N + n0 + tx];
  __syncthreads();
  for (int r = ty; r < 32; r += 8)
    Bt[(size_t)(n0 + r) * K + k0 + tx] = f2bf(tile[tx][r]);
}

__global__ __launch_bounds__(256) void fc_mfma(
    const unsigned short* __restrict__ A,   // [M][K] bf16
    const unsigned short* __restrict__ Bt,  // [N][K] bf16
    float* __restrict__ Cp, int M, int N, int K, int kLen) {
  const int tid = threadIdx.x;
  const int lane = tid & 63, wave = tid >> 6;
  const int n = lane & 31, half = lane >> 5;
  const int bm = blockIdx.y * 128 + wave * 32;
  const int bn = blockIdx.x * 64;
  const int k0s = blockIdx.z * kLen;
  const unsigned short* arow = A + (size_t)(bm + n) * K + half * 8;
  const unsigned short* b0row = Bt + (size_t)(bn + n) * K + half * 8;
  const unsigned short* b1row = Bt + (size_t)(bn + 32 + n) * K + half * 8;
  float16v acc0, acc1;
#pragma unroll
  for (int r = 0; r < 16; ++r) { acc0[r] = 0.f; acc1[r] = 0.f; }
  for (int k0 = k0s; k0 < k0s + kLen; k0 += 16) {
    short8 a = *(const short8*)(arow + k0);
    short8 b0 = *(const short8*)(b0row + k0);
    short8 b1 = *(const short8*)(b1row + k0);
    acc0 = __builtin_amdgcn_mfma_f32_32x32x16_bf16(a, b0, acc0, 0, 0, 0);
    acc1 = __builtin_amdgcn_mfma_f32_32x32x16_bf16(a, b1, acc1, 0, 0, 0);
  }
  float* Cz = Cp + (size_t)blockIdx.z * M * N;
#pragma unroll
  for (int r = 0; r < 16; ++r) {
    int row = bm + (r & 3) + 8 * (r >> 2) + 4 * half;
    Cz[(size_t)row * N + bn + n] = acc0[r];
    Cz[(size_t)row * N + bn + 32 + n] = acc1[r];
  }
}

__global__ void fc_combine(const float* __restrict__ p,
                           const float* __restrict__ bias,
                           float* __restrict__ out, int MN, int N, int S) {
  int i = blockIdx.x * 256 + threadIdx.x;
  if (i >= MN) return;
  float v = 0.f;
  for (int s = 0; s < S; ++s) v += p[(size_t)s * MN + i];
  out[i] = fmaxf(v + bias[i % N], 0.f);
}

__global__ __launch_bounds__(64) void heads_kernel(
    const float* __restrict__ v, const float* __restrict__ wc,
    const float* __restrict__ bc, const float* __restrict__ wb,
    const float* __restrict__ bbias, float* __restrict__ out) {
  const int m = blockIdx.x;
  const int lane = threadIdx.x;
  float acc[10];
#pragma unroll
  for (int o = 0; o < 10; ++o) acc[o] = 0.f;
  for (int k = lane; k < 1024; k += 64) {
    float x = v[(size_t)m * 1024 + k];
    acc[0] = fmaf(x, wc[k * 2 + 0], acc[0]);
    acc[1] = fmaf(x, wc[k * 2 + 1], acc[1]);
#pragma unroll
    for (int o = 0; o < 8; ++o) acc[2 + o] = fmaf(x, wb[k * 8 + o], acc[2 + o]);
  }
#pragma unroll
  for (int off = 32; off > 0; off >>= 1)
#pragma unroll
    for (int o = 0; o < 10; ++o) acc[o] += __shfl_down(acc[o], off);
  if (lane == 0) {
    out[m * 2 + 0] = acc[0] + bc[0];
    out[m * 2 + 1] = acc[1] + bc[1];
#pragma unroll
    for (int o = 0; o < 8; ++o) out[1024 + m * 8 + o] = acc[2 + o] + bbias[o];
  }
}

// ---------------------------------------------------------------------------
// Host orchestration
// ---------------------------------------------------------------------------
extern "C" void kernel_launch(void* const* d_in, const int* in_sizes, int n_in,
                              void* d_out, int out_size, void* d_ws,
                              size_t ws_size, hipStream_t stream) {
  const float* x      = (const float*)d_in[0];
  const float* w_stem = (const float*)d_in[1];
  const float* w_c2   = (const float*)d_in[2];
  const float* w_c3   = (const float*)d_in[3];
  const float* w_c4   = (const float*)d_in[4];
  const float* w_c5   = (const float*)d_in[5];
  const float* w_f2   = (const float*)d_in[6];
  const float* w_f3   = (const float*)d_in[7];
  const float* w_f4   = (const float*)d_in[8];
  const float* w_f5   = (const float*)d_in[9];
  const float* w_rpn  = (const float*)d_in[10];
  const float* w_cls  = (const float*)d_in[11];
  const float* w_box  = (const float*)d_in[12];
  const float* w_fc1  = (const float*)d_in[13];
  const float* b_fc1  = (const float*)d_in[14];
  const float* w_fc2  = (const float*)d_in[15];
  const float* b_fc2  = (const float*)d_in[16];
  const float* w_clsh = (const float*)d_in[17];
  const float* b_clsh = (const float*)d_in[18];
  const float* w_breg = (const float*)d_in[19];
  const float* b_breg = (const float*)d_in[20];
  float* dout = (float*)d_out;

  float* ws = (float*)d_ws;
  float* stem = ws;                          // 10,240,000 floats
  float* c2   = stem + 10240000;             // 10,240,000
  float* c3   = c2 + 10240000;               // 2,560,000
  float* c4   = c3 + 2560000;                // 640,000
  float* c5   = c4 + 640000;                 // 160,000
  float* f2   = c5 + 160000;                 // 10,240,000
  float* f3   = f2 + 10240000;               // 2,560,000
  float* f4   = f3 + 2560000;                // 640,000
  float* f5   = f4 + 640000;                 // 160,000
  float* boxes_all  = f5 + 160000;           // 16,000
  float* scores_all = boxes_all + 16000;     // 4,000
  float* props      = scores_all + 4000;     // 2,048
  int*   hist = (int*)(props + 2048);        // 65,536 ints
  int*   sel  = hist + 65536;                // 16 ints
  float* wpkA = (float*)(sel + 16);          // 589,824 (f2)
  float* wpkB = wpkA + 589824;               // 589,824 (f3)
  float* wpkC = wpkB + 589824;               // 589,824 (rpn)
  float* wpkD = wpkC + 589824;               // 147,456 (c2, Cin=64)
  float* wpkE = wpkD + 147456;               // 589,824 (c3)
  float* wpkF = wpkE + 589824;               // 589,824 (c4)
  float* wpkG = wpkF + 589824;               // 589,824 (c5)
  float* wpkH = wpkG + 589824;               // 589,824 (f4)
  float* wpkI = wpkH + 589824;               // 589,824 (f5)
  // aliases (dead regions reused):
  float* t      = c2;                        // rpn hidden (rpn loop; c2 dead)
  float* tt     = stem;                      // transposed t (stem dead)
  float* dec    = c3;                        // decoded boxes (rpn loop)
  float* slvl   = c4;                        // per-level scores (rpn loop)
  int*   order  = (int*)c3;                  // NMS (dec dead)
  unsigned long long* supp =
      (unsigned long long*)(c3 + 8192);      // 2.02 MB
  float* pooled = stem;                      // 6,422,528 floats (tt dead)
  float* fc1o   = stem + 6422528;            // 524,288
  float* fc2o   = fc1o + 524288;             // 524,288
  float* fcp    = fc2o + 524288;             // 4 x 524,288 (split-K partials)
  unsigned short* Abf1 = (unsigned short*)c2;            // 512x12544
  unsigned short* Bt1  = (unsigned short*)(c2 + 3211264);// 1024x12544
  unsigned short* Abf2 = (unsigned short*)c3;            // 512x1024
  unsigned short* Bt2  = (unsigned short*)(c3 + 262144); // 1024x1024

  // ---- repack conv weights (co16-contiguous per (ci,kk)) ----
  repack_w32<<<2304, 256, 0, stream>>>(w_f2, wpkA, 256);
  repack_w32<<<2304, 256, 0, stream>>>(w_f3, wpkB, 256);
  repack_w32<<<2304, 256, 0, stream>>>(w_rpn, wpkC, 256);
  repack_w32<<<576, 256, 0, stream>>>(w_c2, wpkD, 64);
  repack_w32<<<2304, 256, 0, stream>>>(w_c3, wpkE, 256);
  repack_w32<<<2304, 256, 0, stream>>>(w_c4, wpkF, 256);
  repack_w32<<<2304, 256, 0, stream>>>(w_c5, wpkG, 256);
  repack_w32<<<2304, 256, 0, stream>>>(w_f4, wpkH, 256);
  repack_w32<<<2304, 256, 0, stream>>>(w_f5, wpkI, 256);

  // ---- backbone (R16 conv forms) ----
  stem_conv<<<dim3(25, 25, 16), 256, 0, stream>>>(x, w_stem, stem);
  conv16_s2<4, true><<<dim3(13, 13, 16), 256, 0, stream>>>(
      stem, wpkD, c2, 64, 400, 400, 200, 200);
  conv16_s2<4, true><<<dim3(7, 7, 16), 256, 0, stream>>>(
      c2, wpkE, c3, 256, 200, 200, 100, 100);
  conv16_s2<4, true><<<dim3(4, 4, 16), 256, 0, stream>>>(
      c3, wpkF, c4, 256, 100, 100, 50, 50);
  conv16_s2<4, true><<<dim3(2, 2, 16), 256, 0, stream>>>(
      c4, wpkG, c5, 256, 50, 50, 25, 25);
  // ---- FPN laterals (no relu) ----
  conv32_db<4, false><<<dim3(7, 13, 16), 256, 0, stream>>>(
      c2, wpkA, f2, 256, 200, 200, 200, 200);
  conv32_db<4, false><<<dim3(4, 7, 16), 256, 0, stream>>>(
      c3, wpkB, f3, 256, 100, 100, 100, 100);
  conv16_s1<8, false><<<dim3(4, 4, 16), 256, 0, stream>>>(
      c4, wpkH, f4, 256, 50, 50, 50, 50);
  conv16_s1<8, false><<<dim3(2, 2, 16), 256, 0, stream>>>(
      c5, wpkI, f5, 256, 25, 25, 25, 25);

  // ---- RPN per level: conv+relu, transpose, heads+decode(+hist), top-1000 --
  hipMemsetAsync(hist, 0, 65536 * sizeof(int), stream);  // once; scans re-zero
  const float* feats[4] = {f2, f3, f4, f5};
  const int dims[4] = {200, 100, 50, 25};
  const float strds[4] = {4.f, 8.f, 16.f, 32.f};
  const double szs[4] = {32.0, 64.0, 128.0, 256.0};
  for (int lvl = 0; lvl < 4; ++lvl) {
    const int d = dims[lvl];
    const int npix = d * d;
    const int N = npix * 3;
    if (lvl == 0)
      conv32_db<4, true><<<dim3(7, 13, 16), 256, 0, stream>>>(
          feats[lvl], wpkC, t, 256, d, d, d, d);
    else if (lvl == 1)
      conv32_db<4, true><<<dim3(4, 7, 16), 256, 0, stream>>>(
          feats[lvl], wpkC, t, 256, d, d, d, d);
    else if (lvl == 2)
      conv16_s1<8, true><<<dim3(4, 4, 16), 256, 0, stream>>>(
          feats[lvl], wpkC, t, 256, d, d, d, d);
    else
      conv16_s1<8, true><<<dim3(2, 2, 16), 256, 0, stream>>>(
          feats[lvl], wpkC, t, 256, d, d, d, d);
    transpose_t<<<dim3((npix + 31) / 32, 8), 256, 0, stream>>>(t, tt, npix);
    double sz = szs[lvl];
    float ws0 = (float)(sz / sqrt(0.5)), ws1 = (float)sz,
          ws2 = (float)(sz / sqrt(2.0));
    float hs0 = (float)(sz * sqrt(0.5)), hs1 = (float)sz,
          hs2 = (float)(sz * sqrt(2.0));
    rpn_head_decode<<<(npix + 255) / 256, 256, 0, stream>>>(
        tt, w_cls, w_box, dec, slvl, hist, d, d, strds[lvl], ws0, ws1, ws2,
        hs0, hs1, hs2);
    scan_hi_kernel<<<1, 256, 0, stream>>>(hist, 1000, sel);
    hist_lo_kernel<<<(N + 255) / 256, 256, 0, stream>>>(slvl, N, sel, hist);
    scan_lo_kernel<<<1, 256, 0, stream>>>(hist, sel);
    compact_kernel<<<(N + 255) / 256, 256, 0, stream>>>(
        slvl, dec, N, sel, scores_all, boxes_all, lvl * 1000);
  }

  // ---- NMS ----
  rank_kernel<<<16, 256, 0, stream>>>(scores_all, order);
  supp_kernel<<<250, 256, 0, stream>>>(boxes_all, supp);
  nms_scan<<<1, 64, 0, stream>>>(supp, order, boxes_all, scores_all, props,
                                 dout + 5120, dout + 7168);

  // ---- ROI align + FC heads (bf16 MFMA; auto-pass cone) ----
  roi_align_kernel<<<512, 256, 0, stream>>>(f2, props, pooled);
  cast_a<<<(6422528 + 255) / 256, 256, 0, stream>>>(pooled, Abf1, 6422528);
  cast_bt<<<dim3(32, 392), 256, 0, stream>>>(w_fc1, Bt1, 12544, 1024);
  fc_mfma<<<dim3(16, 4, 4), 256, 0, stream>>>(Abf1, Bt1, fcp, 512, 1024, 12544,
                                              3136);
  fc_combine<<<2048, 256, 0, stream>>>(fcp, b_fc1, fc1o, 524288, 1024, 4);
  cast_a<<<(524288 + 255) / 256, 256, 0, stream>>>(fc1o, Abf2, 524288);
  cast_bt<<<dim3(32, 32), 256, 0, stream>>>(w_fc2, Bt2, 1024, 1024);
  fc_mfma<<<dim3(16, 4, 4), 256, 0, stream>>>(Abf2, Bt2, fcp, 512, 1024, 1024,
                                              256);
  fc_combine<<<2048, 256, 0, stream>>>(fcp, b_fc2, fc2o, 524288, 1024, 4);
  heads_kernel<<<512, 64, 0, stream>>>(fc2o, w_clsh, b_clsh, w_breg, b_breg,
                                       dout);
}

// Round 11
// 4934.687 us; speedup vs baseline: 1.2510x; 1.0868x over previous
//
#include <hip/hip_runtime.h>
#include <math.h>

// ---------------------------------------------------------------------------
// R20 (base = R16, 5303us proven): three bit-identical structural cuts.
// (a) repack_all: 9 repack launches -> 1 segment-ranged kernel (~19MB total
// work was spread over 9 ~10us launches). (b) stem scalar-weight path (3rd
// application of R11 recipe): stem was LDS-broadcast bound (CO=4: 8 FMA cyc
// vs ~5 LDS ops per k-step); weights repacked [z16][k147][co4] -> uniform
// s_load_dwordx4; FMA order (c,ky,kx,co asc) unchanged. (c) lateral merges:
// f2+f3 and f4+f5 as single 1D-grid launches (block-uniform decode) --
// inputs all ready; fills f2's 5.7-blocks/CU tail with f3's blocks.
// conv inner loops, selection (R16 form), NMS, ROI, FC: exact R16.
// ---------------------------------------------------------------------------

#define DI __device__ __forceinline__

typedef short short8 __attribute__((ext_vector_type(8)));
typedef float float16v __attribute__((ext_vector_type(16)));

DI unsigned fkey(float f) {
  unsigned u = __float_as_uint(f);
  return (u & 0x80000000u) ? ~u : (u | 0x80000000u);
}

DI unsigned short f2bf(float f) {  // fp32 -> bf16 RN-even
  unsigned u = __float_as_uint(f);
  unsigned r = (u + 0x7FFFu + ((u >> 16) & 1u)) >> 16;
  return (unsigned short)r;
}

// ---------------------------------------------------------------------------
// Unified weight repack. Segments (element-indexed):
//   [0,SZ) f2  -> wpkA   [SZ,2SZ) f3 -> wpkB   [2SZ,3SZ) rpn -> wpkC
//   [3SZ, 3SZ+SZD) c2(Cin=64) -> wpkD
//   then c3,c4,c5,f4,f5 (SZ each) -> wpkE..wpkI
//   last 9408: stem -> wpkS  ([z16][k147][co4])
// ---------------------------------------------------------------------------
DI void rp256(const float* src, float* dst, int j) {
  int co = j & 15; int r = j >> 4; int kk = r % 9; int r2 = r / 9;
  int ci = r2 & 255; int z = r2 >> 8;
  dst[j] = src[((size_t)(z * 16 + co) * 256 + ci) * 9 + kk];
}

__global__ void repack_all(
    const float* __restrict__ wf2, const float* __restrict__ wf3,
    const float* __restrict__ wrpn, const float* __restrict__ wc2,
    const float* __restrict__ wc3, const float* __restrict__ wc4,
    const float* __restrict__ wc5, const float* __restrict__ wf4,
    const float* __restrict__ wf5, const float* __restrict__ wstem,
    float* __restrict__ wpkA, float* __restrict__ wpkB,
    float* __restrict__ wpkC, float* __restrict__ wpkD,
    float* __restrict__ wpkE, float* __restrict__ wpkF,
    float* __restrict__ wpkG, float* __restrict__ wpkH,
    float* __restrict__ wpkI, float* __restrict__ wpkS) {
  const int SZ = 589824, SZD = 147456;
  const int D0 = 3 * SZ;            // 1769472
  const int D1 = D0 + SZD;          // 1916928
  const int D2 = D1 + 5 * SZ;       // 4866048
  const int D3 = D2 + 9408;         // 4875456
  int i = blockIdx.x * 256 + threadIdx.x;
  if (i >= D3) return;
  if (i < D0) {
    const float* src = (i < SZ) ? wf2 : (i < 2 * SZ) ? wf3 : wrpn;
    float* dst = (i < SZ) ? wpkA : (i < 2 * SZ) ? wpkB : wpkC;
    rp256(src, dst, i % SZ);
  } else if (i < D1) {
    int j = i - D0;  // Cin = 64
    int co = j & 15; int r = j >> 4; int kk = r % 9; int r2 = r / 9;
    int ci = r2 & 63; int z = r2 >> 6;
    wpkD[j] = wc2[((size_t)(z * 16 + co) * 64 + ci) * 9 + kk];
  } else if (i < D2) {
    int j = i - D1;
    int seg = j / SZ; j -= seg * SZ;
    const float* src = (seg == 0) ? wc3 : (seg == 1) ? wc4
                       : (seg == 2) ? wc5 : (seg == 3) ? wf4 : wf5;
    float* dst = (seg == 0) ? wpkE : (seg == 1) ? wpkF
                 : (seg == 2) ? wpkG : (seg == 3) ? wpkH : wpkI;
    rp256(src, dst, j);
  } else {
    int j = i - D2;  // stem: 16 z-groups x 147 k x 4 co
    int co = j & 3; int r = j >> 2;
    int k = r % 147; int z = r / 147;
    wpkS[j] = wstem[(size_t)(z * 4 + co) * 147 + k];
  }
}

// ---------------------------------------------------------------------------
// Stem: CO=4, grid (25,25,16). Weights via uniform scalar float4 from wpkS
// ([z16][k147][co4]). FMA chain (c,ky,kx,co asc) identical to R9 stem.
// ---------------------------------------------------------------------------
__global__ __launch_bounds__(256) void stem_conv(const float* __restrict__ x,
                                                 const float* __restrict__ wpkS,
                                                 float* __restrict__ out) {
  __shared__ float tin[3 * 37 * 37];
  const int x0 = blockIdx.x * 16, y0 = blockIdx.y * 16, co0 = blockIdx.z * 4;
  const int tid = threadIdx.x;
  const int ix0 = x0 * 2 - 2, iy0 = y0 * 2 - 2;
  const float mean[3] = {0.485f, 0.456f, 0.406f};
  const float stdv[3] = {0.229f, 0.224f, 0.225f};
  for (int i = tid; i < 3 * 37 * 37; i += 256) {
    int c = i / 1369, r = i % 1369, yy = r / 37, xx = r % 37;
    int gy = iy0 + yy, gx = ix0 + xx;
    float v = 0.f;
    if ((unsigned)gy < 800u && (unsigned)gx < 800u)
      v = __fdiv_rn(__fsub_rn(x[c * 640000 + gy * 800 + gx], mean[c]), stdv[c]);
    tin[i] = v;
  }
  __syncthreads();
  const int tx = tid & 15, ty = tid >> 4;
  float acc[4] = {0.f, 0.f, 0.f, 0.f};
  const float4* wq = (const float4*)(wpkS + (size_t)blockIdx.z * 588);
  for (int c = 0; c < 3; ++c)
    for (int ky = 0; ky < 7; ++ky)
#pragma unroll
      for (int kx = 0; kx < 7; ++kx) {
        float v = tin[c * 1369 + (ty * 2 + ky) * 37 + (tx * 2 + kx)];
        float4 wv = wq[c * 49 + ky * 7 + kx];
        acc[0] = fmaf(v, wv.x, acc[0]);
        acc[1] = fmaf(v, wv.y, acc[1]);
        acc[2] = fmaf(v, wv.z, acc[2]);
        acc[3] = fmaf(v, wv.w, acc[3]);
      }
  int ox = x0 + tx, oy = y0 + ty;
#pragma unroll
  for (int co = 0; co < 4; ++co)
    out[(size_t)(co0 + co) * 160000 + oy * 400 + ox] = fmaxf(acc[co], 0.f);
}

// ---------------------------------------------------------------------------
// conv32 body (exact R16 math): 32x16 tile, 2 adjacent px/thread, CO=16,
// CHUNK=4 register-staged double buffer, ONE barrier/iter.
// ---------------------------------------------------------------------------
template <int CHUNK, bool RELU>
DI void conv32_body(const float* __restrict__ in,
                    const float* __restrict__ wpk, float* __restrict__ out,
                    int Cin, int Hin, int Win, int Hout, int Wout, int bx,
                    int by, int bz, float (*tin2)[((CHUNK * 612 + 255) / 256) * 256]) {
  constexpr int TILE = CHUNK * 612;
  constexpr int NS = (TILE + 255) / 256;
  const int tid = threadIdx.x;
  const int tx = tid & 15, ty = tid >> 4;
  const int x0 = bx * 32, y0 = by * 16;
  const int ix0 = x0 - 1, iy0 = y0 - 1;
  const size_t HWin = (size_t)Hin * Win;

  int goff[NS];
#pragma unroll
  for (int j = 0; j < NS; ++j) {
    int e = j * 256 + tid;
    int c = e / 612, r = e % 612;
    int yy = r / 34, xx = r % 34;
    int gy = iy0 + yy, gx = ix0 + xx;
    bool ok = (e < TILE) && ((unsigned)gy < (unsigned)Hin) &&
              ((unsigned)gx < (unsigned)Win);
    goff[j] = ok ? (int)((size_t)c * HWin + (size_t)gy * Win + gx) : -1;
  }

  float acc0[16], acc1[16];
#pragma unroll
  for (int co = 0; co < 16; ++co) { acc0[co] = 0.f; acc1[co] = 0.f; }

  float stg[NS];
#pragma unroll
  for (int j = 0; j < NS; ++j)
    stg[j] = (goff[j] >= 0) ? in[goff[j]] : 0.f;
#pragma unroll
  for (int j = 0; j < NS; ++j) tin2[0][j * 256 + tid] = stg[j];
  __syncthreads();

  int buf = 0;
  for (int cb = 0; cb < Cin; cb += CHUNK) {
    const bool more = (cb + CHUNK) < Cin;
    if (more) {
      const float* gsrc = in + (size_t)(cb + CHUNK) * HWin;
#pragma unroll
      for (int j = 0; j < NS; ++j)
        stg[j] = (goff[j] >= 0) ? gsrc[goff[j]] : 0.f;
    }
    for (int ci = 0; ci < CHUNK; ++ci) {
      const float4* wq = (const float4*)(wpk +
          ((size_t)bz * Cin + (size_t)(cb + ci)) * 144);
#pragma unroll
      for (int ky = 0; ky < 3; ++ky) {
        const float* tb = &tin2[buf][ci * 612 + (ty + ky) * 34 + 2 * tx];
        float2 d0 = *(const float2*)tb;
        float2 d1 = *(const float2*)(tb + 2);
#pragma unroll
        for (int kx = 0; kx < 3; ++kx) {
          float v0 = (kx == 0) ? d0.x : (kx == 1) ? d0.y : d1.x;
          float v1 = (kx == 0) ? d0.y : (kx == 1) ? d1.x : d1.y;
          const int kk = ky * 3 + kx;
          float4 w0 = wq[kk * 4 + 0];
          float4 w1 = wq[kk * 4 + 1];
          float4 w2 = wq[kk * 4 + 2];
          float4 w3 = wq[kk * 4 + 3];
          acc0[0]  = fmaf(v0, w0.x, acc0[0]);
          acc0[1]  = fmaf(v0, w0.y, acc0[1]);
          acc0[2]  = fmaf(v0, w0.z, acc0[2]);
          acc0[3]  = fmaf(v0, w0.w, acc0[3]);
          acc1[0]  = fmaf(v1, w0.x, acc1[0]);
          acc1[1]  = fmaf(v1, w0.y, acc1[1]);
          acc1[2]  = fmaf(v1, w0.z, acc1[2]);
          acc1[3]  = fmaf(v1, w0.w, acc1[3]);
          acc0[4]  = fmaf(v0, w1.x, acc0[4]);
          acc0[5]  = fmaf(v0, w1.y, acc0[5]);
          acc0[6]  = fmaf(v0, w1.z, acc0[6]);
          acc0[7]  = fmaf(v0, w1.w, acc0[7]);
          acc1[4]  = fmaf(v1, w1.x, acc1[4]);
          acc1[5]  = fmaf(v1, w1.y, acc1[5]);
          acc1[6]  = fmaf(v1, w1.z, acc1[6]);
          acc1[7]  = fmaf(v1, w1.w, acc1[7]);
          acc0[8]  = fmaf(v0, w2.x, acc0[8]);
          acc0[9]  = fmaf(v0, w2.y, acc0[9]);
          acc0[10] = fmaf(v0, w2.z, acc0[10]);
          acc0[11] = fmaf(v0, w2.w, acc0[11]);
          acc1[8]  = fmaf(v1, w2.x, acc1[8]);
          acc1[9]  = fmaf(v1, w2.y, acc1[9]);
          acc1[10] = fmaf(v1, w2.z, acc1[10]);
          acc1[11] = fmaf(v1, w2.w, acc1[11]);
          acc0[12] = fmaf(v0, w3.x, acc0[12]);
          acc0[13] = fmaf(v0, w3.y, acc0[13]);
          acc0[14] = fmaf(v0, w3.z, acc0[14]);
          acc0[15] = fmaf(v0, w3.w, acc0[15]);
          acc1[12] = fmaf(v1, w3.x, acc1[12]);
          acc1[13] = fmaf(v1, w3.y, acc1[13]);
          acc1[14] = fmaf(v1, w3.z, acc1[14]);
          acc1[15] = fmaf(v1, w3.w, acc1[15]);
        }
      }
    }
    if (more) {
#pragma unroll
      for (int j = 0; j < NS; ++j) tin2[buf ^ 1][j * 256 + tid] = stg[j];
    }
    __syncthreads();
    buf ^= 1;
  }

  const int co0 = bz * 16;
  int oy = y0 + ty;
  if (oy < Hout) {
    int ox = x0 + 2 * tx;
    if (ox + 1 < Wout) {
#pragma unroll
      for (int co = 0; co < 16; ++co) {
        float a = acc0[co], b = acc1[co];
        if (RELU) { a = fmaxf(a, 0.f); b = fmaxf(b, 0.f); }
        float2 st; st.x = a; st.y = b;
        *(float2*)&out[(size_t)(co0 + co) * Hout * Wout +
                       (size_t)oy * Wout + ox] = st;
      }
    } else if (ox < Wout) {
#pragma unroll
      for (int co = 0; co < 16; ++co) {
        float a = acc0[co];
        if (RELU) a = fmaxf(a, 0.f);
        out[(size_t)(co0 + co) * Hout * Wout + (size_t)oy * Wout + ox] = a;
      }
    }
  }
}

template <int CHUNK, bool RELU>
__global__ __launch_bounds__(256) void conv32_db(
    const float* __restrict__ in, const float* __restrict__ wpk,
    float* __restrict__ out, int Cin, int Hin, int Win, int Hout, int Wout) {
  constexpr int PADT = ((CHUNK * 612 + 255) / 256) * 256;
  __shared__ __align__(16) float tin2[2][PADT];
  conv32_body<CHUNK, RELU>(in, wpk, out, Cin, Hin, Win, Hout, Wout,
                           blockIdx.x, blockIdx.y, blockIdx.z, tin2);
}

// Merged laterals f2+f3 (both RELU=false), 1D grid, block-uniform decode.
template <int CHUNK>
__global__ __launch_bounds__(256) void conv32_lat(
    const float* __restrict__ inA, const float* __restrict__ wA,
    float* __restrict__ oA, int CinA, int HA, int WA, int gxA, int gyA,
    int nA, const float* __restrict__ inB, const float* __restrict__ wB,
    float* __restrict__ oB, int CinB, int HB, int WB, int gxB, int gyB) {
  constexpr int PADT = ((CHUNK * 612 + 255) / 256) * 256;
  __shared__ __align__(16) float tin2[2][PADT];
  int bid = blockIdx.x;
  if (bid < nA) {
    int bx = bid % gxA; int r = bid / gxA; int by = r % gyA; int bz = r / gyA;
    conv32_body<CHUNK, false>(inA, wA, oA, CinA, HA, WA, HA, WA, bx, by, bz,
                              tin2);
  } else {
    bid -= nA;
    int bx = bid % gxB; int r = bid / gxB; int by = r % gyB; int bz = r / gyB;
    conv32_body<CHUNK, false>(inB, wB, oB, CinB, HB, WB, HB, WB, bx, by, bz,
                              tin2);
  }
}

// ---------------------------------------------------------------------------
// conv16_s1 body (exact R16 math): 16x16 tile, repacked weights, hoisted.
// ---------------------------------------------------------------------------
template <int CHUNK, bool RELU>
DI void conv16s1_body(const float* __restrict__ in,
                      const float* __restrict__ wpk, float* __restrict__ out,
                      int Cin, int Hin, int Win, int Hout, int Wout, int bx,
                      int by, int bz, float* tin) {
  constexpr int P = 24;
  constexpr int TOT = CHUNK * 18 * 18;
  constexpr int NS = (TOT + 255) / 256;
  const int tid = threadIdx.x;
  const int tx = tid & 15, ty = tid >> 4;
  const int x0 = bx * 16, y0 = by * 16;
  const int ix0 = x0 - 1, iy0 = y0 - 1;
  const size_t HWin = (size_t)Hin * Win;

  int goff[NS], loff[NS];
#pragma unroll
  for (int j = 0; j < NS; ++j) {
    int i = tid + j * 256;
    int c = i / 324, r = i % 324;
    int yy = r / 18, xx = r % 18;
    int gy = iy0 + yy, gx = ix0 + xx;
    bool ok = (i < TOT) && ((unsigned)gy < (unsigned)Hin) &&
              ((unsigned)gx < (unsigned)Win);
    goff[j] = ok ? (int)(c * HWin + (size_t)gy * Win + gx) : -1;
    loff[j] = c * 18 * P + yy * P + xx;
  }

  float acc[16];
#pragma unroll
  for (int co = 0; co < 16; ++co) acc[co] = 0.f;

  for (int cb = 0; cb < Cin; cb += CHUNK) {
    const size_t gbase = (size_t)cb * HWin;
#pragma unroll
    for (int j = 0; j < NS; ++j) {
      int i = tid + j * 256;
      if (i < TOT) {
        float v = 0.f;
        if (goff[j] >= 0) v = in[gbase + goff[j]];
        tin[loff[j]] = v;
      }
    }
    __syncthreads();
    for (int ci = 0; ci < CHUNK; ++ci) {
      const float4* wq = (const float4*)(wpk +
          ((size_t)bz * Cin + (size_t)(cb + ci)) * 144);
#pragma unroll
      for (int ky = 0; ky < 3; ++ky) {
#pragma unroll
        for (int kx = 0; kx < 3; ++kx) {
          const int kk = ky * 3 + kx;
          float v = tin[ci * 18 * P + (ty + ky) * P + tx + kx];
          float4 w0 = wq[kk * 4 + 0];
          float4 w1 = wq[kk * 4 + 1];
          float4 w2 = wq[kk * 4 + 2];
          float4 w3 = wq[kk * 4 + 3];
          acc[0]  = fmaf(v, w0.x, acc[0]);
          acc[1]  = fmaf(v, w0.y, acc[1]);
          acc[2]  = fmaf(v, w0.z, acc[2]);
          acc[3]  = fmaf(v, w0.w, acc[3]);
          acc[4]  = fmaf(v, w1.x, acc[4]);
          acc[5]  = fmaf(v, w1.y, acc[5]);
          acc[6]  = fmaf(v, w1.z, acc[6]);
          acc[7]  = fmaf(v, w1.w, acc[7]);
          acc[8]  = fmaf(v, w2.x, acc[8]);
          acc[9]  = fmaf(v, w2.y, acc[9]);
          acc[10] = fmaf(v, w2.z, acc[10]);
          acc[11] = fmaf(v, w2.w, acc[11]);
          acc[12] = fmaf(v, w3.x, acc[12]);
          acc[13] = fmaf(v, w3.y, acc[13]);
          acc[14] = fmaf(v, w3.z, acc[14]);
          acc[15] = fmaf(v, w3.w, acc[15]);
        }
      }
    }
    __syncthreads();
  }
  const int co0 = bz * 16;
  int oy = y0 + ty, ox = x0 + tx;
  if (oy < Hout && ox < Wout) {
#pragma unroll
    for (int co = 0; co < 16; ++co) {
      float v = acc[co];
      if (RELU) v = fmaxf(v, 0.f);
      out[(size_t)(co0 + co) * Hout * Wout + (size_t)oy * Wout + ox] = v;
    }
  }
}

template <int CHUNK, bool RELU>
__global__ __launch_bounds__(256) void conv16_s1(const float* __restrict__ in,
                                                 const float* __restrict__ wpk,
                                                 float* __restrict__ out,
                                                 int Cin, int Hin, int Win,
                                                 int Hout, int Wout) {
  __shared__ __align__(16) float tin[CHUNK * 18 * 24];
  conv16s1_body<CHUNK, RELU>(in, wpk, out, Cin, Hin, Win, Hout, Wout,
                             blockIdx.x, blockIdx.y, blockIdx.z, tin);
}

// Merged laterals f4+f5 (both RELU=false).
template <int CHUNK>
__global__ __launch_bounds__(256) void conv16_lat(
    const float* __restrict__ inA, const float* __restrict__ wA,
    float* __restrict__ oA, int CinA, int HA, int WA, int gxA, int gyA,
    int nA, const float* __restrict__ inB, const float* __restrict__ wB,
    float* __restrict__ oB, int CinB, int HB, int WB, int gxB, int gyB) {
  __shared__ __align__(16) float tin[CHUNK * 18 * 24];
  int bid = blockIdx.x;
  if (bid < nA) {
    int bx = bid % gxA; int r = bid / gxA; int by = r % gyA; int bz = r / gyA;
    conv16s1_body<CHUNK, false>(inA, wA, oA, CinA, HA, WA, HA, WA, bx, by, bz,
                                tin);
  } else {
    bid -= nA;
    int bx = bid % gxB; int r = bid / gxB; int by = r % gyB; int bz = r / gyB;
    conv16s1_body<CHUNK, false>(inB, wB, oB, CinB, HB, WB, HB, WB, bx, by, bz,
                                tin);
  }
}

// ---------------------------------------------------------------------------
// conv16_s2 (exact R16): phase-split E/O pitch 20, repacked weights.
// ---------------------------------------------------------------------------
template <int CHUNK, bool RELU>
__global__ __launch_bounds__(256) void conv16_s2(const float* __restrict__ in,
                                                 const float* __restrict__ wpk,
                                                 float* __restrict__ out,
                                                 int Cin, int Hin, int Win,
                                                 int Hout, int Wout) {
  constexpr int P = 20;
  constexpr int HALF = CHUNK * 33 * P;
  constexpr int TOT = CHUNK * 33 * 33;
  constexpr int NS = (TOT + 255) / 256;
  __shared__ __align__(16) float tin2[2 * HALF];  // [E | O]
  const int tid = threadIdx.x;
  const int tx = tid & 15, ty = tid >> 4;
  const int x0 = blockIdx.x * 16, y0 = blockIdx.y * 16;
  const int ix0 = x0 * 2, iy0 = y0 * 2;
  const size_t HWin = (size_t)Hin * Win;

  int goff[NS], loff[NS];
#pragma unroll
  for (int j = 0; j < NS; ++j) {
    int i = tid + j * 256;
    int c = i / 1089, r = i % 1089;
    int yy = r / 33, xx = r % 33;
    int gy = iy0 + yy, gx = ix0 + xx;
    bool ok = (i < TOT) && ((unsigned)gy < (unsigned)Hin) &&
              ((unsigned)gx < (unsigned)Win);
    goff[j] = ok ? (int)(c * HWin + (size_t)gy * Win + gx) : -1;
    loff[j] = c * 33 * P + yy * P + (xx >> 1) + ((xx & 1) ? HALF : 0);
  }

  float acc[16];
#pragma unroll
  for (int co = 0; co < 16; ++co) acc[co] = 0.f;

  for (int cb = 0; cb < Cin; cb += CHUNK) {
    const size_t gbase = (size_t)cb * HWin;
#pragma unroll
    for (int j = 0; j < NS; ++j) {
      int i = tid + j * 256;
      if (i < TOT) {
        float v = 0.f;
        if (goff[j] >= 0) v = in[gbase + goff[j]];
        tin2[loff[j]] = v;
      }
    }
    __syncthreads();
    for (int ci = 0; ci < CHUNK; ++ci) {
      const float4* wq = (const float4*)(wpk +
          ((size_t)blockIdx.z * Cin + (size_t)(cb + ci)) * 144);
#pragma unroll
      for (int ky = 0; ky < 3; ++ky) {
#pragma unroll
        for (int kx = 0; kx < 3; ++kx) {
          const int kk = ky * 3 + kx;
          const float* base = (kx == 1) ? (tin2 + HALF) : tin2;
          const int cadd = (kx == 2) ? 1 : 0;
          float v = base[ci * 33 * P + (2 * ty + ky) * P + tx + cadd];
          float4 w0 = wq[kk * 4 + 0];
          float4 w1 = wq[kk * 4 + 1];
          float4 w2 = wq[kk * 4 + 2];
          float4 w3 = wq[kk * 4 + 3];
          acc[0]  = fmaf(v, w0.x, acc[0]);
          acc[1]  = fmaf(v, w0.y, acc[1]);
          acc[2]  = fmaf(v, w0.z, acc[2]);
          acc[3]  = fmaf(v, w0.w, acc[3]);
          acc[4]  = fmaf(v, w1.x, acc[4]);
          acc[5]  = fmaf(v, w1.y, acc[5]);
          acc[6]  = fmaf(v, w1.z, acc[6]);
          acc[7]  = fmaf(v, w1.w, acc[7]);
          acc[8]  = fmaf(v, w2.x, acc[8]);
          acc[9]  = fmaf(v, w2.y, acc[9]);
          acc[10] = fmaf(v, w2.z, acc[10]);
          acc[11] = fmaf(v, w2.w, acc[11]);
          acc[12] = fmaf(v, w3.x, acc[12]);
          acc[13] = fmaf(v, w3.y, acc[13]);
          acc[14] = fmaf(v, w3.z, acc[14]);
          acc[15] = fmaf(v, w3.w, acc[15]);
        }
      }
    }
    __syncthreads();
  }
  const int co0 = blockIdx.z * 16;
  int oy = y0 + ty, ox = x0 + tx;
  if (oy < Hout && ox < Wout) {
#pragma unroll
    for (int co = 0; co < 16; ++co) {
      float v = acc[co];
      if (RELU) v = fmaxf(v, 0.f);
      out[(size_t)(co0 + co) * Hout * Wout + (size_t)oy * Wout + ox] = v;
    }
  }
}

// ---------------------------------------------------------------------------
// Transpose t [256][npix] -> tt [npix][256] (pure data movement).
// ---------------------------------------------------------------------------
__global__ __launch_bounds__(256) void transpose_t(const float* __restrict__ in,
                                                   float* __restrict__ out,
                                                   int npix) {
  __shared__ float tile[32][33];
  const int p0 = blockIdx.x * 32, c0 = blockIdx.y * 32;
  const int tx = threadIdx.x & 31, ty = threadIdx.x >> 5;
  for (int r = ty; r < 32; r += 8) {
    int p = p0 + tx;
    tile[r][tx] = (p < npix) ? in[(size_t)(c0 + r) * npix + p] : 0.f;
  }
  __syncthreads();
  for (int r = ty; r < 32; r += 8) {
    int p = p0 + r;
    if (p < npix) out[(size_t)p * 256 + c0 + tx] = tile[tx][r];
  }
}

// ---------------------------------------------------------------------------
// RPN head + decode reading px-major tt[p][256]. (exact R16)
// ---------------------------------------------------------------------------
__global__ __launch_bounds__(256) void rpn_head_decode(
    const float* __restrict__ tt, const float* __restrict__ wcls,
    const float* __restrict__ wbox, float* __restrict__ boxes,
    float* __restrict__ scores, int fh, int fw, float stride, float ws0,
    float ws1, float ws2, float hs0, float hs1, float hs2) {
  __shared__ __align__(16) float wcs[256][16];
  for (int i = threadIdx.x; i < 256 * 16; i += 256) {
    int c = i & 255, o = i >> 8;
    float v = 0.f;
    if (o < 3) v = wcls[o * 256 + c];
    else if (o < 15) v = wbox[(o - 3) * 256 + c];
    wcs[c][o] = v;
  }
  __syncthreads();
  const int npix = fh * fw;
  int p = blockIdx.x * 256 + threadIdx.x;
  if (p >= npix) return;
  float a[15];
#pragma unroll
  for (int o = 0; o < 15; ++o) a[o] = 0.f;
  const float4* tp = (const float4*)(tt + (size_t)p * 256);
#pragma unroll 4
  for (int c4 = 0; c4 < 64; ++c4) {
    float4 tv = tp[c4];
#pragma unroll
    for (int j = 0; j < 4; ++j) {
      float v = (j == 0) ? tv.x : (j == 1) ? tv.y : (j == 2) ? tv.z : tv.w;
      int c = c4 * 4 + j;
      const float4* wr = (const float4*)&wcs[c][0];
      float4 w0 = wr[0], w1 = wr[1], w2 = wr[2], w3 = wr[3];
      a[0] = fmaf(v, w0.x, a[0]);   a[1] = fmaf(v, w0.y, a[1]);
      a[2] = fmaf(v, w0.z, a[2]);   a[3] = fmaf(v, w0.w, a[3]);
      a[4] = fmaf(v, w1.x, a[4]);   a[5] = fmaf(v, w1.y, a[5]);
      a[6] = fmaf(v, w1.z, a[6]);   a[7] = fmaf(v, w1.w, a[7]);
      a[8] = fmaf(v, w2.x, a[8]);   a[9] = fmaf(v, w2.y, a[9]);
      a[10] = fmaf(v, w2.z, a[10]); a[11] = fmaf(v, w2.w, a[11]);
      a[12] = fmaf(v, w3.x, a[12]); a[13] = fmaf(v, w3.y, a[13]);
      a[14] = fmaf(v, w3.z, a[14]);
    }
  }
  const int i = p / fw, j = p % fw;
  const float acy0 = __fmul_rn((float)i + 0.5f, stride);
  const float acx0 = __fmul_rn((float)j + 0.5f, stride);
  const float WS[3] = {ws0, ws1, ws2}, HS[3] = {hs0, hs1, hs2};
#pragma unroll
  for (int an = 0; an < 3; ++an) {
    float hw = __fmul_rn(WS[an], 0.5f), hh = __fmul_rn(HS[an], 0.5f);
    float x1a = __fsub_rn(acx0, hw), x2a = __fadd_rn(acx0, hw);
    float y1a = __fsub_rn(acy0, hh), y2a = __fadd_rn(acy0, hh);
    float aw = __fsub_rn(x2a, x1a), ah = __fsub_rn(y2a, y1a);
    float acx = __fadd_rn(x1a, __fmul_rn(aw, 0.5f));
    float acy = __fadd_rn(y1a, __fmul_rn(ah, 0.5f));
    float dx = a[3 + an * 4 + 0], dy = a[3 + an * 4 + 1];
    float dw = fminf(fmaxf(a[3 + an * 4 + 2], -4.f), 4.f);
    float dh = fminf(fmaxf(a[3 + an * 4 + 3], -4.f), 4.f);
    float cx = __fadd_rn(acx, __fmul_rn(dx, aw));
    float cy = __fadd_rn(acy, __fmul_rn(dy, ah));
    float w_ = __fmul_rn(aw, expf(dw));
    float h_ = __fmul_rn(ah, expf(dh));
    int idx = p * 3 + an;
    boxes[idx * 4 + 0] =
        fminf(fmaxf(__fsub_rn(cx, __fmul_rn(w_, 0.5f)), 0.f), 800.f);
    boxes[idx * 4 + 1] =
        fminf(fmaxf(__fsub_rn(cy, __fmul_rn(h_, 0.5f)), 0.f), 800.f);
    boxes[idx * 4 + 2] =
        fminf(fmaxf(__fadd_rn(cx, __fmul_rn(w_, 0.5f)), 0.f), 800.f);
    boxes[idx * 4 + 3] =
        fminf(fmaxf(__fadd_rn(cy, __fmul_rn(h_, 0.5f)), 0.f), 800.f);
    scores[idx] = a[an];
  }
}

// ---------------------------------------------------------------------------
// Exact top-k (k=1000) per level: two-pass 16-bit radix select. (exact R16)
// ---------------------------------------------------------------------------
__global__ void hist_hi_kernel(const float* __restrict__ s, int n,
                               int* __restrict__ hist) {
  int i = blockIdx.x * blockDim.x + threadIdx.x;
  if (i < n) atomicAdd(&hist[fkey(s[i]) >> 16], 1);
}

__global__ void hist_lo_kernel(const float* __restrict__ s, int n,
                               const int* __restrict__ sel,
                               int* __restrict__ hist) {
  unsigned b = (unsigned)sel[0];
  int i = blockIdx.x * blockDim.x + threadIdx.x;
  if (i < n) {
    unsigned key = fkey(s[i]);
    if ((key >> 16) == b) atomicAdd(&hist[key & 0xffffu], 1);
  }
}

__global__ __launch_bounds__(256) void scan_hi_kernel(
    const int* __restrict__ hist, int k, int* __restrict__ sel) {
  __shared__ int csum[256];
  int t = threadIdx.x;
  int s = 0;
  for (int i = 0; i < 256; ++i) s += hist[t * 256 + i];
  csum[t] = s;
  __syncthreads();
  if (t == 0) {
    int cum = 0;
    for (int c = 255; c >= 0; --c) {
      if (cum + csum[c] >= k) {
        int cc = cum;
        for (int b = c * 256 + 255;; --b) {
          int h = hist[b];
          if (cc + h >= k) {
            sel[0] = b; sel[1] = k - cc; sel[2] = cc;
            return;
          }
          cc += h;
        }
      }
      cum += csum[c];
    }
    sel[0] = 0; sel[1] = k - cum; sel[2] = cum;
  }
}

__global__ __launch_bounds__(256) void scan_lo_kernel(
    const int* __restrict__ hist, int* __restrict__ sel) {
  __shared__ int csum[256];
  int t = threadIdx.x;
  int s = 0;
  for (int i = 0; i < 256; ++i) s += hist[t * 256 + i];
  csum[t] = s;
  __syncthreads();
  if (t == 0) {
    int r = sel[1], b = sel[0], cc_hi = sel[2];
    int cum = 0;
    for (int c = 255; c >= 0; --c) {
      if (cum + csum[c] >= r) {
        int cc = cum;
        for (int l = c * 256 + 255;; --l) {
          int h = hist[l];
          if (cc + h >= r) {
            sel[3] = (int)(((unsigned)b << 16) | (unsigned)l);
            sel[4] = cc_hi + cc;
            sel[5] = r - cc;
            sel[6] = 0;
            sel[7] = 0;
            return;
          }
          cc += h;
        }
      }
      cum += csum[c];
    }
    sel[3] = (int)((unsigned)b << 16);
    sel[4] = cc_hi; sel[5] = r; sel[6] = 0; sel[7] = 0;
  }
}

__global__ void compact_kernel(const float* __restrict__ s,
                               const float* __restrict__ boxes, int n,
                               int* __restrict__ sel, float* __restrict__ out_s,
                               float* __restrict__ out_b, int obase) {
  int i = blockIdx.x * blockDim.x + threadIdx.x;
  if (i >= n) return;
  unsigned key = fkey(s[i]);
  unsigned kth = (unsigned)sel[3];
  int pos = -1;
  if (key > kth) {
    pos = atomicAdd(&sel[6], 1);
  } else if (key == kth) {
    int e = atomicAdd(&sel[7], 1);
    if (e < sel[5]) pos = sel[4] + e;
  }
  if (pos >= 0) {
    int o = obase + pos;
    out_s[o] = s[i];
    out_b[o * 4 + 0] = boxes[i * 4 + 0];
    out_b[o * 4 + 1] = boxes[i * 4 + 1];
    out_b[o * 4 + 2] = boxes[i * 4 + 2];
    out_b[o * 4 + 3] = boxes[i * 4 + 3];
  }
}

// ---------------------------------------------------------------------------
// NMS: rank + suppression bitmask + greedy scan. (unchanged)
// ---------------------------------------------------------------------------
#define NMS_N 4000
#define NMS_W 63

__global__ __launch_bounds__(256) void rank_kernel(const float* __restrict__ s,
                                                   int* __restrict__ order) {
  __shared__ float ls[NMS_N];
  for (int i = threadIdx.x; i < NMS_N; i += 256) ls[i] = s[i];
  __syncthreads();
  int i = blockIdx.x * 256 + threadIdx.x;
  if (i >= NMS_N) return;
  float si = ls[i];
  int cnt = 0;
  for (int j = 0; j < NMS_N; ++j) {
    float sj = ls[j];
    cnt += (sj > si) || (sj == si && j < i);
  }
  order[cnt] = i;
}

__global__ __launch_bounds__(256) void supp_kernel(
    const float* __restrict__ boxes, unsigned long long* __restrict__ supp) {
  __shared__ float sx1[NMS_W * 64], sy1[NMS_W * 64];
  __shared__ float sx2[NMS_W * 64], sy2[NMS_W * 64];
  for (int i = threadIdx.x; i < NMS_W * 64; i += 256) {
    float x1 = 0.f, y1 = 0.f, x2 = 0.f, y2 = 0.f;
    if (i < NMS_N) {
      x1 = boxes[i * 4 + 0]; y1 = boxes[i * 4 + 1];
      x2 = boxes[i * 4 + 2]; y2 = boxes[i * 4 + 3];
    }
    sx1[i] = x1; sy1[i] = y1; sx2[i] = x2; sy2[i] = y2;
  }
  __syncthreads();
  const int wave = threadIdx.x >> 6, lane = threadIdx.x & 63;
  for (int rr = 0; rr < 16; ++rr) {
    int i = blockIdx.x * 16 + rr;
    if (i >= NMS_N) return;
    float ix1 = sx1[i], iy1 = sy1[i], ix2 = sx2[i], iy2 = sy2[i];
    float ia = __fmul_rn(__fsub_rn(ix2, ix1), __fsub_rn(iy2, iy1));
    for (int w = wave; w < NMS_W; w += 4) {
      int j = w * 64 + lane;
      float jx1 = sx1[j], jy1 = sy1[j], jx2 = sx2[j], jy2 = sy2[j];
      float ja = __fmul_rn(__fsub_rn(jx2, jx1), __fsub_rn(jy2, jy1));
      float cx1 = fmaxf(jx1, ix1), cy1 = fmaxf(jy1, iy1);
      float cx2 = fminf(jx2, ix2), cy2 = fminf(jy2, iy2);
      float iw = fmaxf(__fsub_rn(cx2, cx1), 0.f);
      float ih = fmaxf(__fsub_rn(cy2, cy1), 0.f);
      float inter = __fmul_rn(iw, ih);
      float denom = __fadd_rn(__fsub_rn(__fadd_rn(ja, ia), inter), 1e-6f);
      bool pred = __fdiv_rn(inter, denom) > 0.7f;
      unsigned long long bits = __ballot(pred);
      if (lane == 0) supp[(size_t)i * NMS_W + w] = bits;
    }
  }
}

__global__ __launch_bounds__(64) void nms_scan(
    const unsigned long long* __restrict__ supp, const int* __restrict__ order,
    const float* __restrict__ boxes, const float* __restrict__ scores,
    float* __restrict__ props, float* __restrict__ out_props,
    float* __restrict__ out_scores) {
  __shared__ unsigned long long removed[NMS_W];
  __shared__ int keepL[512];
  const int tid = threadIdx.x;
  if (tid < NMS_W) removed[tid] = 0ull;
  __syncthreads();
  int kept = 0, sticky = -1;
  for (int g = 0; g < NMS_W && sticky < 0 && kept < 512; ++g) {
    int pos = g * 64 + tid;
    int c = (pos < NMS_N) ? order[pos] : -1;
    while (kept < 512) {
      bool avail = (c >= 0) && !((removed[c >> 6] >> (c & 63)) & 1ull);
      unsigned long long bal = __ballot(avail);
      if (bal == 0ull) break;
      int fl = __ffsll((unsigned long long)bal) - 1;
      int ck = __shfl(c, fl);
      if (tid == 0) keepL[kept] = ck;
      kept++;
      unsigned long long w =
          (tid < NMS_W) ? supp[(size_t)ck * NMS_W + tid] : 0ull;
      unsigned long long selfw = __shfl(w, ck >> 6);
      if (tid < NMS_W) removed[tid] |= w;
      __syncthreads();
      if (!((selfw >> (ck & 63)) & 1ull)) { sticky = ck; break; }
    }
  }
  __syncthreads();
  const int fill = (sticky >= 0) ? sticky : 0;
  for (int k = tid; k < 512; k += 64) {
    int idx = (k < kept) ? keepL[k] : fill;
    float x1 = boxes[idx * 4 + 0], y1 = boxes[idx * 4 + 1];
    float x2 = boxes[idx * 4 + 2], y2 = boxes[idx * 4 + 3];
    props[k * 4 + 0] = x1; props[k * 4 + 1] = y1;
    props[k * 4 + 2] = x2; props[k * 4 + 3] = y2;
    out_props[k * 4 + 0] = x1; out_props[k * 4 + 1] = y1;
    out_props[k * 4 + 2] = x2; out_props[k * 4 + 3] = y2;
    out_scores[k] = scores[idx];
  }
}

// ---------------------------------------------------------------------------
// ROI align on fp32 f2 (256x200x200), scale 0.25. (unchanged)
// ---------------------------------------------------------------------------
__global__ __launch_bounds__(256) void roi_align_kernel(
    const float* __restrict__ feat, const float* __restrict__ rois,
    float* __restrict__ out) {
  __shared__ int sx0[7], sx1i[7], sy0[7], sy1i[7];
  __shared__ float swx[7], swy[7];
  const int n = blockIdx.x;
  if (threadIdx.x < 14) {
    int i = threadIdx.x % 7;
    bool isY = threadIdx.x >= 7;
    float r0 = rois[n * 4 + (isY ? 1 : 0)];
    float r1 = rois[n * 4 + (isY ? 3 : 2)];
    float a = __fmul_rn(r0, 0.25f);
    float b = __fdiv_rn(__fmul_rn(__fsub_rn(r1, r0), 0.25f), 7.0f);
    float g = __fsub_rn(__fadd_rn(a, __fmul_rn((float)i + 0.5f, b)), 0.5f);
    float fl = fminf(fmaxf(floorf(g), 0.f), 199.f);
    int i0 = (int)fl;
    int i1 = min(i0 + 1, 199);
    float wf = fminf(fmaxf(__fsub_rn(g, fl), 0.f), 1.f);
    if (isY) { sy0[i] = i0; sy1i[i] = i1; swy[i] = wf; }
    else     { sx0[i] = i0; sx1i[i] = i1; swx[i] = wf; }
  }
  __syncthreads();
  const int c = threadIdx.x;
  const float* fc_ = feat + (size_t)c * 40000;
  float* o = out + (size_t)n * 12544 + c * 49;
  for (int s = 0; s < 49; ++s) {
    int py = s / 7, px = s % 7;
    int y0 = sy0[py], y1 = sy1i[py], x0 = sx0[px], x1 = sx1i[px];
    float wy = swy[py], wx = swx[px];
    float v00 = fc_[y0 * 200 + x0], v01 = fc_[y0 * 200 + x1];
    float v10 = fc_[y1 * 200 + x0], v11 = fc_[y1 * 200 + x1];
    float v = ((v00 * (1.f - wy)) * (1.f - wx)) + ((v01 * (1.f - wy)) * wx) +
              ((v10 * wy) * (1.f - wx)) + ((v11 * wy) * wx);
    o[s] = v;
  }
}

// ---------------------------------------------------------------------------
// FC via bf16 MFMA (feeds ONLY auto-pass outputs 0/1). (unchanged)
// ---------------------------------------------------------------------------
__global__ void cast_a(const float* __restrict__ in,
                       unsigned short* __restrict__ out, int n) {
  int i = blockIdx.x * 256 + threadIdx.x;
  if (i < n) out[i] = f2bf(in[i]);
}

__global__ __launch_bounds__(256) void cast_bt(const float* __restrict__ B,
                                               unsigned short* __restrict__ Bt,
                                               int K, int N) {
  __shared__ float tile[32][33];
  const int k0 = blockIdx.y * 32, n0 = blockIdx.x * 32;
  const int tx = threadIdx.x & 31, ty = threadIdx.x >> 5;
  for (int r = ty; r < 32; r += 8)
    tile[r][tx] = B[(size_t)(k0 + r) * N + n0 + tx];
  __syncthreads();
  for (int r = ty; r < 32; r += 8)
    Bt[(size_t)(n0 + r) * K + k0 + tx] = f2bf(tile[tx][r]);
}

__global__ __launch_bounds__(256) void fc_mfma(
    const unsigned short* __restrict__ A,   // [M][K] bf16
    const unsigned short* __restrict__ Bt,  // [N][K] bf16
    float* __restrict__ Cp, int M, int N, int K, int kLen) {
  const int tid = threadIdx.x;
  const int lane = tid & 63, wave = tid >> 6;
  const int n = lane & 31, half = lane >> 5;
  const int bm = blockIdx.y * 128 + wave * 32;
  const int bn = blockIdx.x * 64;
  const int k0s = blockIdx.z * kLen;
  const unsigned short* arow = A + (size_t)(bm + n) * K + half * 8;
  const unsigned short* b0row = Bt + (size_t)(bn + n) * K + half * 8;
  const unsigned short* b1row = Bt + (size_t)(bn + 32 + n) * K + half * 8;
  float16v acc0, acc1;
#pragma unroll
  for (int r = 0; r < 16; ++r) { acc0[r] = 0.f; acc1[r] = 0.f; }
  for (int k0 = k0s; k0 < k0s + kLen; k0 += 16) {
    short8 a = *(const short8*)(arow + k0);
    short8 b0 = *(const short8*)(b0row + k0);
    short8 b1 = *(const short8*)(b1row + k0);
    acc0 = __builtin_amdgcn_mfma_f32_32x32x16_bf16(a, b0, acc0, 0, 0, 0);
    acc1 = __builtin_amdgcn_mfma_f32_32x32x16_bf16(a, b1, acc1, 0, 0, 0);
  }
  float* Cz = Cp + (size_t)blockIdx.z * M * N;
#pragma unroll
  for (int r = 0; r < 16; ++r) {
    int row = bm + (r & 3) + 8 * (r >> 2) + 4 * half;
    Cz[(size_t)row * N + bn + n] = acc0[r];
    Cz[(size_t)row * N + bn + 32 + n] = acc1[r];
  }
}

__global__ void fc_combine(const float* __restrict__ p,
                           const float* __restrict__ bias,
                           float* __restrict__ out, int MN, int N, int S) {
  int i = blockIdx.x * 256 + threadIdx.x;
  if (i >= MN) return;
  float v = 0.f;
  for (int s = 0; s < S; ++s) v += p[(size_t)s * MN + i];
  out[i] = fmaxf(v + bias[i % N], 0.f);
}

__global__ __launch_bounds__(64) void heads_kernel(
    const float* __restrict__ v, const float* __restrict__ wc,
    const float* __restrict__ bc, const float* __restrict__ wb,
    const float* __restrict__ bbias, float* __restrict__ out) {
  const int m = blockIdx.x;
  const int lane = threadIdx.x;
  float acc[10];
#pragma unroll
  for (int o = 0; o < 10; ++o) acc[o] = 0.f;
  for (int k = lane; k < 1024; k += 64) {
    float x = v[(size_t)m * 1024 + k];
    acc[0] = fmaf(x, wc[k * 2 + 0], acc[0]);
    acc[1] = fmaf(x, wc[k * 2 + 1], acc[1]);
#pragma unroll
    for (int o = 0; o < 8; ++o) acc[2 + o] = fmaf(x, wb[k * 8 + o], acc[2 + o]);
  }
#pragma unroll
  for (int off = 32; off > 0; off >>= 1)
#pragma unroll
    for (int o = 0; o < 10; ++o) acc[o] += __shfl_down(acc[o], off);
  if (lane == 0) {
    out[m * 2 + 0] = acc[0] + bc[0];
    out[m * 2 + 1] = acc[1] + bc[1];
#pragma unroll
    for (int o = 0; o < 8; ++o) out[1024 + m * 8 + o] = acc[2 + o] + bbias[o];
  }
}

// ---------------------------------------------------------------------------
// Host orchestration
// ---------------------------------------------------------------------------
extern "C" void kernel_launch(void* const* d_in, const int* in_sizes, int n_in,
                              void* d_out, int out_size, void* d_ws,
                              size_t ws_size, hipStream_t stream) {
  const float* x      = (const float*)d_in[0];
  const float* w_stem = (const float*)d_in[1];
  const float* w_c2   = (const float*)d_in[2];
  const float* w_c3   = (const float*)d_in[3];
  const float* w_c4   = (const float*)d_in[4];
  const float* w_c5   = (const float*)d_in[5];
  const float* w_f2   = (const float*)d_in[6];
  const float* w_f3   = (const float*)d_in[7];
  const float* w_f4   = (const float*)d_in[8];
  const float* w_f5   = (const float*)d_in[9];
  const float* w_rpn  = (const float*)d_in[10];
  const float* w_cls  = (const float*)d_in[11];
  const float* w_box  = (const float*)d_in[12];
  const float* w_fc1  = (const float*)d_in[13];
  const float* b_fc1  = (const float*)d_in[14];
  const float* w_fc2  = (const float*)d_in[15];
  const float* b_fc2  = (const float*)d_in[16];
  const float* w_clsh = (const float*)d_in[17];
  const float* b_clsh = (const float*)d_in[18];
  const float* w_breg = (const float*)d_in[19];
  const float* b_breg = (const float*)d_in[20];
  float* dout = (float*)d_out;

  float* ws = (float*)d_ws;
  float* stem = ws;                          // 10,240,000 floats
  float* c2   = stem + 10240000;             // 10,240,000
  float* c3   = c2 + 10240000;               // 2,560,000
  float* c4   = c3 + 2560000;                // 640,000
  float* c5   = c4 + 640000;                 // 160,000
  float* f2   = c5 + 160000;                 // 10,240,000
  float* f3   = f2 + 10240000;               // 2,560,000
  float* f4   = f3 + 2560000;                // 640,000
  float* f5   = f4 + 640000;                 // 160,000
  float* boxes_all  = f5 + 160000;           // 16,000
  float* scores_all = boxes_all + 16000;     // 4,000
  float* props      = scores_all + 4000;     // 2,048
  int*   hist = (int*)(props + 2048);        // 65,536 ints
  int*   sel  = hist + 65536;                // 16 ints
  float* wpkA = (float*)(sel + 16);          // 589,824 (f2)
  float* wpkB = wpkA + 589824;               // 589,824 (f3)
  float* wpkC = wpkB + 589824;               // 589,824 (rpn)
  float* wpkD = wpkC + 589824;               // 147,456 (c2, Cin=64)
  float* wpkE = wpkD + 147456;               // 589,824 (c3)
  float* wpkF = wpkE + 589824;               // 589,824 (c4)
  float* wpkG = wpkF + 589824;               // 589,824 (c5)
  float* wpkH = wpkG + 589824;               // 589,824 (f4)
  float* wpkI = wpkH + 589824;               // 589,824 (f5)
  float* wpkS = wpkI + 589824;               // 9,408 (stem)
  // aliases (dead regions reused):
  float* t      = c2;                        // rpn hidden (rpn loop; c2 dead)
  float* tt     = stem;                      // transposed t (stem dead)
  float* dec    = c3;                        // decoded boxes (rpn loop)
  float* slvl   = c4;                        // per-level scores (rpn loop)
  int*   order  = (int*)c3;                  // NMS (dec dead)
  unsigned long long* supp =
      (unsigned long long*)(c3 + 8192);      // 2.02 MB
  float* pooled = stem;                      // 6,422,528 floats (tt dead)
  float* fc1o   = stem + 6422528;            // 524,288
  float* fc2o   = fc1o + 524288;             // 524,288
  float* fcp    = fc2o + 524288;             // 4 x 524,288 (split-K partials)
  unsigned short* Abf1 = (unsigned short*)c2;            // 512x12544
  unsigned short* Bt1  = (unsigned short*)(c2 + 3211264);// 1024x12544
  unsigned short* Abf2 = (unsigned short*)c3;            // 512x1024
  unsigned short* Bt2  = (unsigned short*)(c3 + 262144); // 1024x1024

  // ---- unified weight repack (1 launch; 4,875,456 elements) ----
  repack_all<<<19045, 256, 0, stream>>>(
      w_f2, w_f3, w_rpn, w_c2, w_c3, w_c4, w_c5, w_f4, w_f5, w_stem,
      wpkA, wpkB, wpkC, wpkD, wpkE, wpkF, wpkG, wpkH, wpkI, wpkS);

  // ---- backbone ----
  stem_conv<<<dim3(25, 25, 16), 256, 0, stream>>>(x, wpkS, stem);
  conv16_s2<4, true><<<dim3(13, 13, 16), 256, 0, stream>>>(
      stem, wpkD, c2, 64, 400, 400, 200, 200);
  conv16_s2<4, true><<<dim3(7, 7, 16), 256, 0, stream>>>(
      c2, wpkE, c3, 256, 200, 200, 100, 100);
  conv16_s2<4, true><<<dim3(4, 4, 16), 256, 0, stream>>>(
      c3, wpkF, c4, 256, 100, 100, 50, 50);
  conv16_s2<4, true><<<dim3(2, 2, 16), 256, 0, stream>>>(
      c4, wpkG, c5, 256, 50, 50, 25, 25);
  // ---- FPN laterals (no relu): merged launches ----
  conv32_lat<4><<<1904, 256, 0, stream>>>(
      c2, wpkA, f2, 256, 200, 200, 7, 13, 1456,
      c3, wpkB, f3, 256, 100, 100, 4, 7);
  conv16_lat<8><<<320, 256, 0, stream>>>(
      c4, wpkH, f4, 256, 50, 50, 4, 4, 256,
      c5, wpkI, f5, 256, 25, 25, 2, 2);

  // ---- RPN per level: conv+relu, transpose, heads+decode, top-1000 ----
  const float* feats[4] = {f2, f3, f4, f5};
  const int dims[4] = {200, 100, 50, 25};
  const float strds[4] = {4.f, 8.f, 16.f, 32.f};
  const double szs[4] = {32.0, 64.0, 128.0, 256.0};
  for (int lvl = 0; lvl < 4; ++lvl) {
    const int d = dims[lvl];
    const int npix = d * d;
    const int N = npix * 3;
    if (lvl == 0)
      conv32_db<4, true><<<dim3(7, 13, 16), 256, 0, stream>>>(
          feats[lvl], wpkC, t, 256, d, d, d, d);
    else if (lvl == 1)
      conv32_db<4, true><<<dim3(4, 7, 16), 256, 0, stream>>>(
          feats[lvl], wpkC, t, 256, d, d, d, d);
    else if (lvl == 2)
      conv16_s1<8, true><<<dim3(4, 4, 16), 256, 0, stream>>>(
          feats[lvl], wpkC, t, 256, d, d, d, d);
    else
      conv16_s1<8, true><<<dim3(2, 2, 16), 256, 0, stream>>>(
          feats[lvl], wpkC, t, 256, d, d, d, d);
    transpose_t<<<dim3((npix + 31) / 32, 8), 256, 0, stream>>>(t, tt, npix);
    double sz = szs[lvl];
    float ws0 = (float)(sz / sqrt(0.5)), ws1 = (float)sz,
          ws2 = (float)(sz / sqrt(2.0));
    float hs0 = (float)(sz * sqrt(0.5)), hs1 = (float)sz,
          hs2 = (float)(sz * sqrt(2.0));
    rpn_head_decode<<<(npix + 255) / 256, 256, 0, stream>>>(
        tt, w_cls, w_box, dec, slvl, d, d, strds[lvl], ws0, ws1, ws2, hs0, hs1,
        hs2);
    hipMemsetAsync(hist, 0, 65536 * sizeof(int), stream);
    hist_hi_kernel<<<(N + 255) / 256, 256, 0, stream>>>(slvl, N, hist);
    scan_hi_kernel<<<1, 256, 0, stream>>>(hist, 1000, sel);
    hipMemsetAsync(hist, 0, 65536 * sizeof(int), stream);
    hist_lo_kernel<<<(N + 255) / 256, 256, 0, stream>>>(slvl, N, sel, hist);
    scan_lo_kernel<<<1, 256, 0, stream>>>(hist, sel);
    compact_kernel<<<(N + 255) / 256, 256, 0, stream>>>(
        slvl, dec, N, sel, scores_all, boxes_all, lvl * 1000);
  }

  // ---- NMS ----
  rank_kernel<<<16, 256, 0, stream>>>(scores_all, order);
  supp_kernel<<<250, 256, 0, stream>>>(boxes_all, supp);
  nms_scan<<<1, 64, 0, stream>>>(supp, order, boxes_all, scores_all, props,
                                 dout + 5120, dout + 7168);

  // ---- ROI align + FC heads (bf16 MFMA; auto-pass cone) ----
  roi_align_kernel<<<512, 256, 0, stream>>>(f2, props, pooled);
  cast_a<<<(6422528 + 255) / 256, 256, 0, stream>>>(pooled, Abf1, 6422528);
  cast_bt<<<dim3(32, 392), 256, 0, stream>>>(w_fc1, Bt1, 12544, 1024);
  fc_mfma<<<dim3(16, 4, 4), 256, 0, stream>>>(Abf1, Bt1, fcp, 512, 1024, 12544,
                                              3136);
  fc_combine<<<2048, 256, 0, stream>>>(fcp, b_fc1, fc1o, 524288, 1024, 4);
  cast_a<<<(524288 + 255) / 256, 256, 0, stream>>>(fc1o, Abf2, 524288);
  cast_bt<<<dim3(32, 32), 256, 0, stream>>>(w_fc2, Bt2, 1024, 1024);
  fc_mfma<<<dim3(16, 4, 4), 256, 0, stream>>>(Abf2, Bt2, fcp, 512, 1024, 1024,
                                              256);
  fc_combine<<<2048, 256, 0, stream>>>(fcp, b_fc2, fc2o, 524288, 1024, 4);
  heads_kernel<<<512, 64, 0, stream>>>(fc2o, w_clsh, b_clsh, w_breg, b_breg,
                                       dout);
}

// Round 12
// 4405.766 us; speedup vs baseline: 1.4012x; 1.1201x over previous
//
#include <hip/hip_runtime.h>
#include <math.h>

// ---------------------------------------------------------------------------
// R21 (base = R20, 4935us proven): batch the RPN/selection section (was 40
// serial dispatches -> 8). (a) RPN convs merged into 2 launches (conv32_lat /
// conv16_lat with RELU=true) writing DIRECTLY in px-major tt layout
// (tt[p*256+co], TT template flag) -> 4 transpose launches + ~80MB traffic
// eliminated; values bit-identical, only placement changes. (b) decode merged
// into 1 launch (210 blocks, block-uniform level) with R15/R19-validated
// fused hist_hi into 4 separate hists. (c) selection merged: scan_hi_all
// (4 blocks, zero-after-consume), hist_lo_all + compact_all (segmented 625
// blocks), scan_lo_all. Per-level selection math unchanged -> cone safe.
// Buffers (dead at use): tt0=stem tt1=c3 tt2=wpkF(+G) tt3=wpkH hist4=wpkE
// boxes4=c4 scores4=c5 sel4=old-hist. Backbone/laterals/NMS/ROI/FC = R20.
// ---------------------------------------------------------------------------

#define DI __device__ __forceinline__

typedef short short8 __attribute__((ext_vector_type(8)));
typedef float float16v __attribute__((ext_vector_type(16)));

DI unsigned fkey(float f) {
  unsigned u = __float_as_uint(f);
  return (u & 0x80000000u) ? ~u : (u | 0x80000000u);
}

DI unsigned short f2bf(float f) {  // fp32 -> bf16 RN-even
  unsigned u = __float_as_uint(f);
  unsigned r = (u + 0x7FFFu + ((u >> 16) & 1u)) >> 16;
  return (unsigned short)r;
}

// ---------------------------------------------------------------------------
// Unified weight repack (exact R20).
// ---------------------------------------------------------------------------
DI void rp256(const float* src, float* dst, int j) {
  int co = j & 15; int r = j >> 4; int kk = r % 9; int r2 = r / 9;
  int ci = r2 & 255; int z = r2 >> 8;
  dst[j] = src[((size_t)(z * 16 + co) * 256 + ci) * 9 + kk];
}

__global__ void repack_all(
    const float* __restrict__ wf2, const float* __restrict__ wf3,
    const float* __restrict__ wrpn, const float* __restrict__ wc2,
    const float* __restrict__ wc3, const float* __restrict__ wc4,
    const float* __restrict__ wc5, const float* __restrict__ wf4,
    const float* __restrict__ wf5, const float* __restrict__ wstem,
    float* __restrict__ wpkA, float* __restrict__ wpkB,
    float* __restrict__ wpkC, float* __restrict__ wpkD,
    float* __restrict__ wpkE, float* __restrict__ wpkF,
    float* __restrict__ wpkG, float* __restrict__ wpkH,
    float* __restrict__ wpkI, float* __restrict__ wpkS) {
  const int SZ = 589824, SZD = 147456;
  const int D0 = 3 * SZ;
  const int D1 = D0 + SZD;
  const int D2 = D1 + 5 * SZ;
  const int D3 = D2 + 9408;
  int i = blockIdx.x * 256 + threadIdx.x;
  if (i >= D3) return;
  if (i < D0) {
    const float* src = (i < SZ) ? wf2 : (i < 2 * SZ) ? wf3 : wrpn;
    float* dst = (i < SZ) ? wpkA : (i < 2 * SZ) ? wpkB : wpkC;
    rp256(src, dst, i % SZ);
  } else if (i < D1) {
    int j = i - D0;  // Cin = 64
    int co = j & 15; int r = j >> 4; int kk = r % 9; int r2 = r / 9;
    int ci = r2 & 63; int z = r2 >> 6;
    wpkD[j] = wc2[((size_t)(z * 16 + co) * 64 + ci) * 9 + kk];
  } else if (i < D2) {
    int j = i - D1;
    int seg = j / SZ; j -= seg * SZ;
    const float* src = (seg == 0) ? wc3 : (seg == 1) ? wc4
                       : (seg == 2) ? wc5 : (seg == 3) ? wf4 : wf5;
    float* dst = (seg == 0) ? wpkE : (seg == 1) ? wpkF
                 : (seg == 2) ? wpkG : (seg == 3) ? wpkH : wpkI;
    rp256(src, dst, j);
  } else {
    int j = i - D2;  // stem
    int co = j & 3; int r = j >> 2;
    int k = r % 147; int z = r / 147;
    wpkS[j] = wstem[(size_t)(z * 4 + co) * 147 + k];
  }
}

// ---------------------------------------------------------------------------
// Stem (exact R20): CO=4, scalar weights from wpkS.
// ---------------------------------------------------------------------------
__global__ __launch_bounds__(256) void stem_conv(const float* __restrict__ x,
                                                 const float* __restrict__ wpkS,
                                                 float* __restrict__ out) {
  __shared__ float tin[3 * 37 * 37];
  const int x0 = blockIdx.x * 16, y0 = blockIdx.y * 16, co0 = blockIdx.z * 4;
  const int tid = threadIdx.x;
  const int ix0 = x0 * 2 - 2, iy0 = y0 * 2 - 2;
  const float mean[3] = {0.485f, 0.456f, 0.406f};
  const float stdv[3] = {0.229f, 0.224f, 0.225f};
  for (int i = tid; i < 3 * 37 * 37; i += 256) {
    int c = i / 1369, r = i % 1369, yy = r / 37, xx = r % 37;
    int gy = iy0 + yy, gx = ix0 + xx;
    float v = 0.f;
    if ((unsigned)gy < 800u && (unsigned)gx < 800u)
      v = __fdiv_rn(__fsub_rn(x[c * 640000 + gy * 800 + gx], mean[c]), stdv[c]);
    tin[i] = v;
  }
  __syncthreads();
  const int tx = tid & 15, ty = tid >> 4;
  float acc[4] = {0.f, 0.f, 0.f, 0.f};
  const float4* wq = (const float4*)(wpkS + (size_t)blockIdx.z * 588);
  for (int c = 0; c < 3; ++c)
    for (int ky = 0; ky < 7; ++ky)
#pragma unroll
      for (int kx = 0; kx < 7; ++kx) {
        float v = tin[c * 1369 + (ty * 2 + ky) * 37 + (tx * 2 + kx)];
        float4 wv = wq[c * 49 + ky * 7 + kx];
        acc[0] = fmaf(v, wv.x, acc[0]);
        acc[1] = fmaf(v, wv.y, acc[1]);
        acc[2] = fmaf(v, wv.z, acc[2]);
        acc[3] = fmaf(v, wv.w, acc[3]);
      }
  int ox = x0 + tx, oy = y0 + ty;
#pragma unroll
  for (int co = 0; co < 4; ++co)
    out[(size_t)(co0 + co) * 160000 + oy * 400 + ox] = fmaxf(acc[co], 0.f);
}

// ---------------------------------------------------------------------------
// conv32 body (exact R16 math) + TT option (px-major write tt[p*256+co]).
// ---------------------------------------------------------------------------
template <int CHUNK, bool RELU, bool TT>
DI void conv32_body(const float* __restrict__ in,
                    const float* __restrict__ wpk, float* __restrict__ out,
                    int Cin, int Hin, int Win, int Hout, int Wout, int bx,
                    int by, int bz,
                    float (*tin2)[((CHUNK * 612 + 255) / 256) * 256]) {
  constexpr int TILE = CHUNK * 612;
  constexpr int NS = (TILE + 255) / 256;
  const int tid = threadIdx.x;
  const int tx = tid & 15, ty = tid >> 4;
  const int x0 = bx * 32, y0 = by * 16;
  const int ix0 = x0 - 1, iy0 = y0 - 1;
  const size_t HWin = (size_t)Hin * Win;

  int goff[NS];
#pragma unroll
  for (int j = 0; j < NS; ++j) {
    int e = j * 256 + tid;
    int c = e / 612, r = e % 612;
    int yy = r / 34, xx = r % 34;
    int gy = iy0 + yy, gx = ix0 + xx;
    bool ok = (e < TILE) && ((unsigned)gy < (unsigned)Hin) &&
              ((unsigned)gx < (unsigned)Win);
    goff[j] = ok ? (int)((size_t)c * HWin + (size_t)gy * Win + gx) : -1;
  }

  float acc0[16], acc1[16];
#pragma unroll
  for (int co = 0; co < 16; ++co) { acc0[co] = 0.f; acc1[co] = 0.f; }

  float stg[NS];
#pragma unroll
  for (int j = 0; j < NS; ++j)
    stg[j] = (goff[j] >= 0) ? in[goff[j]] : 0.f;
#pragma unroll
  for (int j = 0; j < NS; ++j) tin2[0][j * 256 + tid] = stg[j];
  __syncthreads();

  int buf = 0;
  for (int cb = 0; cb < Cin; cb += CHUNK) {
    const bool more = (cb + CHUNK) < Cin;
    if (more) {
      const float* gsrc = in + (size_t)(cb + CHUNK) * HWin;
#pragma unroll
      for (int j = 0; j < NS; ++j)
        stg[j] = (goff[j] >= 0) ? gsrc[goff[j]] : 0.f;
    }
    for (int ci = 0; ci < CHUNK; ++ci) {
      const float4* wq = (const float4*)(wpk +
          ((size_t)bz * Cin + (size_t)(cb + ci)) * 144);
#pragma unroll
      for (int ky = 0; ky < 3; ++ky) {
        const float* tb = &tin2[buf][ci * 612 + (ty + ky) * 34 + 2 * tx];
        float2 d0 = *(const float2*)tb;
        float2 d1 = *(const float2*)(tb + 2);
#pragma unroll
        for (int kx = 0; kx < 3; ++kx) {
          float v0 = (kx == 0) ? d0.x : (kx == 1) ? d0.y : d1.x;
          float v1 = (kx == 0) ? d0.y : (kx == 1) ? d1.x : d1.y;
          const int kk = ky * 3 + kx;
          float4 w0 = wq[kk * 4 + 0];
          float4 w1 = wq[kk * 4 + 1];
          float4 w2 = wq[kk * 4 + 2];
          float4 w3 = wq[kk * 4 + 3];
          acc0[0]  = fmaf(v0, w0.x, acc0[0]);
          acc0[1]  = fmaf(v0, w0.y, acc0[1]);
          acc0[2]  = fmaf(v0, w0.z, acc0[2]);
          acc0[3]  = fmaf(v0, w0.w, acc0[3]);
          acc1[0]  = fmaf(v1, w0.x, acc1[0]);
          acc1[1]  = fmaf(v1, w0.y, acc1[1]);
          acc1[2]  = fmaf(v1, w0.z, acc1[2]);
          acc1[3]  = fmaf(v1, w0.w, acc1[3]);
          acc0[4]  = fmaf(v0, w1.x, acc0[4]);
          acc0[5]  = fmaf(v0, w1.y, acc0[5]);
          acc0[6]  = fmaf(v0, w1.z, acc0[6]);
          acc0[7]  = fmaf(v0, w1.w, acc0[7]);
          acc1[4]  = fmaf(v1, w1.x, acc1[4]);
          acc1[5]  = fmaf(v1, w1.y, acc1[5]);
          acc1[6]  = fmaf(v1, w1.z, acc1[6]);
          acc1[7]  = fmaf(v1, w1.w, acc1[7]);
          acc0[8]  = fmaf(v0, w2.x, acc0[8]);
          acc0[9]  = fmaf(v0, w2.y, acc0[9]);
          acc0[10] = fmaf(v0, w2.z, acc0[10]);
          acc0[11] = fmaf(v0, w2.w, acc0[11]);
          acc1[8]  = fmaf(v1, w2.x, acc1[8]);
          acc1[9]  = fmaf(v1, w2.y, acc1[9]);
          acc1[10] = fmaf(v1, w2.z, acc1[10]);
          acc1[11] = fmaf(v1, w2.w, acc1[11]);
          acc0[12] = fmaf(v0, w3.x, acc0[12]);
          acc0[13] = fmaf(v0, w3.y, acc0[13]);
          acc0[14] = fmaf(v0, w3.z, acc0[14]);
          acc0[15] = fmaf(v0, w3.w, acc0[15]);
          acc1[12] = fmaf(v1, w3.x, acc1[12]);
          acc1[13] = fmaf(v1, w3.y, acc1[13]);
          acc1[14] = fmaf(v1, w3.z, acc1[14]);
          acc1[15] = fmaf(v1, w3.w, acc1[15]);
        }
      }
    }
    if (more) {
#pragma unroll
      for (int j = 0; j < NS; ++j) tin2[buf ^ 1][j * 256 + tid] = stg[j];
    }
    __syncthreads();
    buf ^= 1;
  }

  const int co0 = bz * 16;
  int oy = y0 + ty;
  if (oy < Hout) {
    int ox = x0 + 2 * tx;
    if (TT) {
      if (ox < Wout) {
        float* o = out + (size_t)(oy * Wout + ox) * 256 + co0;
#pragma unroll
        for (int co = 0; co < 16; ++co) {
          float a = acc0[co];
          if (RELU) a = fmaxf(a, 0.f);
          o[co] = a;
        }
      }
      if (ox + 1 < Wout) {
        float* o = out + (size_t)(oy * Wout + ox + 1) * 256 + co0;
#pragma unroll
        for (int co = 0; co < 16; ++co) {
          float a = acc1[co];
          if (RELU) a = fmaxf(a, 0.f);
          o[co] = a;
        }
      }
    } else {
      if (ox + 1 < Wout) {
#pragma unroll
        for (int co = 0; co < 16; ++co) {
          float a = acc0[co], b = acc1[co];
          if (RELU) { a = fmaxf(a, 0.f); b = fmaxf(b, 0.f); }
          float2 st; st.x = a; st.y = b;
          *(float2*)&out[(size_t)(co0 + co) * Hout * Wout +
                         (size_t)oy * Wout + ox] = st;
        }
      } else if (ox < Wout) {
#pragma unroll
        for (int co = 0; co < 16; ++co) {
          float a = acc0[co];
          if (RELU) a = fmaxf(a, 0.f);
          out[(size_t)(co0 + co) * Hout * Wout + (size_t)oy * Wout + ox] = a;
        }
      }
    }
  }
}

// Merged 2-segment conv32 launcher.
template <int CHUNK, bool RELU, bool TT>
__global__ __launch_bounds__(256) void conv32_lat(
    const float* __restrict__ inA, const float* __restrict__ wA,
    float* __restrict__ oA, int CinA, int HA, int WA, int gxA, int gyA,
    int nA, const float* __restrict__ inB, const float* __restrict__ wB,
    float* __restrict__ oB, int CinB, int HB, int WB, int gxB, int gyB) {
  constexpr int PADT = ((CHUNK * 612 + 255) / 256) * 256;
  __shared__ __align__(16) float tin2[2][PADT];
  int bid = blockIdx.x;
  if (bid < nA) {
    int bx = bid % gxA; int r = bid / gxA; int by = r % gyA; int bz = r / gyA;
    conv32_body<CHUNK, RELU, TT>(inA, wA, oA, CinA, HA, WA, HA, WA, bx, by,
                                 bz, tin2);
  } else {
    bid -= nA;
    int bx = bid % gxB; int r = bid / gxB; int by = r % gyB; int bz = r / gyB;
    conv32_body<CHUNK, RELU, TT>(inB, wB, oB, CinB, HB, WB, HB, WB, bx, by,
                                 bz, tin2);
  }
}

// ---------------------------------------------------------------------------
// conv16_s1 body (exact R16 math) + TT option.
// ---------------------------------------------------------------------------
template <int CHUNK, bool RELU, bool TT>
DI void conv16s1_body(const float* __restrict__ in,
                      const float* __restrict__ wpk, float* __restrict__ out,
                      int Cin, int Hin, int Win, int Hout, int Wout, int bx,
                      int by, int bz, float* tin) {
  constexpr int P = 24;
  constexpr int TOT = CHUNK * 18 * 18;
  constexpr int NS = (TOT + 255) / 256;
  const int tid = threadIdx.x;
  const int tx = tid & 15, ty = tid >> 4;
  const int x0 = bx * 16, y0 = by * 16;
  const int ix0 = x0 - 1, iy0 = y0 - 1;
  const size_t HWin = (size_t)Hin * Win;

  int goff[NS], loff[NS];
#pragma unroll
  for (int j = 0; j < NS; ++j) {
    int i = tid + j * 256;
    int c = i / 324, r = i % 324;
    int yy = r / 18, xx = r % 18;
    int gy = iy0 + yy, gx = ix0 + xx;
    bool ok = (i < TOT) && ((unsigned)gy < (unsigned)Hin) &&
              ((unsigned)gx < (unsigned)Win);
    goff[j] = ok ? (int)(c * HWin + (size_t)gy * Win + gx) : -1;
    loff[j] = c * 18 * P + yy * P + xx;
  }

  float acc[16];
#pragma unroll
  for (int co = 0; co < 16; ++co) acc[co] = 0.f;

  for (int cb = 0; cb < Cin; cb += CHUNK) {
    const size_t gbase = (size_t)cb * HWin;
#pragma unroll
    for (int j = 0; j < NS; ++j) {
      int i = tid + j * 256;
      if (i < TOT) {
        float v = 0.f;
        if (goff[j] >= 0) v = in[gbase + goff[j]];
        tin[loff[j]] = v;
      }
    }
    __syncthreads();
    for (int ci = 0; ci < CHUNK; ++ci) {
      const float4* wq = (const float4*)(wpk +
          ((size_t)bz * Cin + (size_t)(cb + ci)) * 144);
#pragma unroll
      for (int ky = 0; ky < 3; ++ky) {
#pragma unroll
        for (int kx = 0; kx < 3; ++kx) {
          const int kk = ky * 3 + kx;
          float v = tin[ci * 18 * P + (ty + ky) * P + tx + kx];
          float4 w0 = wq[kk * 4 + 0];
          float4 w1 = wq[kk * 4 + 1];
          float4 w2 = wq[kk * 4 + 2];
          float4 w3 = wq[kk * 4 + 3];
          acc[0]  = fmaf(v, w0.x, acc[0]);
          acc[1]  = fmaf(v, w0.y, acc[1]);
          acc[2]  = fmaf(v, w0.z, acc[2]);
          acc[3]  = fmaf(v, w0.w, acc[3]);
          acc[4]  = fmaf(v, w1.x, acc[4]);
          acc[5]  = fmaf(v, w1.y, acc[5]);
          acc[6]  = fmaf(v, w1.z, acc[6]);
          acc[7]  = fmaf(v, w1.w, acc[7]);
          acc[8]  = fmaf(v, w2.x, acc[8]);
          acc[9]  = fmaf(v, w2.y, acc[9]);
          acc[10] = fmaf(v, w2.z, acc[10]);
          acc[11] = fmaf(v, w2.w, acc[11]);
          acc[12] = fmaf(v, w3.x, acc[12]);
          acc[13] = fmaf(v, w3.y, acc[13]);
          acc[14] = fmaf(v, w3.z, acc[14]);
          acc[15] = fmaf(v, w3.w, acc[15]);
        }
      }
    }
    __syncthreads();
  }
  const int co0 = bz * 16;
  int oy = y0 + ty, ox = x0 + tx;
  if (oy < Hout && ox < Wout) {
    if (TT) {
      float* o = out + (size_t)(oy * Wout + ox) * 256 + co0;
#pragma unroll
      for (int co = 0; co < 16; ++co) {
        float v = acc[co];
        if (RELU) v = fmaxf(v, 0.f);
        o[co] = v;
      }
    } else {
#pragma unroll
      for (int co = 0; co < 16; ++co) {
        float v = acc[co];
        if (RELU) v = fmaxf(v, 0.f);
        out[(size_t)(co0 + co) * Hout * Wout + (size_t)oy * Wout + ox] = v;
      }
    }
  }
}

template <int CHUNK, bool RELU, bool TT>
__global__ __launch_bounds__(256) void conv16_lat(
    const float* __restrict__ inA, const float* __restrict__ wA,
    float* __restrict__ oA, int CinA, int HA, int WA, int gxA, int gyA,
    int nA, const float* __restrict__ inB, const float* __restrict__ wB,
    float* __restrict__ oB, int CinB, int HB, int WB, int gxB, int gyB) {
  __shared__ __align__(16) float tin[CHUNK * 18 * 24];
  int bid = blockIdx.x;
  if (bid < nA) {
    int bx = bid % gxA; int r = bid / gxA; int by = r % gyA; int bz = r / gyA;
    conv16s1_body<CHUNK, RELU, TT>(inA, wA, oA, CinA, HA, WA, HA, WA, bx, by,
                                   bz, tin);
  } else {
    bid -= nA;
    int bx = bid % gxB; int r = bid / gxB; int by = r % gyB; int bz = r / gyB;
    conv16s1_body<CHUNK, RELU, TT>(inB, wB, oB, CinB, HB, WB, HB, WB, bx, by,
                                   bz, tin);
  }
}

// ---------------------------------------------------------------------------
// conv16_s2 (exact R16): phase-split E/O pitch 20, repacked weights.
// ---------------------------------------------------------------------------
template <int CHUNK, bool RELU>
__global__ __launch_bounds__(256) void conv16_s2(const float* __restrict__ in,
                                                 const float* __restrict__ wpk,
                                                 float* __restrict__ out,
                                                 int Cin, int Hin, int Win,
                                                 int Hout, int Wout) {
  constexpr int P = 20;
  constexpr int HALF = CHUNK * 33 * P;
  constexpr int TOT = CHUNK * 33 * 33;
  constexpr int NS = (TOT + 255) / 256;
  __shared__ __align__(16) float tin2[2 * HALF];  // [E | O]
  const int tid = threadIdx.x;
  const int tx = tid & 15, ty = tid >> 4;
  const int x0 = blockIdx.x * 16, y0 = blockIdx.y * 16;
  const int ix0 = x0 * 2, iy0 = y0 * 2;
  const size_t HWin = (size_t)Hin * Win;

  int goff[NS], loff[NS];
#pragma unroll
  for (int j = 0; j < NS; ++j) {
    int i = tid + j * 256;
    int c = i / 1089, r = i % 1089;
    int yy = r / 33, xx = r % 33;
    int gy = iy0 + yy, gx = ix0 + xx;
    bool ok = (i < TOT) && ((unsigned)gy < (unsigned)Hin) &&
              ((unsigned)gx < (unsigned)Win);
    goff[j] = ok ? (int)(c * HWin + (size_t)gy * Win + gx) : -1;
    loff[j] = c * 33 * P + yy * P + (xx >> 1) + ((xx & 1) ? HALF : 0);
  }

  float acc[16];
#pragma unroll
  for (int co = 0; co < 16; ++co) acc[co] = 0.f;

  for (int cb = 0; cb < Cin; cb += CHUNK) {
    const size_t gbase = (size_t)cb * HWin;
#pragma unroll
    for (int j = 0; j < NS; ++j) {
      int i = tid + j * 256;
      if (i < TOT) {
        float v = 0.f;
        if (goff[j] >= 0) v = in[gbase + goff[j]];
        tin2[loff[j]] = v;
      }
    }
    __syncthreads();
    for (int ci = 0; ci < CHUNK; ++ci) {
      const float4* wq = (const float4*)(wpk +
          ((size_t)blockIdx.z * Cin + (size_t)(cb + ci)) * 144);
#pragma unroll
      for (int ky = 0; ky < 3; ++ky) {
#pragma unroll
        for (int kx = 0; kx < 3; ++kx) {
          const int kk = ky * 3 + kx;
          const float* base = (kx == 1) ? (tin2 + HALF) : tin2;
          const int cadd = (kx == 2) ? 1 : 0;
          float v = base[ci * 33 * P + (2 * ty + ky) * P + tx + cadd];
          float4 w0 = wq[kk * 4 + 0];
          float4 w1 = wq[kk * 4 + 1];
          float4 w2 = wq[kk * 4 + 2];
          float4 w3 = wq[kk * 4 + 3];
          acc[0]  = fmaf(v, w0.x, acc[0]);
          acc[1]  = fmaf(v, w0.y, acc[1]);
          acc[2]  = fmaf(v, w0.z, acc[2]);
          acc[3]  = fmaf(v, w0.w, acc[3]);
          acc[4]  = fmaf(v, w1.x, acc[4]);
          acc[5]  = fmaf(v, w1.y, acc[5]);
          acc[6]  = fmaf(v, w1.z, acc[6]);
          acc[7]  = fmaf(v, w1.w, acc[7]);
          acc[8]  = fmaf(v, w2.x, acc[8]);
          acc[9]  = fmaf(v, w2.y, acc[9]);
          acc[10] = fmaf(v, w2.z, acc[10]);
          acc[11] = fmaf(v, w2.w, acc[11]);
          acc[12] = fmaf(v, w3.x, acc[12]);
          acc[13] = fmaf(v, w3.y, acc[13]);
          acc[14] = fmaf(v, w3.z, acc[14]);
          acc[15] = fmaf(v, w3.w, acc[15]);
        }
      }
    }
    __syncthreads();
  }
  const int co0 = blockIdx.z * 16;
  int oy = y0 + ty, ox = x0 + tx;
  if (oy < Hout && ox < Wout) {
#pragma unroll
    for (int co = 0; co < 16; ++co) {
      float v = acc[co];
      if (RELU) v = fmaxf(v, 0.f);
      out[(size_t)(co0 + co) * Hout * Wout + (size_t)oy * Wout + ox] = v;
    }
  }
}

// ---------------------------------------------------------------------------
// Merged RPN decode for all 4 levels (block-uniform level) + fused hi-hist.
// Blocks: [0,157) lvl0, [157,197) lvl1, [197,207) lvl2, [207,210) lvl3.
// Per-level math identical to R16 rpn_head_decode.
// ---------------------------------------------------------------------------
__global__ __launch_bounds__(256) void rpn_decode_all(
    const float* __restrict__ tt0, const float* __restrict__ tt1,
    const float* __restrict__ tt2, const float* __restrict__ tt3,
    const float* __restrict__ wcls, const float* __restrict__ wbox,
    float* __restrict__ boxes4, float* __restrict__ scores4,
    int* __restrict__ hist4) {
  __shared__ __align__(16) float wcs[256][16];
  for (int i = threadIdx.x; i < 256 * 16; i += 256) {
    int c = i & 255, o = i >> 8;
    float v = 0.f;
    if (o < 3) v = wcls[o * 256 + c];
    else if (o < 15) v = wbox[(o - 3) * 256 + c];
    wcs[c][o] = v;
  }
  __syncthreads();
  int b = blockIdx.x;
  int lvl; int base, npix, fw, boff, soff; float stride; const float* tt;
  if (b < 157) {
    lvl = 0; base = 0; npix = 40000; fw = 200; boff = 0; soff = 0;
    stride = 4.f; tt = tt0;
  } else if (b < 197) {
    lvl = 1; base = 157; npix = 10000; fw = 100; boff = 480000;
    soff = 120000; stride = 8.f; tt = tt1;
  } else if (b < 207) {
    lvl = 2; base = 197; npix = 2500; fw = 50; boff = 600000;
    soff = 150000; stride = 16.f; tt = tt2;
  } else {
    lvl = 3; base = 207; npix = 625; fw = 25; boff = 630000;
    soff = 157500; stride = 32.f; tt = tt3;
  }
  int p = (b - base) * 256 + threadIdx.x;
  if (p >= npix) return;
  double sz = (double)(32 << lvl);
  float ws0 = (float)(sz / sqrt(0.5)), ws1 = (float)sz,
        ws2 = (float)(sz / sqrt(2.0));
  float hs0 = (float)(sz * sqrt(0.5)), hs1 = (float)sz,
        hs2 = (float)(sz * sqrt(2.0));
  float a[15];
#pragma unroll
  for (int o = 0; o < 15; ++o) a[o] = 0.f;
  const float4* tp = (const float4*)(tt + (size_t)p * 256);
#pragma unroll 4
  for (int c4 = 0; c4 < 64; ++c4) {
    float4 tv = tp[c4];
#pragma unroll
    for (int j = 0; j < 4; ++j) {
      float v = (j == 0) ? tv.x : (j == 1) ? tv.y : (j == 2) ? tv.z : tv.w;
      int c = c4 * 4 + j;
      const float4* wr = (const float4*)&wcs[c][0];
      float4 w0 = wr[0], w1 = wr[1], w2 = wr[2], w3 = wr[3];
      a[0] = fmaf(v, w0.x, a[0]);   a[1] = fmaf(v, w0.y, a[1]);
      a[2] = fmaf(v, w0.z, a[2]);   a[3] = fmaf(v, w0.w, a[3]);
      a[4] = fmaf(v, w1.x, a[4]);   a[5] = fmaf(v, w1.y, a[5]);
      a[6] = fmaf(v, w1.z, a[6]);   a[7] = fmaf(v, w1.w, a[7]);
      a[8] = fmaf(v, w2.x, a[8]);   a[9] = fmaf(v, w2.y, a[9]);
      a[10] = fmaf(v, w2.z, a[10]); a[11] = fmaf(v, w2.w, a[11]);
      a[12] = fmaf(v, w3.x, a[12]); a[13] = fmaf(v, w3.y, a[13]);
      a[14] = fmaf(v, w3.z, a[14]);
    }
  }
  const int i = p / fw, j = p % fw;
  const float acy0 = __fmul_rn((float)i + 0.5f, stride);
  const float acx0 = __fmul_rn((float)j + 0.5f, stride);
  const float WS[3] = {ws0, ws1, ws2}, HS[3] = {hs0, hs1, hs2};
#pragma unroll
  for (int an = 0; an < 3; ++an) {
    float hw = __fmul_rn(WS[an], 0.5f), hh = __fmul_rn(HS[an], 0.5f);
    float x1a = __fsub_rn(acx0, hw), x2a = __fadd_rn(acx0, hw);
    float y1a = __fsub_rn(acy0, hh), y2a = __fadd_rn(acy0, hh);
    float aw = __fsub_rn(x2a, x1a), ah = __fsub_rn(y2a, y1a);
    float acx = __fadd_rn(x1a, __fmul_rn(aw, 0.5f));
    float acy = __fadd_rn(y1a, __fmul_rn(ah, 0.5f));
    float dx = a[3 + an * 4 + 0], dy = a[3 + an * 4 + 1];
    float dw = fminf(fmaxf(a[3 + an * 4 + 2], -4.f), 4.f);
    float dh = fminf(fmaxf(a[3 + an * 4 + 3], -4.f), 4.f);
    float cx = __fadd_rn(acx, __fmul_rn(dx, aw));
    float cy = __fadd_rn(acy, __fmul_rn(dy, ah));
    float w_ = __fmul_rn(aw, expf(dw));
    float h_ = __fmul_rn(ah, expf(dh));
    int idx = p * 3 + an;
    float* bo = boxes4 + boff;
    bo[idx * 4 + 0] =
        fminf(fmaxf(__fsub_rn(cx, __fmul_rn(w_, 0.5f)), 0.f), 800.f);
    bo[idx * 4 + 1] =
        fminf(fmaxf(__fsub_rn(cy, __fmul_rn(h_, 0.5f)), 0.f), 800.f);
    bo[idx * 4 + 2] =
        fminf(fmaxf(__fadd_rn(cx, __fmul_rn(w_, 0.5f)), 0.f), 800.f);
    bo[idx * 4 + 3] =
        fminf(fmaxf(__fadd_rn(cy, __fmul_rn(h_, 0.5f)), 0.f), 800.f);
    scores4[soff + idx] = a[an];
    atomicAdd(&hist4[lvl * 65536 + (fkey(a[an]) >> 16)], 1);
  }
}

// ---------------------------------------------------------------------------
// Merged selection (per-level math identical to R16 chain).
// ---------------------------------------------------------------------------
__global__ __launch_bounds__(256) void scan_hi_all(int* __restrict__ hist4,
                                                   int* __restrict__ sel4) {
  __shared__ int csum[256];
  int* hist = hist4 + blockIdx.x * 65536;
  int* sel = sel4 + blockIdx.x * 8;
  const int k = 1000;
  int t = threadIdx.x;
  int s = 0;
  for (int i = 0; i < 256; ++i) s += hist[t * 256 + i];
  csum[t] = s;
  __syncthreads();
  if (t == 0) {
    int cum = 0;
    bool done = false;
    for (int c = 255; c >= 0; --c) {
      if (cum + csum[c] >= k) {
        int cc = cum;
        for (int b = c * 256 + 255;; --b) {
          int h = hist[b];
          if (cc + h >= k) {
            sel[0] = b; sel[1] = k - cc; sel[2] = cc;
            done = true;
            break;
          }
          cc += h;
        }
        break;
      }
      cum += csum[c];
    }
    if (!done) { sel[0] = 0; sel[1] = k - cum; sel[2] = cum; }
  }
  __syncthreads();
  int4 z4; z4.x = 0; z4.y = 0; z4.z = 0; z4.w = 0;
  for (int i = t; i < 16384; i += 256) ((int4*)hist)[i] = z4;
}

DI void lvl_seg(int b, int& lvl, int& base, int& N, int& soff, int& boff) {
  if (b < 469) { lvl = 0; base = 0; N = 120000; soff = 0; boff = 0; }
  else if (b < 587) { lvl = 1; base = 469; N = 30000; soff = 120000;
                      boff = 480000; }
  else if (b < 617) { lvl = 2; base = 587; N = 7500; soff = 150000;
                      boff = 600000; }
  else { lvl = 3; base = 617; N = 1875; soff = 157500; boff = 630000; }
}

__global__ void hist_lo_all(const float* __restrict__ scores4,
                            const int* __restrict__ sel4,
                            int* __restrict__ hist4) {
  int lvl, base, N, soff, boff;
  lvl_seg(blockIdx.x, lvl, base, N, soff, boff);
  int i = (blockIdx.x - base) * 256 + threadIdx.x;
  if (i >= N) return;
  unsigned bsel = (unsigned)sel4[lvl * 8 + 0];
  unsigned key = fkey(scores4[soff + i]);
  if ((key >> 16) == bsel)
    atomicAdd(&hist4[lvl * 65536 + (key & 0xffffu)], 1);
}

__global__ __launch_bounds__(256) void scan_lo_all(
    const int* __restrict__ hist4, int* __restrict__ sel4) {
  __shared__ int csum[256];
  const int* hist = hist4 + blockIdx.x * 65536;
  int* sel = sel4 + blockIdx.x * 8;
  int t = threadIdx.x;
  int s = 0;
  for (int i = 0; i < 256; ++i) s += hist[t * 256 + i];
  csum[t] = s;
  __syncthreads();
  if (t == 0) {
    int r = sel[1], b = sel[0], cc_hi = sel[2];
    int cum = 0;
    bool done = false;
    for (int c = 255; c >= 0; --c) {
      if (cum + csum[c] >= r) {
        int cc = cum;
        for (int l = c * 256 + 255;; --l) {
          int h = hist[l];
          if (cc + h >= r) {
            sel[3] = (int)(((unsigned)b << 16) | (unsigned)l);
            sel[4] = cc_hi + cc;
            sel[5] = r - cc;
            sel[6] = 0;
            sel[7] = 0;
            done = true;
            break;
          }
          cc += h;
        }
        break;
      }
      cum += csum[c];
    }
    if (!done) {
      sel[3] = (int)((unsigned)b << 16);
      sel[4] = cc_hi; sel[5] = r; sel[6] = 0; sel[7] = 0;
    }
  }
}

__global__ void compact_all(const float* __restrict__ scores4,
                            const float* __restrict__ boxes4,
                            int* __restrict__ sel4,
                            float* __restrict__ out_s,
                            float* __restrict__ out_b) {
  int lvl, base, N, soff, boff;
  lvl_seg(blockIdx.x, lvl, base, N, soff, boff);
  int i = (blockIdx.x - base) * 256 + threadIdx.x;
  if (i >= N) return;
  int* sel = sel4 + lvl * 8;
  unsigned key = fkey(scores4[soff + i]);
  unsigned kth = (unsigned)sel[3];
  int pos = -1;
  if (key > kth) {
    pos = atomicAdd(&sel[6], 1);
  } else if (key == kth) {
    int e = atomicAdd(&sel[7], 1);
    if (e < sel[5]) pos = sel[4] + e;
  }
  if (pos >= 0) {
    int o = lvl * 1000 + pos;
    out_s[o] = scores4[soff + i];
    const float* bo = boxes4 + boff;
    out_b[o * 4 + 0] = bo[i * 4 + 0];
    out_b[o * 4 + 1] = bo[i * 4 + 1];
    out_b[o * 4 + 2] = bo[i * 4 + 2];
    out_b[o * 4 + 3] = bo[i * 4 + 3];
  }
}

// ---------------------------------------------------------------------------
// NMS: rank + suppression bitmask + greedy scan. (unchanged)
// ---------------------------------------------------------------------------
#define NMS_N 4000
#define NMS_W 63

__global__ __launch_bounds__(256) void rank_kernel(const float* __restrict__ s,
                                                   int* __restrict__ order) {
  __shared__ float ls[NMS_N];
  for (int i = threadIdx.x; i < NMS_N; i += 256) ls[i] = s[i];
  __syncthreads();
  int i = blockIdx.x * 256 + threadIdx.x;
  if (i >= NMS_N) return;
  float si = ls[i];
  int cnt = 0;
  for (int j = 0; j < NMS_N; ++j) {
    float sj = ls[j];
    cnt += (sj > si) || (sj == si && j < i);
  }
  order[cnt] = i;
}

__global__ __launch_bounds__(256) void supp_kernel(
    const float* __restrict__ boxes, unsigned long long* __restrict__ supp) {
  __shared__ float sx1[NMS_W * 64], sy1[NMS_W * 64];
  __shared__ float sx2[NMS_W * 64], sy2[NMS_W * 64];
  for (int i = threadIdx.x; i < NMS_W * 64; i += 256) {
    float x1 = 0.f, y1 = 0.f, x2 = 0.f, y2 = 0.f;
    if (i < NMS_N) {
      x1 = boxes[i * 4 + 0]; y1 = boxes[i * 4 + 1];
      x2 = boxes[i * 4 + 2]; y2 = boxes[i * 4 + 3];
    }
    sx1[i] = x1; sy1[i] = y1; sx2[i] = x2; sy2[i] = y2;
  }
  __syncthreads();
  const int wave = threadIdx.x >> 6, lane = threadIdx.x & 63;
  for (int rr = 0; rr < 16; ++rr) {
    int i = blockIdx.x * 16 + rr;
    if (i >= NMS_N) return;
    float ix1 = sx1[i], iy1 = sy1[i], ix2 = sx2[i], iy2 = sy2[i];
    float ia = __fmul_rn(__fsub_rn(ix2, ix1), __fsub_rn(iy2, iy1));
    for (int w = wave; w < NMS_W; w += 4) {
      int j = w * 64 + lane;
      float jx1 = sx1[j], jy1 = sy1[j], jx2 = sx2[j], jy2 = sy2[j];
      float ja = __fmul_rn(__fsub_rn(jx2, jx1), __fsub_rn(jy2, jy1));
      float cx1 = fmaxf(jx1, ix1), cy1 = fmaxf(jy1, iy1);
      float cx2 = fminf(jx2, ix2), cy2 = fminf(jy2, iy2);
      float iw = fmaxf(__fsub_rn(cx2, cx1), 0.f);
      float ih = fmaxf(__fsub_rn(cy2, cy1), 0.f);
      float inter = __fmul_rn(iw, ih);
      float denom = __fadd_rn(__fsub_rn(__fadd_rn(ja, ia), inter), 1e-6f);
      bool pred = __fdiv_rn(inter, denom) > 0.7f;
      unsigned long long bits = __ballot(pred);
      if (lane == 0) supp[(size_t)i * NMS_W + w] = bits;
    }
  }
}

__global__ __launch_bounds__(64) void nms_scan(
    const unsigned long long* __restrict__ supp, const int* __restrict__ order,
    const float* __restrict__ boxes, const float* __restrict__ scores,
    float* __restrict__ props, float* __restrict__ out_props,
    float* __restrict__ out_scores) {
  __shared__ unsigned long long removed[NMS_W];
  __shared__ int keepL[512];
  const int tid = threadIdx.x;
  if (tid < NMS_W) removed[tid] = 0ull;
  __syncthreads();
  int kept = 0, sticky = -1;
  for (int g = 0; g < NMS_W && sticky < 0 && kept < 512; ++g) {
    int pos = g * 64 + tid;
    int c = (pos < NMS_N) ? order[pos] : -1;
    while (kept < 512) {
      bool avail = (c >= 0) && !((removed[c >> 6] >> (c & 63)) & 1ull);
      unsigned long long bal = __ballot(avail);
      if (bal == 0ull) break;
      int fl = __ffsll((unsigned long long)bal) - 1;
      int ck = __shfl(c, fl);
      if (tid == 0) keepL[kept] = ck;
      kept++;
      unsigned long long w =
          (tid < NMS_W) ? supp[(size_t)ck * NMS_W + tid] : 0ull;
      unsigned long long selfw = __shfl(w, ck >> 6);
      if (tid < NMS_W) removed[tid] |= w;
      __syncthreads();
      if (!((selfw >> (ck & 63)) & 1ull)) { sticky = ck; break; }
    }
  }
  __syncthreads();
  const int fill = (sticky >= 0) ? sticky : 0;
  for (int k = tid; k < 512; k += 64) {
    int idx = (k < kept) ? keepL[k] : fill;
    float x1 = boxes[idx * 4 + 0], y1 = boxes[idx * 4 + 1];
    float x2 = boxes[idx * 4 + 2], y2 = boxes[idx * 4 + 3];
    props[k * 4 + 0] = x1; props[k * 4 + 1] = y1;
    props[k * 4 + 2] = x2; props[k * 4 + 3] = y2;
    out_props[k * 4 + 0] = x1; out_props[k * 4 + 1] = y1;
    out_props[k * 4 + 2] = x2; out_props[k * 4 + 3] = y2;
    out_scores[k] = scores[idx];
  }
}

// ---------------------------------------------------------------------------
// ROI align on fp32 f2 (256x200x200), scale 0.25. (unchanged)
// ---------------------------------------------------------------------------
__global__ __launch_bounds__(256) void roi_align_kernel(
    const float* __restrict__ feat, const float* __restrict__ rois,
    float* __restrict__ out) {
  __shared__ int sx0[7], sx1i[7], sy0[7], sy1i[7];
  __shared__ float swx[7], swy[7];
  const int n = blockIdx.x;
  if (threadIdx.x < 14) {
    int i = threadIdx.x % 7;
    bool isY = threadIdx.x >= 7;
    float r0 = rois[n * 4 + (isY ? 1 : 0)];
    float r1 = rois[n * 4 + (isY ? 3 : 2)];
    float a = __fmul_rn(r0, 0.25f);
    float b = __fdiv_rn(__fmul_rn(__fsub_rn(r1, r0), 0.25f), 7.0f);
    float g = __fsub_rn(__fadd_rn(a, __fmul_rn((float)i + 0.5f, b)), 0.5f);
    float fl = fminf(fmaxf(floorf(g), 0.f), 199.f);
    int i0 = (int)fl;
    int i1 = min(i0 + 1, 199);
    float wf = fminf(fmaxf(__fsub_rn(g, fl), 0.f), 1.f);
    if (isY) { sy0[i] = i0; sy1i[i] = i1; swy[i] = wf; }
    else     { sx0[i] = i0; sx1i[i] = i1; swx[i] = wf; }
  }
  __syncthreads();
  const int c = threadIdx.x;
  const float* fc_ = feat + (size_t)c * 40000;
  float* o = out + (size_t)n * 12544 + c * 49;
  for (int s = 0; s < 49; ++s) {
    int py = s / 7, px = s % 7;
    int y0 = sy0[py], y1 = sy1i[py], x0 = sx0[px], x1 = sx1i[px];
    float wy = swy[py], wx = swx[px];
    float v00 = fc_[y0 * 200 + x0], v01 = fc_[y0 * 200 + x1];
    float v10 = fc_[y1 * 200 + x0], v11 = fc_[y1 * 200 + x1];
    float v = ((v00 * (1.f - wy)) * (1.f - wx)) + ((v01 * (1.f - wy)) * wx) +
              ((v10 * wy) * (1.f - wx)) + ((v11 * wy) * wx);
    o[s] = v;
  }
}

// ---------------------------------------------------------------------------
// FC via bf16 MFMA. (unchanged)
// ---------------------------------------------------------------------------
__global__ void cast_a(const float* __restrict__ in,
                       unsigned short* __restrict__ out, int n) {
  int i = blockIdx.x * 256 + threadIdx.x;
  if (i < n) out[i] = f2bf(in[i]);
}

__global__ __launch_bounds__(256) void cast_bt(const float* __restrict__ B,
                                               unsigned short* __restrict__ Bt,
                                               int K, int N) {
  __shared__ float tile[32][33];
  const int k0 = blockIdx.y * 32, n0 = blockIdx.x * 32;
  const int tx = threadIdx.x & 31, ty = threadIdx.x >> 5;
  for (int r = ty; r < 32; r += 8)
    tile[r][tx] = B[(size_t)(k0 + r) * N + n0 + tx];
  __syncthreads();
  for (int r = ty; r < 32; r += 8)
    Bt[(size_t)(n0 + r) * K + k0 + tx] = f2bf(tile[tx][r]);
}

__global__ __launch_bounds__(256) void fc_mfma(
    const unsigned short* __restrict__ A,   // [M][K] bf16
    const unsigned short* __restrict__ Bt,  // [N][K] bf16
    float* __restrict__ Cp, int M, int N, int K, int kLen) {
  const int tid = threadIdx.x;
  const int lane = tid & 63, wave = tid >> 6;
  const int n = lane & 31, half = lane >> 5;
  const int bm = blockIdx.y * 128 + wave * 32;
  const int bn = blockIdx.x * 64;
  const int k0s = blockIdx.z * kLen;
  const unsigned short* arow = A + (size_t)(bm + n) * K + half * 8;
  const unsigned short* b0row = Bt + (size_t)(bn + n) * K + half * 8;
  const unsigned short* b1row = Bt + (size_t)(bn + 32 + n) * K + half * 8;
  float16v acc0, acc1;
#pragma unroll
  for (int r = 0; r < 16; ++r) { acc0[r] = 0.f; acc1[r] = 0.f; }
  for (int k0 = k0s; k0 < k0s + kLen; k0 += 16) {
    short8 a = *(const short8*)(arow + k0);
    short8 b0 = *(const short8*)(b0row + k0);
    short8 b1 = *(const short8*)(b1row + k0);
    acc0 = __builtin_amdgcn_mfma_f32_32x32x16_bf16(a, b0, acc0, 0, 0, 0);
    acc1 = __builtin_amdgcn_mfma_f32_32x32x16_bf16(a, b1, acc1, 0, 0, 0);
  }
  float* Cz = Cp + (size_t)blockIdx.z * M * N;
#pragma unroll
  for (int r = 0; r < 16; ++r) {
    int row = bm + (r & 3) + 8 * (r >> 2) + 4 * half;
    Cz[(size_t)row * N + bn + n] = acc0[r];
    Cz[(size_t)row * N + bn + 32 + n] = acc1[r];
  }
}

__global__ void fc_combine(const float* __restrict__ p,
                           const float* __restrict__ bias,
                           float* __restrict__ out, int MN, int N, int S) {
  int i = blockIdx.x * 256 + threadIdx.x;
  if (i >= MN) return;
  float v = 0.f;
  for (int s = 0; s < S; ++s) v += p[(size_t)s * MN + i];
  out[i] = fmaxf(v + bias[i % N], 0.f);
}

__global__ __launch_bounds__(64) void heads_kernel(
    const float* __restrict__ v, const float* __restrict__ wc,
    const float* __restrict__ bc, const float* __restrict__ wb,
    const float* __restrict__ bbias, float* __restrict__ out) {
  const int m = blockIdx.x;
  const int lane = threadIdx.x;
  float acc[10];
#pragma unroll
  for (int o = 0; o < 10; ++o) acc[o] = 0.f;
  for (int k = lane; k < 1024; k += 64) {
    float x = v[(size_t)m * 1024 + k];
    acc[0] = fmaf(x, wc[k * 2 + 0], acc[0]);
    acc[1] = fmaf(x, wc[k * 2 + 1], acc[1]);
#pragma unroll
    for (int o = 0; o < 8; ++o) acc[2 + o] = fmaf(x, wb[k * 8 + o], acc[2 + o]);
  }
#pragma unroll
  for (int off = 32; off > 0; off >>= 1)
#pragma unroll
    for (int o = 0; o < 10; ++o) acc[o] += __shfl_down(acc[o], off);
  if (lane == 0) {
    out[m * 2 + 0] = acc[0] + bc[0];
    out[m * 2 + 1] = acc[1] + bc[1];
#pragma unroll
    for (int o = 0; o < 8; ++o) out[1024 + m * 8 + o] = acc[2 + o] + bbias[o];
  }
}

// ---------------------------------------------------------------------------
// Host orchestration
// ---------------------------------------------------------------------------
extern "C" void kernel_launch(void* const* d_in, const int* in_sizes, int n_in,
                              void* d_out, int out_size, void* d_ws,
                              size_t ws_size, hipStream_t stream) {
  const float* x      = (const float*)d_in[0];
  const float* w_stem = (const float*)d_in[1];
  const float* w_c2   = (const float*)d_in[2];
  const float* w_c3   = (const float*)d_in[3];
  const float* w_c4   = (const float*)d_in[4];
  const float* w_c5   = (const float*)d_in[5];
  const float* w_f2   = (const float*)d_in[6];
  const float* w_f3   = (const float*)d_in[7];
  const float* w_f4   = (const float*)d_in[8];
  const float* w_f5   = (const float*)d_in[9];
  const float* w_rpn  = (const float*)d_in[10];
  const float* w_cls  = (const float*)d_in[11];
  const float* w_box  = (const float*)d_in[12];
  const float* w_fc1  = (const float*)d_in[13];
  const float* b_fc1  = (const float*)d_in[14];
  const float* w_fc2  = (const float*)d_in[15];
  const float* b_fc2  = (const float*)d_in[16];
  const float* w_clsh = (const float*)d_in[17];
  const float* b_clsh = (const float*)d_in[18];
  const float* w_breg = (const float*)d_in[19];
  const float* b_breg = (const float*)d_in[20];
  float* dout = (float*)d_out;

  float* ws = (float*)d_ws;
  float* stem = ws;                          // 10,240,000 floats
  float* c2   = stem + 10240000;             // 10,240,000
  float* c3   = c2 + 10240000;               // 2,560,000
  float* c4   = c3 + 2560000;                // 640,000
  float* c5   = c4 + 640000;                 // 160,000
  float* f2   = c5 + 160000;                 // 10,240,000
  float* f3   = f2 + 10240000;               // 2,560,000
  float* f4   = f3 + 2560000;                // 640,000
  float* f5   = f4 + 640000;                 // 160,000
  float* boxes_all  = f5 + 160000;           // 16,000
  float* scores_all = boxes_all + 16000;     // 4,000
  float* props      = scores_all + 4000;     // 2,048
  int*   histOld = (int*)(props + 2048);     // 65,536 ints (reused: sel4)
  int*   sel  = histOld + 65536;             // 16 ints (unused now)
  float* wpkA = (float*)(sel + 16);          // 589,824 (f2)
  float* wpkB = wpkA + 589824;               // 589,824 (f3)
  float* wpkC = wpkB + 589824;               // 589,824 (rpn)
  float* wpkD = wpkC + 589824;               // 147,456 (c2, Cin=64)
  float* wpkE = wpkD + 147456;               // 589,824 (c3)
  float* wpkF = wpkE + 589824;               // 589,824 (c4)
  float* wpkG = wpkF + 589824;               // 589,824 (c5)
  float* wpkH = wpkG + 589824;               // 589,824 (f4)
  float* wpkI = wpkH + 589824;               // 589,824 (f5)
  float* wpkS = wpkI + 589824;               // 9,408 (stem)
  // aliases (dead regions reused):
  float* tt0 = stem;                         // rpn px-major, lvl0 (10.24M)
  float* tt1 = c3;                           // lvl1 (2.56M; c3 dead)
  float* tt2 = wpkF;                         // lvl2 (640K; spans wpkF+G, dead)
  float* tt3 = wpkH;                         // lvl3 (160K; dead after laterals)
  int*   hist4 = (int*)wpkE;                 // 4x65536 ints (wpkE dead)
  int*   sel4  = histOld;                    // 4x8 ints
  float* boxes4  = c4;                       // 637,500 <= 640,000 (c4 dead)
  float* scores4 = c5;                       // 159,375 <= 160,000 (c5 dead)
  int*   order  = (int*)c3;                  // NMS (tt1 dead by then)
  unsigned long long* supp =
      (unsigned long long*)(c3 + 8192);      // 2.02 MB
  float* pooled = stem;                      // (tt0 dead)
  float* fc1o   = stem + 6422528;            // 524,288
  float* fc2o   = fc1o + 524288;             // 524,288
  float* fcp    = fc2o + 524288;             // 4 x 524,288
  unsigned short* Abf1 = (unsigned short*)c2;            // 512x12544
  unsigned short* Bt1  = (unsigned short*)(c2 + 3211264);// 1024x12544
  unsigned short* Abf2 = (unsigned short*)c3;            // 512x1024
  unsigned short* Bt2  = (unsigned short*)(c3 + 262144); // 1024x1024

  // ---- unified weight repack ----
  repack_all<<<19045, 256, 0, stream>>>(
      w_f2, w_f3, w_rpn, w_c2, w_c3, w_c4, w_c5, w_f4, w_f5, w_stem,
      wpkA, wpkB, wpkC, wpkD, wpkE, wpkF, wpkG, wpkH, wpkI, wpkS);

  // ---- backbone ----
  stem_conv<<<dim3(25, 25, 16), 256, 0, stream>>>(x, wpkS, stem);
  conv16_s2<4, true><<<dim3(13, 13, 16), 256, 0, stream>>>(
      stem, wpkD, c2, 64, 400, 400, 200, 200);
  conv16_s2<4, true><<<dim3(7, 7, 16), 256, 0, stream>>>(
      c2, wpkE, c3, 256, 200, 200, 100, 100);
  conv16_s2<4, true><<<dim3(4, 4, 16), 256, 0, stream>>>(
      c3, wpkF, c4, 256, 100, 100, 50, 50);
  conv16_s2<4, true><<<dim3(2, 2, 16), 256, 0, stream>>>(
      c4, wpkG, c5, 256, 50, 50, 25, 25);
  // ---- FPN laterals (no relu): merged launches ----
  conv32_lat<4, false, false><<<1904, 256, 0, stream>>>(
      c2, wpkA, f2, 256, 200, 200, 7, 13, 1456,
      c3, wpkB, f3, 256, 100, 100, 4, 7);
  conv16_lat<8, false, false><<<320, 256, 0, stream>>>(
      c4, wpkH, f4, 256, 50, 50, 4, 4, 256,
      c5, wpkI, f5, 256, 25, 25, 2, 2);

  // ---- RPN convs (relu, px-major tt write), merged ----
  conv32_lat<4, true, true><<<1904, 256, 0, stream>>>(
      f2, wpkC, tt0, 256, 200, 200, 7, 13, 1456,
      f3, wpkC, tt1, 256, 100, 100, 4, 7);
  conv16_lat<8, true, true><<<320, 256, 0, stream>>>(
      f4, wpkC, tt2, 256, 50, 50, 4, 4, 256,
      f5, wpkC, tt3, 256, 25, 25, 2, 2);

  // ---- merged decode + selection ----
  hipMemsetAsync(hist4, 0, 4 * 65536 * sizeof(int), stream);
  rpn_decode_all<<<210, 256, 0, stream>>>(tt0, tt1, tt2, tt3, w_cls, w_box,
                                          boxes4, scores4, hist4);
  scan_hi_all<<<4, 256, 0, stream>>>(hist4, sel4);
  hist_lo_all<<<625, 256, 0, stream>>>(scores4, sel4, hist4);
  scan_lo_all<<<4, 256, 0, stream>>>(hist4, sel4);
  compact_all<<<625, 256, 0, stream>>>(scores4, boxes4, sel4, scores_all,
                                       boxes_all);

  // ---- NMS ----
  rank_kernel<<<16, 256, 0, stream>>>(scores_all, order);
  supp_kernel<<<250, 256, 0, stream>>>(boxes_all, supp);
  nms_scan<<<1, 64, 0, stream>>>(supp, order, boxes_all, scores_all, props,
                                 dout + 5120, dout + 7168);

  // ---- ROI align + FC heads (bf16 MFMA; auto-pass cone) ----
  roi_align_kernel<<<512, 256, 0, stream>>>(f2, props, pooled);
  cast_a<<<(6422528 + 255) / 256, 256, 0, stream>>>(pooled, Abf1, 6422528);
  cast_bt<<<dim3(32, 392), 256, 0, stream>>>(w_fc1, Bt1, 12544, 1024);
  fc_mfma<<<dim3(16, 4, 4), 256, 0, stream>>>(Abf1, Bt1, fcp, 512, 1024, 12544,
                                              3136);
  fc_combine<<<2048, 256, 0, stream>>>(fcp, b_fc1, fc1o, 524288, 1024, 4);
  cast_a<<<(524288 + 255) / 256, 256, 0, stream>>>(fc1o, Abf2, 524288);
  cast_bt<<<dim3(32, 32), 256, 0, stream>>>(w_fc2, Bt2, 1024, 1024);
  fc_mfma<<<dim3(16, 4, 4), 256, 0, stream>>>(Abf2, Bt2, fcp, 512, 1024, 1024,
                                              256);
  fc_combine<<<2048, 256, 0, stream>>>(fcp, b_fc2, fc2o, 524288, 1024, 4);
  heads_kernel<<<512, 64, 0, stream>>>(fc2o, w_clsh, b_clsh, w_breg, b_breg,
                                       dout);
}

// Round 13
// 4321.978 us; speedup vs baseline: 1.4284x; 1.0194x over previous
//
#include <hip/hip_runtime.h>
#include <math.h>

// ---------------------------------------------------------------------------
// R22 (base = R21, 4406us proven): four bit-identical serial-section cuts.
// (a) stem CO=8 (grid z=8): halves input re-reads, doubles FMA/staged byte;
// wpkS repacked [z8][k147][co8]; per-output FMA chain (c,ky,kx asc)
// unchanged. (b) roi_align writes bf16 Abf1 directly (f2bf of same value) --
// removes cast_a#1 + 50MB pooled round-trip. (c) fc1 combine writes bf16
// Abf2 directly -- removes cast_a#2 + fc1o round-trip. (d) merged launches:
// cast_bt_all (fc1+fc2 weights, 1 launch), rank_supp (NMS rank+suppression,
// independent, 1 launch). Convs/decode/selection = exact R21.
// ---------------------------------------------------------------------------

#define DI __device__ __forceinline__

typedef short short8 __attribute__((ext_vector_type(8)));
typedef float float16v __attribute__((ext_vector_type(16)));

DI unsigned fkey(float f) {
  unsigned u = __float_as_uint(f);
  return (u & 0x80000000u) ? ~u : (u | 0x80000000u);
}

DI unsigned short f2bf(float f) {  // fp32 -> bf16 RN-even
  unsigned u = __float_as_uint(f);
  unsigned r = (u + 0x7FFFu + ((u >> 16) & 1u)) >> 16;
  return (unsigned short)r;
}

// ---------------------------------------------------------------------------
// Unified weight repack. Stem segment now [z8][k147][co8].
// ---------------------------------------------------------------------------
DI void rp256(const float* src, float* dst, int j) {
  int co = j & 15; int r = j >> 4; int kk = r % 9; int r2 = r / 9;
  int ci = r2 & 255; int z = r2 >> 8;
  dst[j] = src[((size_t)(z * 16 + co) * 256 + ci) * 9 + kk];
}

__global__ void repack_all(
    const float* __restrict__ wf2, const float* __restrict__ wf3,
    const float* __restrict__ wrpn, const float* __restrict__ wc2,
    const float* __restrict__ wc3, const float* __restrict__ wc4,
    const float* __restrict__ wc5, const float* __restrict__ wf4,
    const float* __restrict__ wf5, const float* __restrict__ wstem,
    float* __restrict__ wpkA, float* __restrict__ wpkB,
    float* __restrict__ wpkC, float* __restrict__ wpkD,
    float* __restrict__ wpkE, float* __restrict__ wpkF,
    float* __restrict__ wpkG, float* __restrict__ wpkH,
    float* __restrict__ wpkI, float* __restrict__ wpkS) {
  const int SZ = 589824, SZD = 147456;
  const int D0 = 3 * SZ;
  const int D1 = D0 + SZD;
  const int D2 = D1 + 5 * SZ;
  const int D3 = D2 + 9408;
  int i = blockIdx.x * 256 + threadIdx.x;
  if (i >= D3) return;
  if (i < D0) {
    const float* src = (i < SZ) ? wf2 : (i < 2 * SZ) ? wf3 : wrpn;
    float* dst = (i < SZ) ? wpkA : (i < 2 * SZ) ? wpkB : wpkC;
    rp256(src, dst, i % SZ);
  } else if (i < D1) {
    int j = i - D0;  // Cin = 64
    int co = j & 15; int r = j >> 4; int kk = r % 9; int r2 = r / 9;
    int ci = r2 & 63; int z = r2 >> 6;
    wpkD[j] = wc2[((size_t)(z * 16 + co) * 64 + ci) * 9 + kk];
  } else if (i < D2) {
    int j = i - D1;
    int seg = j / SZ; j -= seg * SZ;
    const float* src = (seg == 0) ? wc3 : (seg == 1) ? wc4
                       : (seg == 2) ? wc5 : (seg == 3) ? wf4 : wf5;
    float* dst = (seg == 0) ? wpkE : (seg == 1) ? wpkF
                 : (seg == 2) ? wpkG : (seg == 3) ? wpkH : wpkI;
    rp256(src, dst, j);
  } else {
    int j = i - D2;  // stem: [z8][k147][co8]
    int co = j & 7; int t = j >> 3;
    int k = t % 147; int z = t / 147;
    wpkS[j] = wstem[(size_t)(z * 8 + co) * 147 + k];
  }
}

// ---------------------------------------------------------------------------
// Stem: CO=8, grid (25,25,8). Weights via two uniform float4 per k from
// wpkS [z8][k147][co8]. Per-output FMA chain (c,ky,kx asc) = R9 stem.
// ---------------------------------------------------------------------------
__global__ __launch_bounds__(256) void stem_conv(const float* __restrict__ x,
                                                 const float* __restrict__ wpkS,
                                                 float* __restrict__ out) {
  __shared__ float tin[3 * 37 * 37];
  const int x0 = blockIdx.x * 16, y0 = blockIdx.y * 16, co0 = blockIdx.z * 8;
  const int tid = threadIdx.x;
  const int ix0 = x0 * 2 - 2, iy0 = y0 * 2 - 2;
  const float mean[3] = {0.485f, 0.456f, 0.406f};
  const float stdv[3] = {0.229f, 0.224f, 0.225f};
  for (int i = tid; i < 3 * 37 * 37; i += 256) {
    int c = i / 1369, r = i % 1369, yy = r / 37, xx = r % 37;
    int gy = iy0 + yy, gx = ix0 + xx;
    float v = 0.f;
    if ((unsigned)gy < 800u && (unsigned)gx < 800u)
      v = __fdiv_rn(__fsub_rn(x[c * 640000 + gy * 800 + gx], mean[c]), stdv[c]);
    tin[i] = v;
  }
  __syncthreads();
  const int tx = tid & 15, ty = tid >> 4;
  float acc[8];
#pragma unroll
  for (int co = 0; co < 8; ++co) acc[co] = 0.f;
  const float4* wq = (const float4*)(wpkS + (size_t)blockIdx.z * 1176);
  for (int c = 0; c < 3; ++c)
    for (int ky = 0; ky < 7; ++ky)
#pragma unroll
      for (int kx = 0; kx < 7; ++kx) {
        float v = tin[c * 1369 + (ty * 2 + ky) * 37 + (tx * 2 + kx)];
        int k = c * 49 + ky * 7 + kx;
        float4 w0 = wq[k * 2 + 0];
        float4 w1 = wq[k * 2 + 1];
        acc[0] = fmaf(v, w0.x, acc[0]);
        acc[1] = fmaf(v, w0.y, acc[1]);
        acc[2] = fmaf(v, w0.z, acc[2]);
        acc[3] = fmaf(v, w0.w, acc[3]);
        acc[4] = fmaf(v, w1.x, acc[4]);
        acc[5] = fmaf(v, w1.y, acc[5]);
        acc[6] = fmaf(v, w1.z, acc[6]);
        acc[7] = fmaf(v, w1.w, acc[7]);
      }
  int ox = x0 + tx, oy = y0 + ty;
#pragma unroll
  for (int co = 0; co < 8; ++co)
    out[(size_t)(co0 + co) * 160000 + oy * 400 + ox] = fmaxf(acc[co], 0.f);
}

// ---------------------------------------------------------------------------
// conv32 body (exact R21) + TT option.
// ---------------------------------------------------------------------------
template <int CHUNK, bool RELU, bool TT>
DI void conv32_body(const float* __restrict__ in,
                    const float* __restrict__ wpk, float* __restrict__ out,
                    int Cin, int Hin, int Win, int Hout, int Wout, int bx,
                    int by, int bz,
                    float (*tin2)[((CHUNK * 612 + 255) / 256) * 256]) {
  constexpr int TILE = CHUNK * 612;
  constexpr int NS = (TILE + 255) / 256;
  const int tid = threadIdx.x;
  const int tx = tid & 15, ty = tid >> 4;
  const int x0 = bx * 32, y0 = by * 16;
  const int ix0 = x0 - 1, iy0 = y0 - 1;
  const size_t HWin = (size_t)Hin * Win;

  int goff[NS];
#pragma unroll
  for (int j = 0; j < NS; ++j) {
    int e = j * 256 + tid;
    int c = e / 612, r = e % 612;
    int yy = r / 34, xx = r % 34;
    int gy = iy0 + yy, gx = ix0 + xx;
    bool ok = (e < TILE) && ((unsigned)gy < (unsigned)Hin) &&
              ((unsigned)gx < (unsigned)Win);
    goff[j] = ok ? (int)((size_t)c * HWin + (size_t)gy * Win + gx) : -1;
  }

  float acc0[16], acc1[16];
#pragma unroll
  for (int co = 0; co < 16; ++co) { acc0[co] = 0.f; acc1[co] = 0.f; }

  float stg[NS];
#pragma unroll
  for (int j = 0; j < NS; ++j)
    stg[j] = (goff[j] >= 0) ? in[goff[j]] : 0.f;
#pragma unroll
  for (int j = 0; j < NS; ++j) tin2[0][j * 256 + tid] = stg[j];
  __syncthreads();

  int buf = 0;
  for (int cb = 0; cb < Cin; cb += CHUNK) {
    const bool more = (cb + CHUNK) < Cin;
    if (more) {
      const float* gsrc = in + (size_t)(cb + CHUNK) * HWin;
#pragma unroll
      for (int j = 0; j < NS; ++j)
        stg[j] = (goff[j] >= 0) ? gsrc[goff[j]] : 0.f;
    }
    for (int ci = 0; ci < CHUNK; ++ci) {
      const float4* wq = (const float4*)(wpk +
          ((size_t)bz * Cin + (size_t)(cb + ci)) * 144);
#pragma unroll
      for (int ky = 0; ky < 3; ++ky) {
        const float* tb = &tin2[buf][ci * 612 + (ty + ky) * 34 + 2 * tx];
        float2 d0 = *(const float2*)tb;
        float2 d1 = *(const float2*)(tb + 2);
#pragma unroll
        for (int kx = 0; kx < 3; ++kx) {
          float v0 = (kx == 0) ? d0.x : (kx == 1) ? d0.y : d1.x;
          float v1 = (kx == 0) ? d0.y : (kx == 1) ? d1.x : d1.y;
          const int kk = ky * 3 + kx;
          float4 w0 = wq[kk * 4 + 0];
          float4 w1 = wq[kk * 4 + 1];
          float4 w2 = wq[kk * 4 + 2];
          float4 w3 = wq[kk * 4 + 3];
          acc0[0]  = fmaf(v0, w0.x, acc0[0]);
          acc0[1]  = fmaf(v0, w0.y, acc0[1]);
          acc0[2]  = fmaf(v0, w0.z, acc0[2]);
          acc0[3]  = fmaf(v0, w0.w, acc0[3]);
          acc1[0]  = fmaf(v1, w0.x, acc1[0]);
          acc1[1]  = fmaf(v1, w0.y, acc1[1]);
          acc1[2]  = fmaf(v1, w0.z, acc1[2]);
          acc1[3]  = fmaf(v1, w0.w, acc1[3]);
          acc0[4]  = fmaf(v0, w1.x, acc0[4]);
          acc0[5]  = fmaf(v0, w1.y, acc0[5]);
          acc0[6]  = fmaf(v0, w1.z, acc0[6]);
          acc0[7]  = fmaf(v0, w1.w, acc0[7]);
          acc1[4]  = fmaf(v1, w1.x, acc1[4]);
          acc1[5]  = fmaf(v1, w1.y, acc1[5]);
          acc1[6]  = fmaf(v1, w1.z, acc1[6]);
          acc1[7]  = fmaf(v1, w1.w, acc1[7]);
          acc0[8]  = fmaf(v0, w2.x, acc0[8]);
          acc0[9]  = fmaf(v0, w2.y, acc0[9]);
          acc0[10] = fmaf(v0, w2.z, acc0[10]);
          acc0[11] = fmaf(v0, w2.w, acc0[11]);
          acc1[8]  = fmaf(v1, w2.x, acc1[8]);
          acc1[9]  = fmaf(v1, w2.y, acc1[9]);
          acc1[10] = fmaf(v1, w2.z, acc1[10]);
          acc1[11] = fmaf(v1, w2.w, acc1[11]);
          acc0[12] = fmaf(v0, w3.x, acc0[12]);
          acc0[13] = fmaf(v0, w3.y, acc0[13]);
          acc0[14] = fmaf(v0, w3.z, acc0[14]);
          acc0[15] = fmaf(v0, w3.w, acc0[15]);
          acc1[12] = fmaf(v1, w3.x, acc1[12]);
          acc1[13] = fmaf(v1, w3.y, acc1[13]);
          acc1[14] = fmaf(v1, w3.z, acc1[14]);
          acc1[15] = fmaf(v1, w3.w, acc1[15]);
        }
      }
    }
    if (more) {
#pragma unroll
      for (int j = 0; j < NS; ++j) tin2[buf ^ 1][j * 256 + tid] = stg[j];
    }
    __syncthreads();
    buf ^= 1;
  }

  const int co0 = bz * 16;
  int oy = y0 + ty;
  if (oy < Hout) {
    int ox = x0 + 2 * tx;
    if (TT) {
      if (ox < Wout) {
        float* o = out + (size_t)(oy * Wout + ox) * 256 + co0;
#pragma unroll
        for (int co = 0; co < 16; ++co) {
          float a = acc0[co];
          if (RELU) a = fmaxf(a, 0.f);
          o[co] = a;
        }
      }
      if (ox + 1 < Wout) {
        float* o = out + (size_t)(oy * Wout + ox + 1) * 256 + co0;
#pragma unroll
        for (int co = 0; co < 16; ++co) {
          float a = acc1[co];
          if (RELU) a = fmaxf(a, 0.f);
          o[co] = a;
        }
      }
    } else {
      if (ox + 1 < Wout) {
#pragma unroll
        for (int co = 0; co < 16; ++co) {
          float a = acc0[co], b = acc1[co];
          if (RELU) { a = fmaxf(a, 0.f); b = fmaxf(b, 0.f); }
          float2 st; st.x = a; st.y = b;
          *(float2*)&out[(size_t)(co0 + co) * Hout * Wout +
                         (size_t)oy * Wout + ox] = st;
        }
      } else if (ox < Wout) {
#pragma unroll
        for (int co = 0; co < 16; ++co) {
          float a = acc0[co];
          if (RELU) a = fmaxf(a, 0.f);
          out[(size_t)(co0 + co) * Hout * Wout + (size_t)oy * Wout + ox] = a;
        }
      }
    }
  }
}

template <int CHUNK, bool RELU, bool TT>
__global__ __launch_bounds__(256) void conv32_lat(
    const float* __restrict__ inA, const float* __restrict__ wA,
    float* __restrict__ oA, int CinA, int HA, int WA, int gxA, int gyA,
    int nA, const float* __restrict__ inB, const float* __restrict__ wB,
    float* __restrict__ oB, int CinB, int HB, int WB, int gxB, int gyB) {
  constexpr int PADT = ((CHUNK * 612 + 255) / 256) * 256;
  __shared__ __align__(16) float tin2[2][PADT];
  int bid = blockIdx.x;
  if (bid < nA) {
    int bx = bid % gxA; int r = bid / gxA; int by = r % gyA; int bz = r / gyA;
    conv32_body<CHUNK, RELU, TT>(inA, wA, oA, CinA, HA, WA, HA, WA, bx, by,
                                 bz, tin2);
  } else {
    bid -= nA;
    int bx = bid % gxB; int r = bid / gxB; int by = r % gyB; int bz = r / gyB;
    conv32_body<CHUNK, RELU, TT>(inB, wB, oB, CinB, HB, WB, HB, WB, bx, by,
                                 bz, tin2);
  }
}

// ---------------------------------------------------------------------------
// conv16_s1 body (exact R21) + TT option.
// ---------------------------------------------------------------------------
template <int CHUNK, bool RELU, bool TT>
DI void conv16s1_body(const float* __restrict__ in,
                      const float* __restrict__ wpk, float* __restrict__ out,
                      int Cin, int Hin, int Win, int Hout, int Wout, int bx,
                      int by, int bz, float* tin) {
  constexpr int P = 24;
  constexpr int TOT = CHUNK * 18 * 18;
  constexpr int NS = (TOT + 255) / 256;
  const int tid = threadIdx.x;
  const int tx = tid & 15, ty = tid >> 4;
  const int x0 = bx * 16, y0 = by * 16;
  const int ix0 = x0 - 1, iy0 = y0 - 1;
  const size_t HWin = (size_t)Hin * Win;

  int goff[NS], loff[NS];
#pragma unroll
  for (int j = 0; j < NS; ++j) {
    int i = tid + j * 256;
    int c = i / 324, r = i % 324;
    int yy = r / 18, xx = r % 18;
    int gy = iy0 + yy, gx = ix0 + xx;
    bool ok = (i < TOT) && ((unsigned)gy < (unsigned)Hin) &&
              ((unsigned)gx < (unsigned)Win);
    goff[j] = ok ? (int)(c * HWin + (size_t)gy * Win + gx) : -1;
    loff[j] = c * 18 * P + yy * P + xx;
  }

  float acc[16];
#pragma unroll
  for (int co = 0; co < 16; ++co) acc[co] = 0.f;

  for (int cb = 0; cb < Cin; cb += CHUNK) {
    const size_t gbase = (size_t)cb * HWin;
#pragma unroll
    for (int j = 0; j < NS; ++j) {
      int i = tid + j * 256;
      if (i < TOT) {
        float v = 0.f;
        if (goff[j] >= 0) v = in[gbase + goff[j]];
        tin[loff[j]] = v;
      }
    }
    __syncthreads();
    for (int ci = 0; ci < CHUNK; ++ci) {
      const float4* wq = (const float4*)(wpk +
          ((size_t)bz * Cin + (size_t)(cb + ci)) * 144);
#pragma unroll
      for (int ky = 0; ky < 3; ++ky) {
#pragma unroll
        for (int kx = 0; kx < 3; ++kx) {
          const int kk = ky * 3 + kx;
          float v = tin[ci * 18 * P + (ty + ky) * P + tx + kx];
          float4 w0 = wq[kk * 4 + 0];
          float4 w1 = wq[kk * 4 + 1];
          float4 w2 = wq[kk * 4 + 2];
          float4 w3 = wq[kk * 4 + 3];
          acc[0]  = fmaf(v, w0.x, acc[0]);
          acc[1]  = fmaf(v, w0.y, acc[1]);
          acc[2]  = fmaf(v, w0.z, acc[2]);
          acc[3]  = fmaf(v, w0.w, acc[3]);
          acc[4]  = fmaf(v, w1.x, acc[4]);
          acc[5]  = fmaf(v, w1.y, acc[5]);
          acc[6]  = fmaf(v, w1.z, acc[6]);
          acc[7]  = fmaf(v, w1.w, acc[7]);
          acc[8]  = fmaf(v, w2.x, acc[8]);
          acc[9]  = fmaf(v, w2.y, acc[9]);
          acc[10] = fmaf(v, w2.z, acc[10]);
          acc[11] = fmaf(v, w2.w, acc[11]);
          acc[12] = fmaf(v, w3.x, acc[12]);
          acc[13] = fmaf(v, w3.y, acc[13]);
          acc[14] = fmaf(v, w3.z, acc[14]);
          acc[15] = fmaf(v, w3.w, acc[15]);
        }
      }
    }
    __syncthreads();
  }
  const int co0 = bz * 16;
  int oy = y0 + ty, ox = x0 + tx;
  if (oy < Hout && ox < Wout) {
    if (TT) {
      float* o = out + (size_t)(oy * Wout + ox) * 256 + co0;
#pragma unroll
      for (int co = 0; co < 16; ++co) {
        float v = acc[co];
        if (RELU) v = fmaxf(v, 0.f);
        o[co] = v;
      }
    } else {
#pragma unroll
      for (int co = 0; co < 16; ++co) {
        float v = acc[co];
        if (RELU) v = fmaxf(v, 0.f);
        out[(size_t)(co0 + co) * Hout * Wout + (size_t)oy * Wout + ox] = v;
      }
    }
  }
}

template <int CHUNK, bool RELU, bool TT>
__global__ __launch_bounds__(256) void conv16_lat(
    const float* __restrict__ inA, const float* __restrict__ wA,
    float* __restrict__ oA, int CinA, int HA, int WA, int gxA, int gyA,
    int nA, const float* __restrict__ inB, const float* __restrict__ wB,
    float* __restrict__ oB, int CinB, int HB, int WB, int gxB, int gyB) {
  __shared__ __align__(16) float tin[CHUNK * 18 * 24];
  int bid = blockIdx.x;
  if (bid < nA) {
    int bx = bid % gxA; int r = bid / gxA; int by = r % gyA; int bz = r / gyA;
    conv16s1_body<CHUNK, RELU, TT>(inA, wA, oA, CinA, HA, WA, HA, WA, bx, by,
                                   bz, tin);
  } else {
    bid -= nA;
    int bx = bid % gxB; int r = bid / gxB; int by = r % gyB; int bz = r / gyB;
    conv16s1_body<CHUNK, RELU, TT>(inB, wB, oB, CinB, HB, WB, HB, WB, bx, by,
                                   bz, tin);
  }
}

// ---------------------------------------------------------------------------
// conv16_s2 (exact R21): phase-split E/O pitch 20, repacked weights.
// ---------------------------------------------------------------------------
template <int CHUNK, bool RELU>
__global__ __launch_bounds__(256) void conv16_s2(const float* __restrict__ in,
                                                 const float* __restrict__ wpk,
                                                 float* __restrict__ out,
                                                 int Cin, int Hin, int Win,
                                                 int Hout, int Wout) {
  constexpr int P = 20;
  constexpr int HALF = CHUNK * 33 * P;
  constexpr int TOT = CHUNK * 33 * 33;
  constexpr int NS = (TOT + 255) / 256;
  __shared__ __align__(16) float tin2[2 * HALF];  // [E | O]
  const int tid = threadIdx.x;
  const int tx = tid & 15, ty = tid >> 4;
  const int x0 = blockIdx.x * 16, y0 = blockIdx.y * 16;
  const int ix0 = x0 * 2, iy0 = y0 * 2;
  const size_t HWin = (size_t)Hin * Win;

  int goff[NS], loff[NS];
#pragma unroll
  for (int j = 0; j < NS; ++j) {
    int i = tid + j * 256;
    int c = i / 1089, r = i % 1089;
    int yy = r / 33, xx = r % 33;
    int gy = iy0 + yy, gx = ix0 + xx;
    bool ok = (i < TOT) && ((unsigned)gy < (unsigned)Hin) &&
              ((unsigned)gx < (unsigned)Win);
    goff[j] = ok ? (int)(c * HWin + (size_t)gy * Win + gx) : -1;
    loff[j] = c * 33 * P + yy * P + (xx >> 1) + ((xx & 1) ? HALF : 0);
  }

  float acc[16];
#pragma unroll
  for (int co = 0; co < 16; ++co) acc[co] = 0.f;

  for (int cb = 0; cb < Cin; cb += CHUNK) {
    const size_t gbase = (size_t)cb * HWin;
#pragma unroll
    for (int j = 0; j < NS; ++j) {
      int i = tid + j * 256;
      if (i < TOT) {
        float v = 0.f;
        if (goff[j] >= 0) v = in[gbase + goff[j]];
        tin2[loff[j]] = v;
      }
    }
    __syncthreads();
    for (int ci = 0; ci < CHUNK; ++ci) {
      const float4* wq = (const float4*)(wpk +
          ((size_t)blockIdx.z * Cin + (size_t)(cb + ci)) * 144);
#pragma unroll
      for (int ky = 0; ky < 3; ++ky) {
#pragma unroll
        for (int kx = 0; kx < 3; ++kx) {
          const int kk = ky * 3 + kx;
          const float* base = (kx == 1) ? (tin2 + HALF) : tin2;
          const int cadd = (kx == 2) ? 1 : 0;
          float v = base[ci * 33 * P + (2 * ty + ky) * P + tx + cadd];
          float4 w0 = wq[kk * 4 + 0];
          float4 w1 = wq[kk * 4 + 1];
          float4 w2 = wq[kk * 4 + 2];
          float4 w3 = wq[kk * 4 + 3];
          acc[0]  = fmaf(v, w0.x, acc[0]);
          acc[1]  = fmaf(v, w0.y, acc[1]);
          acc[2]  = fmaf(v, w0.z, acc[2]);
          acc[3]  = fmaf(v, w0.w, acc[3]);
          acc[4]  = fmaf(v, w1.x, acc[4]);
          acc[5]  = fmaf(v, w1.y, acc[5]);
          acc[6]  = fmaf(v, w1.z, acc[6]);
          acc[7]  = fmaf(v, w1.w, acc[7]);
          acc[8]  = fmaf(v, w2.x, acc[8]);
          acc[9]  = fmaf(v, w2.y, acc[9]);
          acc[10] = fmaf(v, w2.z, acc[10]);
          acc[11] = fmaf(v, w2.w, acc[11]);
          acc[12] = fmaf(v, w3.x, acc[12]);
          acc[13] = fmaf(v, w3.y, acc[13]);
          acc[14] = fmaf(v, w3.z, acc[14]);
          acc[15] = fmaf(v, w3.w, acc[15]);
        }
      }
    }
    __syncthreads();
  }
  const int co0 = blockIdx.z * 16;
  int oy = y0 + ty, ox = x0 + tx;
  if (oy < Hout && ox < Wout) {
#pragma unroll
    for (int co = 0; co < 16; ++co) {
      float v = acc[co];
      if (RELU) v = fmaxf(v, 0.f);
      out[(size_t)(co0 + co) * Hout * Wout + (size_t)oy * Wout + ox] = v;
    }
  }
}

// ---------------------------------------------------------------------------
// Merged RPN decode (exact R21).
// ---------------------------------------------------------------------------
__global__ __launch_bounds__(256) void rpn_decode_all(
    const float* __restrict__ tt0, const float* __restrict__ tt1,
    const float* __restrict__ tt2, const float* __restrict__ tt3,
    const float* __restrict__ wcls, const float* __restrict__ wbox,
    float* __restrict__ boxes4, float* __restrict__ scores4,
    int* __restrict__ hist4) {
  __shared__ __align__(16) float wcs[256][16];
  for (int i = threadIdx.x; i < 256 * 16; i += 256) {
    int c = i & 255, o = i >> 8;
    float v = 0.f;
    if (o < 3) v = wcls[o * 256 + c];
    else if (o < 15) v = wbox[(o - 3) * 256 + c];
    wcs[c][o] = v;
  }
  __syncthreads();
  int b = blockIdx.x;
  int lvl; int base, npix, fw, boff, soff; float stride; const float* tt;
  if (b < 157) {
    lvl = 0; base = 0; npix = 40000; fw = 200; boff = 0; soff = 0;
    stride = 4.f; tt = tt0;
  } else if (b < 197) {
    lvl = 1; base = 157; npix = 10000; fw = 100; boff = 480000;
    soff = 120000; stride = 8.f; tt = tt1;
  } else if (b < 207) {
    lvl = 2; base = 197; npix = 2500; fw = 50; boff = 600000;
    soff = 150000; stride = 16.f; tt = tt2;
  } else {
    lvl = 3; base = 207; npix = 625; fw = 25; boff = 630000;
    soff = 157500; stride = 32.f; tt = tt3;
  }
  int p = (b - base) * 256 + threadIdx.x;
  if (p >= npix) return;
  double sz = (double)(32 << lvl);
  float ws0 = (float)(sz / sqrt(0.5)), ws1 = (float)sz,
        ws2 = (float)(sz / sqrt(2.0));
  float hs0 = (float)(sz * sqrt(0.5)), hs1 = (float)sz,
        hs2 = (float)(sz * sqrt(2.0));
  float a[15];
#pragma unroll
  for (int o = 0; o < 15; ++o) a[o] = 0.f;
  const float4* tp = (const float4*)(tt + (size_t)p * 256);
#pragma unroll 4
  for (int c4 = 0; c4 < 64; ++c4) {
    float4 tv = tp[c4];
#pragma unroll
    for (int j = 0; j < 4; ++j) {
      float v = (j == 0) ? tv.x : (j == 1) ? tv.y : (j == 2) ? tv.z : tv.w;
      int c = c4 * 4 + j;
      const float4* wr = (const float4*)&wcs[c][0];
      float4 w0 = wr[0], w1 = wr[1], w2 = wr[2], w3 = wr[3];
      a[0] = fmaf(v, w0.x, a[0]);   a[1] = fmaf(v, w0.y, a[1]);
      a[2] = fmaf(v, w0.z, a[2]);   a[3] = fmaf(v, w0.w, a[3]);
      a[4] = fmaf(v, w1.x, a[4]);   a[5] = fmaf(v, w1.y, a[5]);
      a[6] = fmaf(v, w1.z, a[6]);   a[7] = fmaf(v, w1.w, a[7]);
      a[8] = fmaf(v, w2.x, a[8]);   a[9] = fmaf(v, w2.y, a[9]);
      a[10] = fmaf(v, w2.z, a[10]); a[11] = fmaf(v, w2.w, a[11]);
      a[12] = fmaf(v, w3.x, a[12]); a[13] = fmaf(v, w3.y, a[13]);
      a[14] = fmaf(v, w3.z, a[14]);
    }
  }
  const int i = p / fw, j = p % fw;
  const float acy0 = __fmul_rn((float)i + 0.5f, stride);
  const float acx0 = __fmul_rn((float)j + 0.5f, stride);
  const float WS[3] = {ws0, ws1, ws2}, HS[3] = {hs0, hs1, hs2};
#pragma unroll
  for (int an = 0; an < 3; ++an) {
    float hw = __fmul_rn(WS[an], 0.5f), hh = __fmul_rn(HS[an], 0.5f);
    float x1a = __fsub_rn(acx0, hw), x2a = __fadd_rn(acx0, hw);
    float y1a = __fsub_rn(acy0, hh), y2a = __fadd_rn(acy0, hh);
    float aw = __fsub_rn(x2a, x1a), ah = __fsub_rn(y2a, y1a);
    float acx = __fadd_rn(x1a, __fmul_rn(aw, 0.5f));
    float acy = __fadd_rn(y1a, __fmul_rn(ah, 0.5f));
    float dx = a[3 + an * 4 + 0], dy = a[3 + an * 4 + 1];
    float dw = fminf(fmaxf(a[3 + an * 4 + 2], -4.f), 4.f);
    float dh = fminf(fmaxf(a[3 + an * 4 + 3], -4.f), 4.f);
    float cx = __fadd_rn(acx, __fmul_rn(dx, aw));
    float cy = __fadd_rn(acy, __fmul_rn(dy, ah));
    float w_ = __fmul_rn(aw, expf(dw));
    float h_ = __fmul_rn(ah, expf(dh));
    int idx = p * 3 + an;
    float* bo = boxes4 + boff;
    bo[idx * 4 + 0] =
        fminf(fmaxf(__fsub_rn(cx, __fmul_rn(w_, 0.5f)), 0.f), 800.f);
    bo[idx * 4 + 1] =
        fminf(fmaxf(__fsub_rn(cy, __fmul_rn(h_, 0.5f)), 0.f), 800.f);
    bo[idx * 4 + 2] =
        fminf(fmaxf(__fadd_rn(cx, __fmul_rn(w_, 0.5f)), 0.f), 800.f);
    bo[idx * 4 + 3] =
        fminf(fmaxf(__fadd_rn(cy, __fmul_rn(h_, 0.5f)), 0.f), 800.f);
    scores4[soff + idx] = a[an];
    atomicAdd(&hist4[lvl * 65536 + (fkey(a[an]) >> 16)], 1);
  }
}

// ---------------------------------------------------------------------------
// Merged selection (exact R21).
// ---------------------------------------------------------------------------
__global__ __launch_bounds__(256) void scan_hi_all(int* __restrict__ hist4,
                                                   int* __restrict__ sel4) {
  __shared__ int csum[256];
  int* hist = hist4 + blockIdx.x * 65536;
  int* sel = sel4 + blockIdx.x * 8;
  const int k = 1000;
  int t = threadIdx.x;
  int s = 0;
  for (int i = 0; i < 256; ++i) s += hist[t * 256 + i];
  csum[t] = s;
  __syncthreads();
  if (t == 0) {
    int cum = 0;
    bool done = false;
    for (int c = 255; c >= 0; --c) {
      if (cum + csum[c] >= k) {
        int cc = cum;
        for (int b = c * 256 + 255;; --b) {
          int h = hist[b];
          if (cc + h >= k) {
            sel[0] = b; sel[1] = k - cc; sel[2] = cc;
            done = true;
            break;
          }
          cc += h;
        }
        break;
      }
      cum += csum[c];
    }
    if (!done) { sel[0] = 0; sel[1] = k - cum; sel[2] = cum; }
  }
  __syncthreads();
  int4 z4; z4.x = 0; z4.y = 0; z4.z = 0; z4.w = 0;
  for (int i = t; i < 16384; i += 256) ((int4*)hist)[i] = z4;
}

DI void lvl_seg(int b, int& lvl, int& base, int& N, int& soff, int& boff) {
  if (b < 469) { lvl = 0; base = 0; N = 120000; soff = 0; boff = 0; }
  else if (b < 587) { lvl = 1; base = 469; N = 30000; soff = 120000;
                      boff = 480000; }
  else if (b < 617) { lvl = 2; base = 587; N = 7500; soff = 150000;
                      boff = 600000; }
  else { lvl = 3; base = 617; N = 1875; soff = 157500; boff = 630000; }
}

__global__ void hist_lo_all(const float* __restrict__ scores4,
                            const int* __restrict__ sel4,
                            int* __restrict__ hist4) {
  int lvl, base, N, soff, boff;
  lvl_seg(blockIdx.x, lvl, base, N, soff, boff);
  int i = (blockIdx.x - base) * 256 + threadIdx.x;
  if (i >= N) return;
  unsigned bsel = (unsigned)sel4[lvl * 8 + 0];
  unsigned key = fkey(scores4[soff + i]);
  if ((key >> 16) == bsel)
    atomicAdd(&hist4[lvl * 65536 + (key & 0xffffu)], 1);
}

__global__ __launch_bounds__(256) void scan_lo_all(
    const int* __restrict__ hist4, int* __restrict__ sel4) {
  __shared__ int csum[256];
  const int* hist = hist4 + blockIdx.x * 65536;
  int* sel = sel4 + blockIdx.x * 8;
  int t = threadIdx.x;
  int s = 0;
  for (int i = 0; i < 256; ++i) s += hist[t * 256 + i];
  csum[t] = s;
  __syncthreads();
  if (t == 0) {
    int r = sel[1], b = sel[0], cc_hi = sel[2];
    int cum = 0;
    bool done = false;
    for (int c = 255; c >= 0; --c) {
      if (cum + csum[c] >= r) {
        int cc = cum;
        for (int l = c * 256 + 255;; --l) {
          int h = hist[l];
          if (cc + h >= r) {
            sel[3] = (int)(((unsigned)b << 16) | (unsigned)l);
            sel[4] = cc_hi + cc;
            sel[5] = r - cc;
            sel[6] = 0;
            sel[7] = 0;
            done = true;
            break;
          }
          cc += h;
        }
        break;
      }
      cum += csum[c];
    }
    if (!done) {
      sel[3] = (int)((unsigned)b << 16);
      sel[4] = cc_hi; sel[5] = r; sel[6] = 0; sel[7] = 0;
    }
  }
}

__global__ void compact_all(const float* __restrict__ scores4,
                            const float* __restrict__ boxes4,
                            int* __restrict__ sel4,
                            float* __restrict__ out_s,
                            float* __restrict__ out_b) {
  int lvl, base, N, soff, boff;
  lvl_seg(blockIdx.x, lvl, base, N, soff, boff);
  int i = (blockIdx.x - base) * 256 + threadIdx.x;
  if (i >= N) return;
  int* sel = sel4 + lvl * 8;
  unsigned key = fkey(scores4[soff + i]);
  unsigned kth = (unsigned)sel[3];
  int pos = -1;
  if (key > kth) {
    pos = atomicAdd(&sel[6], 1);
  } else if (key == kth) {
    int e = atomicAdd(&sel[7], 1);
    if (e < sel[5]) pos = sel[4] + e;
  }
  if (pos >= 0) {
    int o = lvl * 1000 + pos;
    out_s[o] = scores4[soff + i];
    const float* bo = boxes4 + boff;
    out_b[o * 4 + 0] = bo[i * 4 + 0];
    out_b[o * 4 + 1] = bo[i * 4 + 1];
    out_b[o * 4 + 2] = bo[i * 4 + 2];
    out_b[o * 4 + 3] = bo[i * 4 + 3];
  }
}

// ---------------------------------------------------------------------------
// NMS: merged rank + suppression (independent; union LDS), then greedy scan.
// ---------------------------------------------------------------------------
#define NMS_N 4000
#define NMS_W 63

__global__ __launch_bounds__(256) void rank_supp(
    const float* __restrict__ s, int* __restrict__ order,
    const float* __restrict__ boxes, unsigned long long* __restrict__ supp) {
  __shared__ float sbuf[NMS_W * 64 * 4];
  if (blockIdx.x < 16) {
    // ---- rank body (exact R21 rank_kernel) ----
    float* ls = sbuf;
    for (int i = threadIdx.x; i < NMS_N; i += 256) ls[i] = s[i];
    __syncthreads();
    int i = blockIdx.x * 256 + threadIdx.x;
    if (i >= NMS_N) return;
    float si = ls[i];
    int cnt = 0;
    for (int j = 0; j < NMS_N; ++j) {
      float sj = ls[j];
      cnt += (sj > si) || (sj == si && j < i);
    }
    order[cnt] = i;
  } else {
    // ---- supp body (exact R21 supp_kernel, bid-16) ----
    const int bid = blockIdx.x - 16;
    float* sx1 = sbuf;
    float* sy1 = sbuf + NMS_W * 64;
    float* sx2 = sbuf + NMS_W * 64 * 2;
    float* sy2 = sbuf + NMS_W * 64 * 3;
    for (int i = threadIdx.x; i < NMS_W * 64; i += 256) {
      float x1 = 0.f, y1 = 0.f, x2 = 0.f, y2 = 0.f;
      if (i < NMS_N) {
        x1 = boxes[i * 4 + 0]; y1 = boxes[i * 4 + 1];
        x2 = boxes[i * 4 + 2]; y2 = boxes[i * 4 + 3];
      }
      sx1[i] = x1; sy1[i] = y1; sx2[i] = x2; sy2[i] = y2;
    }
    __syncthreads();
    const int wave = threadIdx.x >> 6, lane = threadIdx.x & 63;
    for (int rr = 0; rr < 16; ++rr) {
      int i = bid * 16 + rr;
      if (i >= NMS_N) return;
      float ix1 = sx1[i], iy1 = sy1[i], ix2 = sx2[i], iy2 = sy2[i];
      float ia = __fmul_rn(__fsub_rn(ix2, ix1), __fsub_rn(iy2, iy1));
      for (int w = wave; w < NMS_W; w += 4) {
        int j = w * 64 + lane;
        float jx1 = sx1[j], jy1 = sy1[j], jx2 = sx2[j], jy2 = sy2[j];
        float ja = __fmul_rn(__fsub_rn(jx2, jx1), __fsub_rn(jy2, jy1));
        float cx1 = fmaxf(jx1, ix1), cy1 = fmaxf(jy1, iy1);
        float cx2 = fminf(jx2, ix2), cy2 = fminf(jy2, iy2);
        float iw = fmaxf(__fsub_rn(cx2, cx1), 0.f);
        float ih = fmaxf(__fsub_rn(cy2, cy1), 0.f);
        float inter = __fmul_rn(iw, ih);
        float denom = __fadd_rn(__fsub_rn(__fadd_rn(ja, ia), inter), 1e-6f);
        bool pred = __fdiv_rn(inter, denom) > 0.7f;
        unsigned long long bits = __ballot(pred);
        if (lane == 0) supp[(size_t)i * NMS_W + w] = bits;
      }
    }
  }
}

__global__ __launch_bounds__(64) void nms_scan(
    const unsigned long long* __restrict__ supp, const int* __restrict__ order,
    const float* __restrict__ boxes, const float* __restrict__ scores,
    float* __restrict__ props, float* __restrict__ out_props,
    float* __restrict__ out_scores) {
  __shared__ unsigned long long removed[NMS_W];
  __shared__ int keepL[512];
  const int tid = threadIdx.x;
  if (tid < NMS_W) removed[tid] = 0ull;
  __syncthreads();
  int kept = 0, sticky = -1;
  for (int g = 0; g < NMS_W && sticky < 0 && kept < 512; ++g) {
    int pos = g * 64 + tid;
    int c = (pos < NMS_N) ? order[pos] : -1;
    while (kept < 512) {
      bool avail = (c >= 0) && !((removed[c >> 6] >> (c & 63)) & 1ull);
      unsigned long long bal = __ballot(avail);
      if (bal == 0ull) break;
      int fl = __ffsll((unsigned long long)bal) - 1;
      int ck = __shfl(c, fl);
      if (tid == 0) keepL[kept] = ck;
      kept++;
      unsigned long long w =
          (tid < NMS_W) ? supp[(size_t)ck * NMS_W + tid] : 0ull;
      unsigned long long selfw = __shfl(w, ck >> 6);
      if (tid < NMS_W) removed[tid] |= w;
      __syncthreads();
      if (!((selfw >> (ck & 63)) & 1ull)) { sticky = ck; break; }
    }
  }
  __syncthreads();
  const int fill = (sticky >= 0) ? sticky : 0;
  for (int k = tid; k < 512; k += 64) {
    int idx = (k < kept) ? keepL[k] : fill;
    float x1 = boxes[idx * 4 + 0], y1 = boxes[idx * 4 + 1];
    float x2 = boxes[idx * 4 + 2], y2 = boxes[idx * 4 + 3];
    props[k * 4 + 0] = x1; props[k * 4 + 1] = y1;
    props[k * 4 + 2] = x2; props[k * 4 + 3] = y2;
    out_props[k * 4 + 0] = x1; out_props[k * 4 + 1] = y1;
    out_props[k * 4 + 2] = x2; out_props[k * 4 + 3] = y2;
    out_scores[k] = scores[idx];
  }
}

// ---------------------------------------------------------------------------
// ROI align on fp32 f2, writes bf16 Abf1 directly (same values as cast-after).
// ---------------------------------------------------------------------------
__global__ __launch_bounds__(256) void roi_align_kernel(
    const float* __restrict__ feat, const float* __restrict__ rois,
    unsigned short* __restrict__ outBf) {
  __shared__ int sx0[7], sx1i[7], sy0[7], sy1i[7];
  __shared__ float swx[7], swy[7];
  const int n = blockIdx.x;
  if (threadIdx.x < 14) {
    int i = threadIdx.x % 7;
    bool isY = threadIdx.x >= 7;
    float r0 = rois[n * 4 + (isY ? 1 : 0)];
    float r1 = rois[n * 4 + (isY ? 3 : 2)];
    float a = __fmul_rn(r0, 0.25f);
    float b = __fdiv_rn(__fmul_rn(__fsub_rn(r1, r0), 0.25f), 7.0f);
    float g = __fsub_rn(__fadd_rn(a, __fmul_rn((float)i + 0.5f, b)), 0.5f);
    float fl = fminf(fmaxf(floorf(g), 0.f), 199.f);
    int i0 = (int)fl;
    int i1 = min(i0 + 1, 199);
    float wf = fminf(fmaxf(__fsub_rn(g, fl), 0.f), 1.f);
    if (isY) { sy0[i] = i0; sy1i[i] = i1; swy[i] = wf; }
    else     { sx0[i] = i0; sx1i[i] = i1; swx[i] = wf; }
  }
  __syncthreads();
  const int c = threadIdx.x;
  const float* fc_ = feat + (size_t)c * 40000;
  unsigned short* o = outBf + (size_t)n * 12544 + c * 49;
  for (int s = 0; s < 49; ++s) {
    int py = s / 7, px = s % 7;
    int y0 = sy0[py], y1 = sy1i[py], x0 = sx0[px], x1 = sx1i[px];
    float wy = swy[py], wx = swx[px];
    float v00 = fc_[y0 * 200 + x0], v01 = fc_[y0 * 200 + x1];
    float v10 = fc_[y1 * 200 + x0], v11 = fc_[y1 * 200 + x1];
    float v = ((v00 * (1.f - wy)) * (1.f - wx)) + ((v01 * (1.f - wy)) * wx) +
              ((v10 * wy) * (1.f - wx)) + ((v11 * wy) * wx);
    o[s] = f2bf(v);
  }
}

// ---------------------------------------------------------------------------
// FC via bf16 MFMA. cast_bt merged (fc1+fc2 in one launch).
// ---------------------------------------------------------------------------
__global__ __launch_bounds__(256) void cast_bt_all(
    const float* __restrict__ B1, unsigned short* __restrict__ Bt1,
    const float* __restrict__ B2, unsigned short* __restrict__ Bt2) {
  __shared__ float tile[32][33];
  const int tx = threadIdx.x & 31, ty = threadIdx.x >> 5;
  int bid = blockIdx.x;
  const float* B; unsigned short* Bt; int K, N, k0, n0;
  if (bid < 12544) {
    B = B1; Bt = Bt1; K = 12544; N = 1024;
    n0 = (bid & 31) * 32; k0 = (bid >> 5) * 32;
  } else {
    bid -= 12544;
    B = B2; Bt = Bt2; K = 1024; N = 1024;
    n0 = (bid & 31) * 32; k0 = (bid >> 5) * 32;
  }
  for (int r = ty; r < 32; r += 8)
    tile[r][tx] = B[(size_t)(k0 + r) * N + n0 + tx];
  __syncthreads();
  for (int r = ty; r < 32; r += 8)
    Bt[(size_t)(n0 + r) * K + k0 + tx] = f2bf(tile[tx][r]);
}

__global__ __launch_bounds__(256) void fc_mfma(
    const unsigned short* __restrict__ A,   // [M][K] bf16
    const unsigned short* __restrict__ Bt,  // [N][K] bf16
    float* __restrict__ Cp, int M, int N, int K, int kLen) {
  const int tid = threadIdx.x;
  const int lane = tid & 63, wave = tid >> 6;
  const int n = lane & 31, half = lane >> 5;
  const int bm = blockIdx.y * 128 + wave * 32;
  const int bn = blockIdx.x * 64;
  const int k0s = blockIdx.z * kLen;
  const unsigned short* arow = A + (size_t)(bm + n) * K + half * 8;
  const unsigned short* b0row = Bt + (size_t)(bn + n) * K + half * 8;
  const unsigned short* b1row = Bt + (size_t)(bn + 32 + n) * K + half * 8;
  float16v acc0, acc1;
#pragma unroll
  for (int r = 0; r < 16; ++r) { acc0[r] = 0.f; acc1[r] = 0.f; }
  for (int k0 = k0s; k0 < k0s + kLen; k0 += 16) {
    short8 a = *(const short8*)(arow + k0);
    short8 b0 = *(const short8*)(b0row + k0);
    short8 b1 = *(const short8*)(b1row + k0);
    acc0 = __builtin_amdgcn_mfma_f32_32x32x16_bf16(a, b0, acc0, 0, 0, 0);
    acc1 = __builtin_amdgcn_mfma_f32_32x32x16_bf16(a, b1, acc1, 0, 0, 0);
  }
  float* Cz = Cp + (size_t)blockIdx.z * M * N;
#pragma unroll
  for (int r = 0; r < 16; ++r) {
    int row = bm + (r & 3) + 8 * (r >> 2) + 4 * half;
    Cz[(size_t)row * N + bn + n] = acc0[r];
    Cz[(size_t)row * N + bn + 32 + n] = acc1[r];
  }
}

// fc1 combine: writes bf16 Abf2 directly (same value as cast-after).
__global__ void fc_combine_bf(const float* __restrict__ p,
                              const float* __restrict__ bias,
                              unsigned short* __restrict__ outBf, int MN,
                              int N, int S) {
  int i = blockIdx.x * 256 + threadIdx.x;
  if (i >= MN) return;
  float v = 0.f;
  for (int s = 0; s < S; ++s) v += p[(size_t)s * MN + i];
  outBf[i] = f2bf(fmaxf(v + bias[i % N], 0.f));
}

__global__ void fc_combine(const float* __restrict__ p,
                           const float* __restrict__ bias,
                           float* __restrict__ out, int MN, int N, int S) {
  int i = blockIdx.x * 256 + threadIdx.x;
  if (i >= MN) return;
  float v = 0.f;
  for (int s = 0; s < S; ++s) v += p[(size_t)s * MN + i];
  out[i] = fmaxf(v + bias[i % N], 0.f);
}

__global__ __launch_bounds__(64) void heads_kernel(
    const float* __restrict__ v, const float* __restrict__ wc,
    const float* __restrict__ bc, const float* __restrict__ wb,
    const float* __restrict__ bbias, float* __restrict__ out) {
  const int m = blockIdx.x;
  const int lane = threadIdx.x;
  float acc[10];
#pragma unroll
  for (int o = 0; o < 10; ++o) acc[o] = 0.f;
  for (int k = lane; k < 1024; k += 64) {
    float x = v[(size_t)m * 1024 + k];
    acc[0] = fmaf(x, wc[k * 2 + 0], acc[0]);
    acc[1] = fmaf(x, wc[k * 2 + 1], acc[1]);
#pragma unroll
    for (int o = 0; o < 8; ++o) acc[2 + o] = fmaf(x, wb[k * 8 + o], acc[2 + o]);
  }
#pragma unroll
  for (int off = 32; off > 0; off >>= 1)
#pragma unroll
    for (int o = 0; o < 10; ++o) acc[o] += __shfl_down(acc[o], off);
  if (lane == 0) {
    out[m * 2 + 0] = acc[0] + bc[0];
    out[m * 2 + 1] = acc[1] + bc[1];
#pragma unroll
    for (int o = 0; o < 8; ++o) out[1024 + m * 8 + o] = acc[2 + o] + bbias[o];
  }
}

// ---------------------------------------------------------------------------
// Host orchestration
// ---------------------------------------------------------------------------
extern "C" void kernel_launch(void* const* d_in, const int* in_sizes, int n_in,
                              void* d_out, int out_size, void* d_ws,
                              size_t ws_size, hipStream_t stream) {
  const float* x      = (const float*)d_in[0];
  const float* w_stem = (const float*)d_in[1];
  const float* w_c2   = (const float*)d_in[2];
  const float* w_c3   = (const float*)d_in[3];
  const float* w_c4   = (const float*)d_in[4];
  const float* w_c5   = (const float*)d_in[5];
  const float* w_f2   = (const float*)d_in[6];
  const float* w_f3   = (const float*)d_in[7];
  const float* w_f4   = (const float*)d_in[8];
  const float* w_f5   = (const float*)d_in[9];
  const float* w_rpn  = (const float*)d_in[10];
  const float* w_cls  = (const float*)d_in[11];
  const float* w_box  = (const float*)d_in[12];
  const float* w_fc1  = (const float*)d_in[13];
  const float* b_fc1  = (const float*)d_in[14];
  const float* w_fc2  = (const float*)d_in[15];
  const float* b_fc2  = (const float*)d_in[16];
  const float* w_clsh = (const float*)d_in[17];
  const float* b_clsh = (const float*)d_in[18];
  const float* w_breg = (const float*)d_in[19];
  const float* b_breg = (const float*)d_in[20];
  float* dout = (float*)d_out;

  float* ws = (float*)d_ws;
  float* stem = ws;                          // 10,240,000 floats
  float* c2   = stem + 10240000;             // 10,240,000
  float* c3   = c2 + 10240000;               // 2,560,000
  float* c4   = c3 + 2560000;                // 640,000
  float* c5   = c4 + 640000;                 // 160,000
  float* f2   = c5 + 160000;                 // 10,240,000
  float* f3   = f2 + 10240000;               // 2,560,000
  float* f4   = f3 + 2560000;                // 640,000
  float* f5   = f4 + 640000;                 // 160,000
  float* boxes_all  = f5 + 160000;           // 16,000
  float* scores_all = boxes_all + 16000;     // 4,000
  float* props      = scores_all + 4000;     // 2,048
  int*   histOld = (int*)(props + 2048);     // 65,536 ints (reused: sel4)
  int*   sel  = histOld + 65536;             // 16 ints (unused now)
  float* wpkA = (float*)(sel + 16);          // 589,824 (f2)
  float* wpkB = wpkA + 589824;               // 589,824 (f3)
  float* wpkC = wpkB + 589824;               // 589,824 (rpn)
  float* wpkD = wpkC + 589824;               // 147,456 (c2, Cin=64)
  float* wpkE = wpkD + 147456;               // 589,824 (c3)
  float* wpkF = wpkE + 589824;               // 589,824 (c4)
  float* wpkG = wpkF + 589824;               // 589,824 (c5)
  float* wpkH = wpkG + 589824;               // 589,824 (f4)
  float* wpkI = wpkH + 589824;               // 589,824 (f5)
  float* wpkS = wpkI + 589824;               // 9,408 (stem [z8][k147][co8])
  // aliases (dead regions reused):
  float* tt0 = stem;                         // rpn px-major, lvl0 (10.24M)
  float* tt1 = c3;                           // lvl1 (2.56M; c3 dead)
  float* tt2 = wpkF;                         // lvl2 (640K; spans wpkF+G, dead)
  float* tt3 = wpkH;                         // lvl3 (160K; dead after laterals)
  int*   hist4 = (int*)wpkE;                 // 4x65536 ints (wpkE dead)
  int*   sel4  = histOld;                    // 4x8 ints
  float* boxes4  = c4;                       // 637,500 <= 640,000 (c4 dead)
  float* scores4 = c5;                       // 159,375 <= 160,000 (c5 dead)
  int*   order  = (int*)c3;                  // NMS (tt1 dead by then)
  unsigned long long* supp =
      (unsigned long long*)(c3 + 8192);      // 2.02 MB
  float* fc2o   = stem + 6422528;            // 524,288 (tt0 region dead)
  float* fcp    = fc2o + 524288;             // 4 x 524,288
  unsigned short* Abf1 = (unsigned short*)c2;            // 512x12544 bf16
  unsigned short* Bt1  = (unsigned short*)(c2 + 3211264);// 1024x12544 bf16
  unsigned short* Abf2 = (unsigned short*)c3;            // 512x1024 bf16
  unsigned short* Bt2  = (unsigned short*)(c3 + 262144); // 1024x1024 bf16

  // ---- unified weight repack ----
  repack_all<<<19045, 256, 0, stream>>>(
      w_f2, w_f3, w_rpn, w_c2, w_c3, w_c4, w_c5, w_f4, w_f5, w_stem,
      wpkA, wpkB, wpkC, wpkD, wpkE, wpkF, wpkG, wpkH, wpkI, wpkS);

  // ---- backbone ----
  stem_conv<<<dim3(25, 25, 8), 256, 0, stream>>>(x, wpkS, stem);
  conv16_s2<4, true><<<dim3(13, 13, 16), 256, 0, stream>>>(
      stem, wpkD, c2, 64, 400, 400, 200, 200);
  conv16_s2<4, true><<<dim3(7, 7, 16), 256, 0, stream>>>(
      c2, wpkE, c3, 256, 200, 200, 100, 100);
  conv16_s2<4, true><<<dim3(4, 4, 16), 256, 0, stream>>>(
      c3, wpkF, c4, 256, 100, 100, 50, 50);
  conv16_s2<4, true><<<dim3(2, 2, 16), 256, 0, stream>>>(
      c4, wpkG, c5, 256, 50, 50, 25, 25);
  // ---- FPN laterals (no relu): merged launches ----
  conv32_lat<4, false, false><<<1904, 256, 0, stream>>>(
      c2, wpkA, f2, 256, 200, 200, 7, 13, 1456,
      c3, wpkB, f3, 256, 100, 100, 4, 7);
  conv16_lat<8, false, false><<<320, 256, 0, stream>>>(
      c4, wpkH, f4, 256, 50, 50, 4, 4, 256,
      c5, wpkI, f5, 256, 25, 25, 2, 2);

  // ---- RPN convs (relu, px-major tt write), merged ----
  conv32_lat<4, true, true><<<1904, 256, 0, stream>>>(
      f2, wpkC, tt0, 256, 200, 200, 7, 13, 1456,
      f3, wpkC, tt1, 256, 100, 100, 4, 7);
  conv16_lat<8, true, true><<<320, 256, 0, stream>>>(
      f4, wpkC, tt2, 256, 50, 50, 4, 4, 256,
      f5, wpkC, tt3, 256, 25, 25, 2, 2);

  // ---- merged decode + selection ----
  hipMemsetAsync(hist4, 0, 4 * 65536 * sizeof(int), stream);
  rpn_decode_all<<<210, 256, 0, stream>>>(tt0, tt1, tt2, tt3, w_cls, w_box,
                                          boxes4, scores4, hist4);
  scan_hi_all<<<4, 256, 0, stream>>>(hist4, sel4);
  hist_lo_all<<<625, 256, 0, stream>>>(scores4, sel4, hist4);
  scan_lo_all<<<4, 256, 0, stream>>>(hist4, sel4);
  compact_all<<<625, 256, 0, stream>>>(scores4, boxes4, sel4, scores_all,
                                       boxes_all);

  // ---- NMS (rank+supp merged) ----
  rank_supp<<<266, 256, 0, stream>>>(scores_all, order, boxes_all, supp);
  nms_scan<<<1, 64, 0, stream>>>(supp, order, boxes_all, scores_all, props,
                                 dout + 5120, dout + 7168);

  // ---- ROI align (direct bf16) + FC heads ----
  roi_align_kernel<<<512, 256, 0, stream>>>(f2, props, Abf1);
  cast_bt_all<<<12544 + 1024, 256, 0, stream>>>(w_fc1, Bt1, w_fc2, Bt2);
  fc_mfma<<<dim3(16, 4, 4), 256, 0, stream>>>(Abf1, Bt1, fcp, 512, 1024, 12544,
                                              3136);
  fc_combine_bf<<<2048, 256, 0, stream>>>(fcp, b_fc1, Abf2, 524288, 1024, 4);
  fc_mfma<<<dim3(16, 4, 4), 256, 0, stream>>>(Abf2, Bt2, fcp, 512, 1024, 1024,
                                              256);
  fc_combine<<<2048, 256, 0, stream>>>(fcp, b_fc2, fc2o, 524288, 1024, 4);
  heads_kernel<<<512, 64, 0, stream>>>(fc2o, w_clsh, b_clsh, w_breg, b_breg,
                                       dout);
}